// Round 1
// baseline (1157.357 us; speedup 1.0000x reference)
//
#include <hip/hip_runtime.h>

#define NN 100000
#define NE 1600000
#define D 128
#define NG 64
#define BM 64

__device__ __forceinline__ int lower_bound_i(const int* a, int n, int key) {
  int lo = 0, hi = n;
  while (lo < hi) { int mid = (lo + hi) >> 1; if (a[mid] < key) lo = mid + 1; else hi = mid; }
  return lo;
}

__global__ void k_degree(const int* __restrict__ src, const int* __restrict__ dst,
                         int* __restrict__ oc, int* __restrict__ ic) {
  int e = blockIdx.x * blockDim.x + threadIdx.x;
  if (e < NE) { atomicAdd(&oc[src[e]], 1); atomicAdd(&ic[dst[e]], 1); }
}

__global__ void k_norms(const int* __restrict__ oc, const int* __restrict__ ic,
                        float* __restrict__ on, float* __restrict__ inn) {
  int n = blockIdx.x * blockDim.x + threadIdx.x;
  if (n < NN) {
    on[n] = 1.0f / sqrtf((float)max(oc[n], 1));
    inn[n] = 1.0f / sqrtf((float)max(ic[n], 1));
  }
}

__global__ void k_scan(const int* __restrict__ cnt, int* __restrict__ off) {
  __shared__ int s[1024];
  const int T = 1024;
  int t = threadIdx.x;
  const int chunk = (NN + T - 1) / T;
  int lo = t * chunk, hi = min(lo + chunk, NN);
  int sum = 0;
  for (int i = lo; i < hi; ++i) sum += cnt[i];
  s[t] = sum;
  __syncthreads();
  for (int o = 1; o < T; o <<= 1) {
    int v = (t >= o) ? s[t - o] : 0;
    __syncthreads();
    s[t] += v;
    __syncthreads();
  }
  int base = s[t] - sum;  // exclusive prefix of this thread's chunk
  for (int i = lo; i < hi; ++i) { off[i] = base; base += cnt[i]; }
  if (t == 0) off[NN] = NE;
}

__global__ void k_fill(const int* __restrict__ src, const int* __restrict__ dst,
                       const int* __restrict__ off, int* __restrict__ cur,
                       int* __restrict__ csr) {
  int e = blockIdx.x * blockDim.x + threadIdx.x;
  if (e < NE) {
    int d = dst[e];
    int p = atomicAdd(&cur[d], 1);
    csr[off[d] + p] = src[e];
  }
}

// C[r,:] = rs[r] * (A[r,:] @ W)   (fp32 vector, W staged in LDS)
__global__ __launch_bounds__(256) void k_matmul(
    const float* __restrict__ A, const float* __restrict__ W,
    const float* __restrict__ rs, float* __restrict__ C) {
  __shared__ float As[BM][132];     // pad 132: a-reads spread over banks
  __shared__ float Ws[128 * 128];
  const int tid = threadIdx.x;
  const int row0 = blockIdx.x * BM;
  {
    const float4* W4 = (const float4*)W;
    float4* Ws4 = (float4*)Ws;
#pragma unroll
    for (int i = 0; i < 16; ++i) Ws4[tid + i * 256] = W4[tid + i * 256];
  }
#pragma unroll
  for (int i = 0; i < 8; ++i) {
    int idx = tid + i * 256;        // 0..2047 float4 slots (64 rows x 32)
    int r = idx >> 5;
    int c4 = idx & 31;
    int grow = row0 + r;
    float4 v = make_float4(0.f, 0.f, 0.f, 0.f);
    if (grow < NN) {
      v = *(const float4*)(A + (size_t)grow * D + c4 * 4);
      float sc = rs[grow];
      v.x *= sc; v.y *= sc; v.z *= sc; v.w *= sc;
    }
    *(float4*)&As[r][c4 * 4] = v;
  }
  __syncthreads();
  const int tx = tid & 15, ty = tid >> 4;
  const int r0 = ty * 4, c0 = tx * 4;
  float acc[4][8];
#pragma unroll
  for (int i = 0; i < 4; ++i)
#pragma unroll
    for (int j = 0; j < 8; ++j) acc[i][j] = 0.f;
#pragma unroll 8
  for (int k = 0; k < 128; ++k) {
    float4 w0 = *(const float4*)&Ws[k * 128 + c0];        // cols c0..c0+3
    float4 w1 = *(const float4*)&Ws[k * 128 + c0 + 64];   // cols 64+c0..
    float av[4];
    av[0] = As[r0 + 0][k]; av[1] = As[r0 + 1][k];
    av[2] = As[r0 + 2][k]; av[3] = As[r0 + 3][k];
#pragma unroll
    for (int i = 0; i < 4; ++i) {
      acc[i][0] = fmaf(av[i], w0.x, acc[i][0]);
      acc[i][1] = fmaf(av[i], w0.y, acc[i][1]);
      acc[i][2] = fmaf(av[i], w0.z, acc[i][2]);
      acc[i][3] = fmaf(av[i], w0.w, acc[i][3]);
      acc[i][4] = fmaf(av[i], w1.x, acc[i][4]);
      acc[i][5] = fmaf(av[i], w1.y, acc[i][5]);
      acc[i][6] = fmaf(av[i], w1.z, acc[i][6]);
      acc[i][7] = fmaf(av[i], w1.w, acc[i][7]);
    }
  }
#pragma unroll
  for (int i = 0; i < 4; ++i) {
    int row = row0 + r0 + i;
    if (row < NN) {
      float4 o0 = make_float4(acc[i][0], acc[i][1], acc[i][2], acc[i][3]);
      float4 o1 = make_float4(acc[i][4], acc[i][5], acc[i][6], acc[i][7]);
      *(float4*)(C + (size_t)row * D + c0) = o0;
      *(float4*)(C + (size_t)row * D + 64 + c0) = o1;
    }
  }
}

// out[d,:] = relu(in_norm[d] * sum_{s in CSR(d)} t[s,:] + bias)
// one wave per dst node; lane holds 2 feature cols (float2)
__global__ __launch_bounds__(256) void k_gather(
    const float* __restrict__ t, const int* __restrict__ csr,
    const int* __restrict__ off, const float* __restrict__ inn,
    const float* __restrict__ bias, float* __restrict__ outp) {
  int w = (blockIdx.x * blockDim.x + threadIdx.x) >> 6;
  int lane = threadIdx.x & 63;
  if (w >= NN) return;
  int lo = off[w], hi = off[w + 1];
  const float* tp = t + 2 * lane;
  float ax = 0.f, ay = 0.f;
  int e = lo;
  for (; e + 3 < hi; e += 4) {
    int s0 = csr[e], s1 = csr[e + 1], s2 = csr[e + 2], s3 = csr[e + 3];
    float2 v0 = *(const float2*)(tp + (size_t)s0 * D);
    float2 v1 = *(const float2*)(tp + (size_t)s1 * D);
    float2 v2 = *(const float2*)(tp + (size_t)s2 * D);
    float2 v3 = *(const float2*)(tp + (size_t)s3 * D);
    ax += v0.x + v1.x + v2.x + v3.x;
    ay += v0.y + v1.y + v2.y + v3.y;
  }
  for (; e < hi; ++e) {
    int s0 = csr[e];
    float2 v0 = *(const float2*)(tp + (size_t)s0 * D);
    ax += v0.x; ay += v0.y;
  }
  float nm = inn[w];
  float2 b = *(const float2*)(bias + 2 * lane);
  float2 o;
  o.x = fmaxf(fmaf(nm, ax, b.x), 0.f);
  o.y = fmaxf(fmaf(nm, ay, b.y), 0.f);
  *(float2*)(outp + (size_t)w * D + 2 * lane) = o;
}

// per-graph mean over sorted node2graph; one block per graph, thread = feature col
__global__ void k_pool(const float* __restrict__ h2, const int* __restrict__ n2g,
                       float* __restrict__ hg) {
  int g = blockIdx.x;
  int c = threadIdx.x;
  int start = lower_bound_i(n2g, NN, g);
  int end = lower_bound_i(n2g, NN, g + 1);
  float sum = 0.f;
  for (int n = start; n < end; ++n) sum += h2[(size_t)n * D + c];
  int cnt = end - start;
  hg[g * D + c] = sum / (float)max(cnt, 1);
}

// 3-layer MLP head; one block per graph, 128 threads
__global__ void k_mlp(const float* __restrict__ hg,
                      const float* __restrict__ Wc1, const float* __restrict__ bc1,
                      const float* __restrict__ Wc2, const float* __restrict__ bc2,
                      const float* __restrict__ Wc3, const float* __restrict__ bc3,
                      float* __restrict__ out) {
  __shared__ float xin[128];
  __shared__ float x1[128];
  __shared__ float red[128];
  int g = blockIdx.x, j = threadIdx.x;
  xin[j] = hg[g * D + j];
  __syncthreads();
  float s = bc1[j];
#pragma unroll 8
  for (int k = 0; k < 128; ++k) s = fmaf(xin[k], Wc1[k * D + j], s);
  x1[j] = fmaxf(s, 0.f);
  __syncthreads();
  float s2 = bc2[j];
#pragma unroll 8
  for (int k = 0; k < 128; ++k) s2 = fmaf(x1[k], Wc2[k * D + j], s2);
  float v2 = fmaxf(s2, 0.f);
  red[j] = v2 * Wc3[j];
  __syncthreads();
  for (int o = 64; o > 0; o >>= 1) {
    if (j < o) red[j] += red[j + o];
    __syncthreads();
  }
  if (j == 0) out[g] = red[0] + bc3[0];
}

extern "C" void kernel_launch(void* const* d_in, const int* in_sizes, int n_in,
                              void* d_out, int out_size, void* d_ws, size_t ws_size,
                              hipStream_t stream) {
  const float* h   = (const float*)d_in[0];
  const int* src   = (const int*)d_in[1];
  const int* dst   = (const int*)d_in[2];
  const int* n2g   = (const int*)d_in[3];
  const float* W1  = (const float*)d_in[4];
  const float* b1  = (const float*)d_in[5];
  const float* W2  = (const float*)d_in[6];
  const float* b2  = (const float*)d_in[7];
  const float* Wc1 = (const float*)d_in[8];
  const float* bc1 = (const float*)d_in[9];
  const float* Wc2 = (const float*)d_in[10];
  const float* bc2 = (const float*)d_in[11];
  const float* Wc3 = (const float*)d_in[12];
  const float* bc3 = (const float*)d_in[13];
  float* out = (float*)d_out;

  char* p = (char*)d_ws;
  size_t o = 0;
  auto take = [&](size_t b) { void* q = p + o; o = (o + b + 255) & ~(size_t)255; return q; };
  int* oc    = (int*)take(NN * 4);
  int* ic    = (int*)take(NN * 4);
  int* cur   = (int*)take(NN * 4);
  size_t zero_bytes = o;                    // zero the 3 counter arrays
  int* off   = (int*)take((NN + 1) * 4);
  float* onrm = (float*)take(NN * 4);
  float* inrm = (float*)take(NN * 4);
  int* csr   = (int*)take((size_t)NE * 4);
  float* tbuf = (float*)take((size_t)NN * D * 4);
  float* ubuf = (float*)take((size_t)NN * D * 4);
  float* hg  = (float*)take(NG * D * 4);
  (void)ws_size; (void)in_sizes; (void)n_in; (void)out_size;

  hipMemsetAsync(d_ws, 0, zero_bytes, stream);
  k_degree<<<(NE + 255) / 256, 256, 0, stream>>>(src, dst, oc, ic);
  k_norms<<<(NN + 255) / 256, 256, 0, stream>>>(oc, ic, onrm, inrm);
  k_scan<<<1, 1024, 0, stream>>>(ic, off);
  k_fill<<<(NE + 255) / 256, 256, 0, stream>>>(src, dst, off, cur, csr);

  // layer 1: t = (h * out_norm) @ W1 ; h1 = relu(in_norm * gather(t) + b1)
  k_matmul<<<(NN + BM - 1) / BM, 256, 0, stream>>>(h, W1, onrm, tbuf);
  k_gather<<<(NN * 64) / 256, 256, 0, stream>>>(tbuf, csr, off, inrm, b1, ubuf);
  // layer 2
  k_matmul<<<(NN + BM - 1) / BM, 256, 0, stream>>>(ubuf, W2, onrm, tbuf);
  k_gather<<<(NN * 64) / 256, 256, 0, stream>>>(tbuf, csr, off, inrm, b2, ubuf);

  k_pool<<<NG, 128, 0, stream>>>(ubuf, n2g, hg);
  k_mlp<<<NG, 128, 0, stream>>>(hg, Wc1, bc1, Wc2, bc2, Wc3, bc3, out);
}

// Round 2
// 866.271 us; speedup vs baseline: 1.3360x; 1.3360x over previous
//
#include <hip/hip_runtime.h>

#define NN 100000
#define NE 1600000
#define D 128
#define NG 64
#define BM 64
#define POOL_CHUNK 256

__device__ __forceinline__ int lower_bound_i(const int* a, int n, int key) {
  int lo = 0, hi = n;
  while (lo < hi) { int mid = (lo + hi) >> 1; if (a[mid] < key) lo = mid + 1; else hi = mid; }
  return lo;
}

__global__ void k_degree(const int* __restrict__ src, const int* __restrict__ dst,
                         int* __restrict__ oc, int* __restrict__ ic) {
  int e = blockIdx.x * blockDim.x + threadIdx.x;
  if (e < NE) { atomicAdd(&oc[src[e]], 1); atomicAdd(&ic[dst[e]], 1); }
}

__global__ void k_norms(const int* __restrict__ oc, const int* __restrict__ ic,
                        float* __restrict__ on, float* __restrict__ inn) {
  int n = blockIdx.x * blockDim.x + threadIdx.x;
  if (n < NN) {
    on[n] = 1.0f / sqrtf((float)max(oc[n], 1));
    inn[n] = 1.0f / sqrtf((float)max(ic[n], 1));
  }
}

__global__ void k_scan(const int* __restrict__ cnt, int* __restrict__ off) {
  __shared__ int s[1024];
  const int T = 1024;
  int t = threadIdx.x;
  const int chunk = (NN + T - 1) / T;
  int lo = t * chunk, hi = min(lo + chunk, NN);
  int sum = 0;
  for (int i = lo; i < hi; ++i) sum += cnt[i];
  s[t] = sum;
  __syncthreads();
  for (int o = 1; o < T; o <<= 1) {
    int v = (t >= o) ? s[t - o] : 0;
    __syncthreads();
    s[t] += v;
    __syncthreads();
  }
  int base = s[t] - sum;  // exclusive prefix of this thread's chunk
  for (int i = lo; i < hi; ++i) { off[i] = base; base += cnt[i]; }
  if (t == 0) off[NN] = NE;
}

__global__ void k_fill(const int* __restrict__ src, const int* __restrict__ dst,
                       const int* __restrict__ off, int* __restrict__ cur,
                       int* __restrict__ csr) {
  int e = blockIdx.x * blockDim.x + threadIdx.x;
  if (e < NE) {
    int d = dst[e];
    int p = atomicAdd(&cur[d], 1);
    csr[off[d] + p] = src[e];
  }
}

// C[r,:] = rs[r] * (A[r,:] @ W)   (fp32 vector, W staged in LDS)
__global__ __launch_bounds__(256) void k_matmul(
    const float* __restrict__ A, const float* __restrict__ W,
    const float* __restrict__ rs, float* __restrict__ C) {
  __shared__ float As[BM][132];     // pad 132: a-reads spread over banks
  __shared__ float Ws[128 * 128];
  const int tid = threadIdx.x;
  const int row0 = blockIdx.x * BM;
  {
    const float4* W4 = (const float4*)W;
    float4* Ws4 = (float4*)Ws;
#pragma unroll
    for (int i = 0; i < 16; ++i) Ws4[tid + i * 256] = W4[tid + i * 256];
  }
#pragma unroll
  for (int i = 0; i < 8; ++i) {
    int idx = tid + i * 256;        // 0..2047 float4 slots (64 rows x 32)
    int r = idx >> 5;
    int c4 = idx & 31;
    int grow = row0 + r;
    float4 v = make_float4(0.f, 0.f, 0.f, 0.f);
    if (grow < NN) {
      v = *(const float4*)(A + (size_t)grow * D + c4 * 4);
      float sc = rs[grow];
      v.x *= sc; v.y *= sc; v.z *= sc; v.w *= sc;
    }
    *(float4*)&As[r][c4 * 4] = v;
  }
  __syncthreads();
  const int tx = tid & 15, ty = tid >> 4;
  const int r0 = ty * 4, c0 = tx * 4;
  float acc[4][8];
#pragma unroll
  for (int i = 0; i < 4; ++i)
#pragma unroll
    for (int j = 0; j < 8; ++j) acc[i][j] = 0.f;
#pragma unroll 8
  for (int k = 0; k < 128; ++k) {
    float4 w0 = *(const float4*)&Ws[k * 128 + c0];        // cols c0..c0+3
    float4 w1 = *(const float4*)&Ws[k * 128 + c0 + 64];   // cols 64+c0..
    float av[4];
    av[0] = As[r0 + 0][k]; av[1] = As[r0 + 1][k];
    av[2] = As[r0 + 2][k]; av[3] = As[r0 + 3][k];
#pragma unroll
    for (int i = 0; i < 4; ++i) {
      acc[i][0] = fmaf(av[i], w0.x, acc[i][0]);
      acc[i][1] = fmaf(av[i], w0.y, acc[i][1]);
      acc[i][2] = fmaf(av[i], w0.z, acc[i][2]);
      acc[i][3] = fmaf(av[i], w0.w, acc[i][3]);
      acc[i][4] = fmaf(av[i], w1.x, acc[i][4]);
      acc[i][5] = fmaf(av[i], w1.y, acc[i][5]);
      acc[i][6] = fmaf(av[i], w1.z, acc[i][6]);
      acc[i][7] = fmaf(av[i], w1.w, acc[i][7]);
    }
  }
#pragma unroll
  for (int i = 0; i < 4; ++i) {
    int row = row0 + r0 + i;
    if (row < NN) {
      float4 o0 = make_float4(acc[i][0], acc[i][1], acc[i][2], acc[i][3]);
      float4 o1 = make_float4(acc[i][4], acc[i][5], acc[i][6], acc[i][7]);
      *(float4*)(C + (size_t)row * D + c0) = o0;
      *(float4*)(C + (size_t)row * D + 64 + c0) = o1;
    }
  }
}

// out[d,:] = relu(in_norm[d] * sum_{s in CSR(d)} t[s,:] + bias)
// one wave per dst node; lane holds 2 feature cols (float2)
__global__ __launch_bounds__(256) void k_gather(
    const float* __restrict__ t, const int* __restrict__ csr,
    const int* __restrict__ off, const float* __restrict__ inn,
    const float* __restrict__ bias, float* __restrict__ outp) {
  int w = (blockIdx.x * blockDim.x + threadIdx.x) >> 6;
  int lane = threadIdx.x & 63;
  if (w >= NN) return;
  int lo = off[w], hi = off[w + 1];
  const float* tp = t + 2 * lane;
  float ax = 0.f, ay = 0.f;
  int e = lo;
  for (; e + 3 < hi; e += 4) {
    int s0 = csr[e], s1 = csr[e + 1], s2 = csr[e + 2], s3 = csr[e + 3];
    float2 v0 = *(const float2*)(tp + (size_t)s0 * D);
    float2 v1 = *(const float2*)(tp + (size_t)s1 * D);
    float2 v2 = *(const float2*)(tp + (size_t)s2 * D);
    float2 v3 = *(const float2*)(tp + (size_t)s3 * D);
    ax += v0.x + v1.x + v2.x + v3.x;
    ay += v0.y + v1.y + v2.y + v3.y;
  }
  for (; e < hi; ++e) {
    int s0 = csr[e];
    float2 v0 = *(const float2*)(tp + (size_t)s0 * D);
    ax += v0.x; ay += v0.y;
  }
  float nm = inn[w];
  float2 b = *(const float2*)(bias + 2 * lane);
  float2 o;
  o.x = fmaxf(fmaf(nm, ax, b.x), 0.f);
  o.y = fmaxf(fmaf(nm, ay, b.y), 0.f);
  *(float2*)(outp + (size_t)w * D + 2 * lane) = o;
}

// parallel pool partial sums: each block owns POOL_CHUNK contiguous nodes,
// thread = feature col; register-accumulate runs of equal graph id (n2g sorted),
// atomicAdd to sums[g][c] only at run boundaries.
__global__ __launch_bounds__(128) void k_pool_partial(
    const float* __restrict__ h2, const int* __restrict__ n2g,
    float* __restrict__ sums) {
  int c = threadIdx.x;
  int n0 = blockIdx.x * POOL_CHUNK;
  int n1 = min(n0 + POOL_CHUNK, NN);
  if (n0 >= NN) return;
  int gcur = n2g[n0];
  float acc = 0.f;
  for (int n = n0; n < n1; ++n) {
    int g = n2g[n];
    if (g != gcur) {
      atomicAdd(&sums[gcur * D + c], acc);
      acc = 0.f;
      gcur = g;
    }
    acc += h2[(size_t)n * D + c];
  }
  atomicAdd(&sums[gcur * D + c], acc);
}

// 3-layer MLP head; one block per graph, 128 threads. Divides sums by count.
__global__ void k_mlp(const float* __restrict__ sums, const int* __restrict__ n2g,
                      const float* __restrict__ Wc1, const float* __restrict__ bc1,
                      const float* __restrict__ Wc2, const float* __restrict__ bc2,
                      const float* __restrict__ Wc3, const float* __restrict__ bc3,
                      float* __restrict__ out) {
  __shared__ float xin[128];
  __shared__ float x1[128];
  __shared__ float red[128];
  int g = blockIdx.x, j = threadIdx.x;
  int start = lower_bound_i(n2g, NN, g);
  int end = lower_bound_i(n2g, NN, g + 1);
  float inv = 1.0f / (float)max(end - start, 1);
  xin[j] = sums[g * D + j] * inv;
  __syncthreads();
  float s = bc1[j];
#pragma unroll 8
  for (int k = 0; k < 128; ++k) s = fmaf(xin[k], Wc1[k * D + j], s);
  x1[j] = fmaxf(s, 0.f);
  __syncthreads();
  float s2 = bc2[j];
#pragma unroll 8
  for (int k = 0; k < 128; ++k) s2 = fmaf(x1[k], Wc2[k * D + j], s2);
  float v2 = fmaxf(s2, 0.f);
  red[j] = v2 * Wc3[j];
  __syncthreads();
  for (int o = 64; o > 0; o >>= 1) {
    if (j < o) red[j] += red[j + o];
    __syncthreads();
  }
  if (j == 0) out[g] = red[0] + bc3[0];
}

extern "C" void kernel_launch(void* const* d_in, const int* in_sizes, int n_in,
                              void* d_out, int out_size, void* d_ws, size_t ws_size,
                              hipStream_t stream) {
  const float* h   = (const float*)d_in[0];
  const int* src   = (const int*)d_in[1];
  const int* dst   = (const int*)d_in[2];
  const int* n2g   = (const int*)d_in[3];
  const float* W1  = (const float*)d_in[4];
  const float* b1  = (const float*)d_in[5];
  const float* W2  = (const float*)d_in[6];
  const float* b2  = (const float*)d_in[7];
  const float* Wc1 = (const float*)d_in[8];
  const float* bc1 = (const float*)d_in[9];
  const float* Wc2 = (const float*)d_in[10];
  const float* bc2 = (const float*)d_in[11];
  const float* Wc3 = (const float*)d_in[12];
  const float* bc3 = (const float*)d_in[13];
  float* out = (float*)d_out;

  char* p = (char*)d_ws;
  size_t o = 0;
  auto take = [&](size_t b) { void* q = p + o; o = (o + b + 255) & ~(size_t)255; return q; };
  int* oc    = (int*)take(NN * 4);
  int* ic    = (int*)take(NN * 4);
  int* cur   = (int*)take(NN * 4);
  float* sums = (float*)take(NG * D * 4);
  size_t zero_bytes = o;                    // zero counters + pool sums
  int* off   = (int*)take((NN + 1) * 4);
  float* onrm = (float*)take(NN * 4);
  float* inrm = (float*)take(NN * 4);
  int* csr   = (int*)take((size_t)NE * 4);
  float* tbuf = (float*)take((size_t)NN * D * 4);
  float* ubuf = (float*)take((size_t)NN * D * 4);
  (void)ws_size; (void)in_sizes; (void)n_in; (void)out_size;

  hipMemsetAsync(d_ws, 0, zero_bytes, stream);
  k_degree<<<(NE + 255) / 256, 256, 0, stream>>>(src, dst, oc, ic);
  k_norms<<<(NN + 255) / 256, 256, 0, stream>>>(oc, ic, onrm, inrm);
  k_scan<<<1, 1024, 0, stream>>>(ic, off);
  k_fill<<<(NE + 255) / 256, 256, 0, stream>>>(src, dst, off, cur, csr);

  // layer 1: t = (h * out_norm) @ W1 ; h1 = relu(in_norm * gather(t) + b1)
  k_matmul<<<(NN + BM - 1) / BM, 256, 0, stream>>>(h, W1, onrm, tbuf);
  k_gather<<<(NN * 64) / 256, 256, 0, stream>>>(tbuf, csr, off, inrm, b1, ubuf);
  // layer 2
  k_matmul<<<(NN + BM - 1) / BM, 256, 0, stream>>>(ubuf, W2, onrm, tbuf);
  k_gather<<<(NN * 64) / 256, 256, 0, stream>>>(tbuf, csr, off, inrm, b2, ubuf);

  k_pool_partial<<<(NN + POOL_CHUNK - 1) / POOL_CHUNK, 128, 0, stream>>>(ubuf, n2g, sums);
  k_mlp<<<NG, 128, 0, stream>>>(sums, n2g, Wc1, bc1, Wc2, bc2, Wc3, bc3, out);
}

// Round 3
// 691.851 us; speedup vs baseline: 1.6728x; 1.2521x over previous
//
#include <hip/hip_runtime.h>

#define NN 100000
#define NE 1600000
#define D 128
#define NG 64
#define BM 64
#define POOL_CHUNK 256
#define SCAN_CHUNK 1024
#define NB_SCAN ((NN + SCAN_CHUNK - 1) / SCAN_CHUNK)   // 98

__device__ __forceinline__ int lower_bound_i(const int* a, int n, int key) {
  int lo = 0, hi = n;
  while (lo < hi) { int mid = (lo + hi) >> 1; if (a[mid] < key) lo = mid + 1; else hi = mid; }
  return lo;
}

__global__ void k_degree(const int* __restrict__ src, const int* __restrict__ dst,
                         int* __restrict__ oc, int* __restrict__ ic) {
  int e = blockIdx.x * blockDim.x + threadIdx.x;
  if (e < NE) { atomicAdd(&oc[src[e]], 1); atomicAdd(&ic[dst[e]], 1); }
}

__global__ void k_norms(const int* __restrict__ oc, const int* __restrict__ ic,
                        float* __restrict__ on, float* __restrict__ inn) {
  int n = blockIdx.x * blockDim.x + threadIdx.x;
  if (n < NN) {
    on[n] = 1.0f / sqrtf((float)max(oc[n], 1));
    inn[n] = 1.0f / sqrtf((float)max(ic[n], 1));
  }
}

// phase A: per-block chunk sums (coalesced int4, shuffle reduce)
__global__ __launch_bounds__(256) void k_scan_a(const int* __restrict__ cnt,
                                                int* __restrict__ bsum) {
  int b = blockIdx.x, t = threadIdx.x;
  int idx = b * SCAN_CHUNK + t * 4;
  int4 v = make_int4(0, 0, 0, 0);
  if (idx < NN) v = *(const int4*)(cnt + idx);   // NN % 4 == 0
  int s = v.x + v.y + v.z + v.w;
#pragma unroll
  for (int o = 1; o < 64; o <<= 1) s += __shfl_xor(s, o);
  __shared__ int ws[4];
  if ((t & 63) == 0) ws[t >> 6] = s;
  __syncthreads();
  if (t == 0) bsum[b] = ws[0] + ws[1] + ws[2] + ws[3];
}

// phase B: exclusive scan of the 98 block sums (in place), set off[NN]
__global__ void k_scan_b(int* __restrict__ bsum, int* __restrict__ off) {
  __shared__ int s[128];
  int t = threadIdx.x;
  int v = (t < NB_SCAN) ? bsum[t] : 0;
  s[t] = v;
  __syncthreads();
  for (int o = 1; o < 128; o <<= 1) {
    int u = (t >= o) ? s[t - o] : 0;
    __syncthreads();
    s[t] += u;
    __syncthreads();
  }
  if (t < NB_SCAN) bsum[t] = s[t] - v;  // exclusive prefix
  if (t == 0) off[NN] = NE;
}

// phase C: intra-block exclusive scan + block prefix -> off[]
__global__ __launch_bounds__(256) void k_scan_c(const int* __restrict__ cnt,
                                                const int* __restrict__ bsum,
                                                int* __restrict__ off) {
  int b = blockIdx.x, t = threadIdx.x;
  int idx = b * SCAN_CHUNK + t * 4;
  int4 v = make_int4(0, 0, 0, 0);
  if (idx < NN) v = *(const int4*)(cnt + idx);
  int lsum = v.x + v.y + v.z + v.w;
  int lane = t & 63, wid = t >> 6;
  int x = lsum;
#pragma unroll
  for (int o = 1; o < 64; o <<= 1) {
    int u = __shfl_up(x, o);
    if (lane >= o) x += u;
  }
  __shared__ int wsum[4];
  if (lane == 63) wsum[wid] = x;
  __syncthreads();
  int woff = 0;
  for (int i = 0; i < 4; ++i) woff += (i < wid) ? wsum[i] : 0;
  int excl = x - lsum + woff + bsum[b];
  if (idx < NN) {
    int4 o4;
    o4.x = excl;
    o4.y = excl + v.x;
    o4.z = o4.y + v.y;
    o4.w = o4.z + v.z;
    *(int4*)(off + idx) = o4;
  }
}

__global__ void k_fill(const int* __restrict__ src, const int* __restrict__ dst,
                       const int* __restrict__ off, int* __restrict__ cur,
                       int* __restrict__ csr) {
  int e = blockIdx.x * blockDim.x + threadIdx.x;
  if (e < NE) {
    int d = dst[e];
    int p = atomicAdd(&cur[d], 1);
    csr[off[d] + p] = src[e];
  }
}

// C[r,:] = rs[r] * (A[r,:] @ W)   (fp32 vector, W staged in LDS)
__global__ __launch_bounds__(256) void k_matmul(
    const float* __restrict__ A, const float* __restrict__ W,
    const float* __restrict__ rs, float* __restrict__ C) {
  __shared__ float As[BM][132];     // pad 132: a-reads spread over banks
  __shared__ float Ws[128 * 128];
  const int tid = threadIdx.x;
  const int row0 = blockIdx.x * BM;
  {
    const float4* W4 = (const float4*)W;
    float4* Ws4 = (float4*)Ws;
#pragma unroll
    for (int i = 0; i < 16; ++i) Ws4[tid + i * 256] = W4[tid + i * 256];
  }
#pragma unroll
  for (int i = 0; i < 8; ++i) {
    int idx = tid + i * 256;        // 0..2047 float4 slots (64 rows x 32)
    int r = idx >> 5;
    int c4 = idx & 31;
    int grow = row0 + r;
    float4 v = make_float4(0.f, 0.f, 0.f, 0.f);
    if (grow < NN) {
      v = *(const float4*)(A + (size_t)grow * D + c4 * 4);
      float sc = rs[grow];
      v.x *= sc; v.y *= sc; v.z *= sc; v.w *= sc;
    }
    *(float4*)&As[r][c4 * 4] = v;
  }
  __syncthreads();
  const int tx = tid & 15, ty = tid >> 4;
  const int r0 = ty * 4, c0 = tx * 4;
  float acc[4][8];
#pragma unroll
  for (int i = 0; i < 4; ++i)
#pragma unroll
    for (int j = 0; j < 8; ++j) acc[i][j] = 0.f;
#pragma unroll 8
  for (int k = 0; k < 128; ++k) {
    float4 w0 = *(const float4*)&Ws[k * 128 + c0];        // cols c0..c0+3
    float4 w1 = *(const float4*)&Ws[k * 128 + c0 + 64];   // cols 64+c0..
    float av[4];
    av[0] = As[r0 + 0][k]; av[1] = As[r0 + 1][k];
    av[2] = As[r0 + 2][k]; av[3] = As[r0 + 3][k];
#pragma unroll
    for (int i = 0; i < 4; ++i) {
      acc[i][0] = fmaf(av[i], w0.x, acc[i][0]);
      acc[i][1] = fmaf(av[i], w0.y, acc[i][1]);
      acc[i][2] = fmaf(av[i], w0.z, acc[i][2]);
      acc[i][3] = fmaf(av[i], w0.w, acc[i][3]);
      acc[i][4] = fmaf(av[i], w1.x, acc[i][4]);
      acc[i][5] = fmaf(av[i], w1.y, acc[i][5]);
      acc[i][6] = fmaf(av[i], w1.z, acc[i][6]);
      acc[i][7] = fmaf(av[i], w1.w, acc[i][7]);
    }
  }
#pragma unroll
  for (int i = 0; i < 4; ++i) {
    int row = row0 + r0 + i;
    if (row < NN) {
      float4 o0 = make_float4(acc[i][0], acc[i][1], acc[i][2], acc[i][3]);
      float4 o1 = make_float4(acc[i][4], acc[i][5], acc[i][6], acc[i][7]);
      *(float4*)(C + (size_t)row * D + c0) = o0;
      *(float4*)(C + (size_t)row * D + 64 + c0) = o1;
    }
  }
}

// out[d,:] = relu(in_norm[d] * sum_{s in CSR(d)} t[s,:] + bias)
// one wave per dst node; lane holds 2 feature cols (float2)
__global__ __launch_bounds__(256) void k_gather(
    const float* __restrict__ t, const int* __restrict__ csr,
    const int* __restrict__ off, const float* __restrict__ inn,
    const float* __restrict__ bias, float* __restrict__ outp) {
  int w = (blockIdx.x * blockDim.x + threadIdx.x) >> 6;
  int lane = threadIdx.x & 63;
  if (w >= NN) return;
  int lo = off[w], hi = off[w + 1];
  const float* tp = t + 2 * lane;
  float ax = 0.f, ay = 0.f;
  int e = lo;
  for (; e + 3 < hi; e += 4) {
    int s0 = csr[e], s1 = csr[e + 1], s2 = csr[e + 2], s3 = csr[e + 3];
    float2 v0 = *(const float2*)(tp + (size_t)s0 * D);
    float2 v1 = *(const float2*)(tp + (size_t)s1 * D);
    float2 v2 = *(const float2*)(tp + (size_t)s2 * D);
    float2 v3 = *(const float2*)(tp + (size_t)s3 * D);
    ax += v0.x + v1.x + v2.x + v3.x;
    ay += v0.y + v1.y + v2.y + v3.y;
  }
  for (; e < hi; ++e) {
    int s0 = csr[e];
    float2 v0 = *(const float2*)(tp + (size_t)s0 * D);
    ax += v0.x; ay += v0.y;
  }
  float nm = inn[w];
  float2 b = *(const float2*)(bias + 2 * lane);
  float2 o;
  o.x = fmaxf(fmaf(nm, ax, b.x), 0.f);
  o.y = fmaxf(fmaf(nm, ay, b.y), 0.f);
  *(float2*)(outp + (size_t)w * D + 2 * lane) = o;
}

// parallel pool partial sums: each block owns POOL_CHUNK contiguous nodes,
// thread = feature col; register-accumulate runs of equal graph id (n2g sorted),
// atomicAdd to sums[g][c] only at run boundaries.
__global__ __launch_bounds__(128) void k_pool_partial(
    const float* __restrict__ h2, const int* __restrict__ n2g,
    float* __restrict__ sums) {
  int c = threadIdx.x;
  int n0 = blockIdx.x * POOL_CHUNK;
  int n1 = min(n0 + POOL_CHUNK, NN);
  if (n0 >= NN) return;
  int gcur = n2g[n0];
  float acc = 0.f;
  for (int n = n0; n < n1; ++n) {
    int g = n2g[n];
    if (g != gcur) {
      atomicAdd(&sums[gcur * D + c], acc);
      acc = 0.f;
      gcur = g;
    }
    acc += h2[(size_t)n * D + c];
  }
  atomicAdd(&sums[gcur * D + c], acc);
}

// 3-layer MLP head; one block per graph, 128 threads. Divides sums by count.
__global__ void k_mlp(const float* __restrict__ sums, const int* __restrict__ n2g,
                      const float* __restrict__ Wc1, const float* __restrict__ bc1,
                      const float* __restrict__ Wc2, const float* __restrict__ bc2,
                      const float* __restrict__ Wc3, const float* __restrict__ bc3,
                      float* __restrict__ out) {
  __shared__ float xin[128];
  __shared__ float x1[128];
  __shared__ float red[128];
  int g = blockIdx.x, j = threadIdx.x;
  int start = lower_bound_i(n2g, NN, g);
  int end = lower_bound_i(n2g, NN, g + 1);
  float inv = 1.0f / (float)max(end - start, 1);
  xin[j] = sums[g * D + j] * inv;
  __syncthreads();
  float s = bc1[j];
#pragma unroll 8
  for (int k = 0; k < 128; ++k) s = fmaf(xin[k], Wc1[k * D + j], s);
  x1[j] = fmaxf(s, 0.f);
  __syncthreads();
  float s2 = bc2[j];
#pragma unroll 8
  for (int k = 0; k < 128; ++k) s2 = fmaf(x1[k], Wc2[k * D + j], s2);
  float v2 = fmaxf(s2, 0.f);
  red[j] = v2 * Wc3[j];
  __syncthreads();
  for (int o = 64; o > 0; o >>= 1) {
    if (j < o) red[j] += red[j + o];
    __syncthreads();
  }
  if (j == 0) out[g] = red[0] + bc3[0];
}

extern "C" void kernel_launch(void* const* d_in, const int* in_sizes, int n_in,
                              void* d_out, int out_size, void* d_ws, size_t ws_size,
                              hipStream_t stream) {
  const float* h   = (const float*)d_in[0];
  const int* src   = (const int*)d_in[1];
  const int* dst   = (const int*)d_in[2];
  const int* n2g   = (const int*)d_in[3];
  const float* W1  = (const float*)d_in[4];
  const float* b1  = (const float*)d_in[5];
  const float* W2  = (const float*)d_in[6];
  const float* b2  = (const float*)d_in[7];
  const float* Wc1 = (const float*)d_in[8];
  const float* bc1 = (const float*)d_in[9];
  const float* Wc2 = (const float*)d_in[10];
  const float* bc2 = (const float*)d_in[11];
  const float* Wc3 = (const float*)d_in[12];
  const float* bc3 = (const float*)d_in[13];
  float* out = (float*)d_out;

  char* p = (char*)d_ws;
  size_t o = 0;
  auto take = [&](size_t b) { void* q = p + o; o = (o + b + 255) & ~(size_t)255; return q; };
  int* oc    = (int*)take(NN * 4);
  int* ic    = (int*)take(NN * 4);
  int* cur   = (int*)take(NN * 4);
  float* sums = (float*)take(NG * D * 4);
  size_t zero_bytes = o;                    // zero counters + pool sums
  int* off   = (int*)take((NN + 1) * 4);
  int* bsum  = (int*)take(NB_SCAN * 4);
  float* onrm = (float*)take(NN * 4);
  float* inrm = (float*)take(NN * 4);
  int* csr   = (int*)take((size_t)NE * 4);
  float* tbuf = (float*)take((size_t)NN * D * 4);
  float* ubuf = (float*)take((size_t)NN * D * 4);
  (void)ws_size; (void)in_sizes; (void)n_in; (void)out_size;

  hipMemsetAsync(d_ws, 0, zero_bytes, stream);
  k_degree<<<(NE + 255) / 256, 256, 0, stream>>>(src, dst, oc, ic);
  k_norms<<<(NN + 255) / 256, 256, 0, stream>>>(oc, ic, onrm, inrm);
  k_scan_a<<<NB_SCAN, 256, 0, stream>>>(ic, bsum);
  k_scan_b<<<1, 128, 0, stream>>>(bsum, off);
  k_scan_c<<<NB_SCAN, 256, 0, stream>>>(ic, bsum, off);
  k_fill<<<(NE + 255) / 256, 256, 0, stream>>>(src, dst, off, cur, csr);

  // layer 1: t = (h * out_norm) @ W1 ; h1 = relu(in_norm * gather(t) + b1)
  k_matmul<<<(NN + BM - 1) / BM, 256, 0, stream>>>(h, W1, onrm, tbuf);
  k_gather<<<(NN * 64) / 256, 256, 0, stream>>>(tbuf, csr, off, inrm, b1, ubuf);
  // layer 2
  k_matmul<<<(NN + BM - 1) / BM, 256, 0, stream>>>(ubuf, W2, onrm, tbuf);
  k_gather<<<(NN * 64) / 256, 256, 0, stream>>>(tbuf, csr, off, inrm, b2, ubuf);

  k_pool_partial<<<(NN + POOL_CHUNK - 1) / POOL_CHUNK, 128, 0, stream>>>(ubuf, n2g, sums);
  k_mlp<<<NG, 128, 0, stream>>>(sums, n2g, Wc1, bc1, Wc2, bc2, Wc3, bc3, out);
}

// Round 4
// 565.413 us; speedup vs baseline: 2.0469x; 1.2236x over previous
//
#include <hip/hip_runtime.h>

#define NN 100000
#define NE 1600000
#define D 128
#define NG 64
#define BM 64
#define POOL_CHUNK 256
#define SCAN_CHUNK 1024
#define NB_SCAN ((NN + SCAN_CHUNK - 1) / SCAN_CHUNK)   // 98

// CSR-build tiling: 32 edge chunks x 13 node partitions of 8192
#define NCHUNK 32
#define CH_E (NE / NCHUNK)          // 50000 edges per chunk
#define HP 8192                     // nodes per partition (LDS-resident counters)
#define NPART 13                    // 13*8192 = 106496 >= NN
#define HSTRIDE (NPART * HP)        // padded node stride of partial hist

__device__ __forceinline__ int lower_bound_i(const int* a, int n, int key) {
  int lo = 0, hi = n;
  while (lo < hi) { int mid = (lo + hi) >> 1; if (a[mid] < key) lo = mid + 1; else hi = mid; }
  return lo;
}

// partial histograms per (chunk, partition): LDS atomics only
__global__ __launch_bounds__(256) void k_hist(
    const int* __restrict__ src, const int* __restrict__ dst,
    int* __restrict__ Hin, int* __restrict__ Hout) {
  __shared__ int hin[HP];
  __shared__ int hout[HP];
  const int c = blockIdx.x, p = blockIdx.y, t = threadIdx.x;
  const int base = p * HP;
  for (int i = t; i < HP; i += 256) { hin[i] = 0; hout[i] = 0; }
  __syncthreads();
  const int4* s4 = (const int4*)(src + c * CH_E);
  const int4* d4 = (const int4*)(dst + c * CH_E);
  const int n4 = CH_E / 4;  // 12500
  for (int i = t; i < n4; i += 256) {
    int4 s = s4[i], d = d4[i];
    if ((unsigned)(d.x - base) < HP) atomicAdd(&hin[d.x - base], 1);
    if ((unsigned)(d.y - base) < HP) atomicAdd(&hin[d.y - base], 1);
    if ((unsigned)(d.z - base) < HP) atomicAdd(&hin[d.z - base], 1);
    if ((unsigned)(d.w - base) < HP) atomicAdd(&hin[d.w - base], 1);
    if ((unsigned)(s.x - base) < HP) atomicAdd(&hout[s.x - base], 1);
    if ((unsigned)(s.y - base) < HP) atomicAdd(&hout[s.y - base], 1);
    if ((unsigned)(s.z - base) < HP) atomicAdd(&hout[s.z - base], 1);
    if ((unsigned)(s.w - base) < HP) atomicAdd(&hout[s.w - base], 1);
  }
  __syncthreads();
  size_t rb = (size_t)c * HSTRIDE + base;
  for (int i = t; i < HP; i += 256) {
    Hin[rb + i] = hin[i];
    Hout[rb + i] = hout[i];
  }
}

// reduce partials over chunks -> in-degree (for scan) + both norms
__global__ __launch_bounds__(256) void k_reduce(
    const int* __restrict__ Hin, const int* __restrict__ Hout,
    int* __restrict__ ic, float* __restrict__ onrm, float* __restrict__ inrm) {
  int n = blockIdx.x * 256 + threadIdx.x;
  if (n >= NN) return;
  int si = 0, so = 0;
#pragma unroll 8
  for (int c = 0; c < NCHUNK; ++c) {
    si += Hin[(size_t)c * HSTRIDE + n];
    so += Hout[(size_t)c * HSTRIDE + n];
  }
  ic[n] = si;
  inrm[n] = 1.0f / sqrtf((float)max(si, 1));
  onrm[n] = 1.0f / sqrtf((float)max(so, 1));
}

// phase A: per-block chunk sums (coalesced int4, shuffle reduce)
__global__ __launch_bounds__(256) void k_scan_a(const int* __restrict__ cnt,
                                                int* __restrict__ bsum) {
  int b = blockIdx.x, t = threadIdx.x;
  int idx = b * SCAN_CHUNK + t * 4;
  int4 v = make_int4(0, 0, 0, 0);
  if (idx < NN) v = *(const int4*)(cnt + idx);   // NN % 4 == 0
  int s = v.x + v.y + v.z + v.w;
#pragma unroll
  for (int o = 1; o < 64; o <<= 1) s += __shfl_xor(s, o);
  __shared__ int ws[4];
  if ((t & 63) == 0) ws[t >> 6] = s;
  __syncthreads();
  if (t == 0) bsum[b] = ws[0] + ws[1] + ws[2] + ws[3];
}

// phase B: exclusive scan of the 98 block sums (in place), set off[NN]
__global__ void k_scan_b(int* __restrict__ bsum, int* __restrict__ off) {
  __shared__ int s[128];
  int t = threadIdx.x;
  int v = (t < NB_SCAN) ? bsum[t] : 0;
  s[t] = v;
  __syncthreads();
  for (int o = 1; o < 128; o <<= 1) {
    int u = (t >= o) ? s[t - o] : 0;
    __syncthreads();
    s[t] += u;
    __syncthreads();
  }
  if (t < NB_SCAN) bsum[t] = s[t] - v;  // exclusive prefix
  if (t == 0) off[NN] = NE;
}

// phase C: intra-block exclusive scan + block prefix -> off[]
__global__ __launch_bounds__(256) void k_scan_c(const int* __restrict__ cnt,
                                                const int* __restrict__ bsum,
                                                int* __restrict__ off) {
  int b = blockIdx.x, t = threadIdx.x;
  int idx = b * SCAN_CHUNK + t * 4;
  int4 v = make_int4(0, 0, 0, 0);
  if (idx < NN) v = *(const int4*)(cnt + idx);
  int lsum = v.x + v.y + v.z + v.w;
  int lane = t & 63, wid = t >> 6;
  int x = lsum;
#pragma unroll
  for (int o = 1; o < 64; o <<= 1) {
    int u = __shfl_up(x, o);
    if (lane >= o) x += u;
  }
  __shared__ int wsum[4];
  if (lane == 63) wsum[wid] = x;
  __syncthreads();
  int woff = 0;
  for (int i = 0; i < 4; ++i) woff += (i < wid) ? wsum[i] : 0;
  int excl = x - lsum + woff + bsum[b];
  if (idx < NN) {
    int4 o4;
    o4.x = excl;
    o4.y = excl + v.x;
    o4.z = o4.y + v.y;
    o4.w = o4.z + v.z;
    *(int4*)(off + idx) = o4;
  }
}

// column-wise running offsets: Hin[c][n] <- off[n] + sum_{c'<c} Hin[c'][n]
__global__ __launch_bounds__(256) void k_start(int* __restrict__ Hin,
                                               const int* __restrict__ off) {
  int n = blockIdx.x * 256 + threadIdx.x;
  if (n >= NN) return;
  int run = off[n];
#pragma unroll 8
  for (int c = 0; c < NCHUNK; ++c) {
    size_t idx = (size_t)c * HSTRIDE + n;
    int v = Hin[idx];
    Hin[idx] = run;
    run += v;
  }
}

// fill CSR: LDS cursors (absolute positions), plain global stores
__global__ __launch_bounds__(256) void k_fill2(
    const int* __restrict__ src, const int* __restrict__ dst,
    const int* __restrict__ Hin, int* __restrict__ csr) {
  __shared__ int cur[HP];
  const int c = blockIdx.x, p = blockIdx.y, t = threadIdx.x;
  const int base = p * HP;
  size_t rb = (size_t)c * HSTRIDE + base;
  for (int i = t; i < HP; i += 256) cur[i] = Hin[rb + i];
  __syncthreads();
  const int4* s4 = (const int4*)(src + c * CH_E);
  const int4* d4 = (const int4*)(dst + c * CH_E);
  const int n4 = CH_E / 4;
  for (int i = t; i < n4; i += 256) {
    int4 s = s4[i], d = d4[i];
    if ((unsigned)(d.x - base) < HP) { int pos = atomicAdd(&cur[d.x - base], 1); csr[pos] = s.x; }
    if ((unsigned)(d.y - base) < HP) { int pos = atomicAdd(&cur[d.y - base], 1); csr[pos] = s.y; }
    if ((unsigned)(d.z - base) < HP) { int pos = atomicAdd(&cur[d.z - base], 1); csr[pos] = s.z; }
    if ((unsigned)(d.w - base) < HP) { int pos = atomicAdd(&cur[d.w - base], 1); csr[pos] = s.w; }
  }
}

// C[r,:] = rs[r] * (A[r,:] @ W)   (fp32 vector, W staged in LDS)
__global__ __launch_bounds__(256) void k_matmul(
    const float* __restrict__ A, const float* __restrict__ W,
    const float* __restrict__ rs, float* __restrict__ C) {
  __shared__ float As[BM][132];     // pad 132: a-reads spread over banks
  __shared__ float Ws[128 * 128];
  const int tid = threadIdx.x;
  const int row0 = blockIdx.x * BM;
  {
    const float4* W4 = (const float4*)W;
    float4* Ws4 = (float4*)Ws;
#pragma unroll
    for (int i = 0; i < 16; ++i) Ws4[tid + i * 256] = W4[tid + i * 256];
  }
#pragma unroll
  for (int i = 0; i < 8; ++i) {
    int idx = tid + i * 256;        // 0..2047 float4 slots (64 rows x 32)
    int r = idx >> 5;
    int c4 = idx & 31;
    int grow = row0 + r;
    float4 v = make_float4(0.f, 0.f, 0.f, 0.f);
    if (grow < NN) {
      v = *(const float4*)(A + (size_t)grow * D + c4 * 4);
      float sc = rs[grow];
      v.x *= sc; v.y *= sc; v.z *= sc; v.w *= sc;
    }
    *(float4*)&As[r][c4 * 4] = v;
  }
  __syncthreads();
  const int tx = tid & 15, ty = tid >> 4;
  const int r0 = ty * 4, c0 = tx * 4;
  float acc[4][8];
#pragma unroll
  for (int i = 0; i < 4; ++i)
#pragma unroll
    for (int j = 0; j < 8; ++j) acc[i][j] = 0.f;
#pragma unroll 8
  for (int k = 0; k < 128; ++k) {
    float4 w0 = *(const float4*)&Ws[k * 128 + c0];        // cols c0..c0+3
    float4 w1 = *(const float4*)&Ws[k * 128 + c0 + 64];   // cols 64+c0..
    float av[4];
    av[0] = As[r0 + 0][k]; av[1] = As[r0 + 1][k];
    av[2] = As[r0 + 2][k]; av[3] = As[r0 + 3][k];
#pragma unroll
    for (int i = 0; i < 4; ++i) {
      acc[i][0] = fmaf(av[i], w0.x, acc[i][0]);
      acc[i][1] = fmaf(av[i], w0.y, acc[i][1]);
      acc[i][2] = fmaf(av[i], w0.z, acc[i][2]);
      acc[i][3] = fmaf(av[i], w0.w, acc[i][3]);
      acc[i][4] = fmaf(av[i], w1.x, acc[i][4]);
      acc[i][5] = fmaf(av[i], w1.y, acc[i][5]);
      acc[i][6] = fmaf(av[i], w1.z, acc[i][6]);
      acc[i][7] = fmaf(av[i], w1.w, acc[i][7]);
    }
  }
#pragma unroll
  for (int i = 0; i < 4; ++i) {
    int row = row0 + r0 + i;
    if (row < NN) {
      float4 o0 = make_float4(acc[i][0], acc[i][1], acc[i][2], acc[i][3]);
      float4 o1 = make_float4(acc[i][4], acc[i][5], acc[i][6], acc[i][7]);
      *(float4*)(C + (size_t)row * D + c0) = o0;
      *(float4*)(C + (size_t)row * D + 64 + c0) = o1;
    }
  }
}

// out[d,:] = relu(in_norm[d] * sum_{s in CSR(d)} t[s,:] + bias)
// one wave per dst node; lane holds 2 feature cols (float2)
__global__ __launch_bounds__(256) void k_gather(
    const float* __restrict__ t, const int* __restrict__ csr,
    const int* __restrict__ off, const float* __restrict__ inn,
    const float* __restrict__ bias, float* __restrict__ outp) {
  int w = (blockIdx.x * blockDim.x + threadIdx.x) >> 6;
  int lane = threadIdx.x & 63;
  if (w >= NN) return;
  int lo = off[w], hi = off[w + 1];
  const float* tp = t + 2 * lane;
  float ax = 0.f, ay = 0.f;
  int e = lo;
  for (; e + 3 < hi; e += 4) {
    int s0 = csr[e], s1 = csr[e + 1], s2 = csr[e + 2], s3 = csr[e + 3];
    float2 v0 = *(const float2*)(tp + (size_t)s0 * D);
    float2 v1 = *(const float2*)(tp + (size_t)s1 * D);
    float2 v2 = *(const float2*)(tp + (size_t)s2 * D);
    float2 v3 = *(const float2*)(tp + (size_t)s3 * D);
    ax += v0.x + v1.x + v2.x + v3.x;
    ay += v0.y + v1.y + v2.y + v3.y;
  }
  for (; e < hi; ++e) {
    int s0 = csr[e];
    float2 v0 = *(const float2*)(tp + (size_t)s0 * D);
    ax += v0.x; ay += v0.y;
  }
  float nm = inn[w];
  float2 b = *(const float2*)(bias + 2 * lane);
  float2 o;
  o.x = fmaxf(fmaf(nm, ax, b.x), 0.f);
  o.y = fmaxf(fmaf(nm, ay, b.y), 0.f);
  *(float2*)(outp + (size_t)w * D + 2 * lane) = o;
}

// parallel pool partial sums
__global__ __launch_bounds__(128) void k_pool_partial(
    const float* __restrict__ h2, const int* __restrict__ n2g,
    float* __restrict__ sums) {
  int c = threadIdx.x;
  int n0 = blockIdx.x * POOL_CHUNK;
  int n1 = min(n0 + POOL_CHUNK, NN);
  if (n0 >= NN) return;
  int gcur = n2g[n0];
  float acc = 0.f;
  for (int n = n0; n < n1; ++n) {
    int g = n2g[n];
    if (g != gcur) {
      atomicAdd(&sums[gcur * D + c], acc);
      acc = 0.f;
      gcur = g;
    }
    acc += h2[(size_t)n * D + c];
  }
  atomicAdd(&sums[gcur * D + c], acc);
}

// 3-layer MLP head; one block per graph, 128 threads. Divides sums by count.
__global__ void k_mlp(const float* __restrict__ sums, const int* __restrict__ n2g,
                      const float* __restrict__ Wc1, const float* __restrict__ bc1,
                      const float* __restrict__ Wc2, const float* __restrict__ bc2,
                      const float* __restrict__ Wc3, const float* __restrict__ bc3,
                      float* __restrict__ out) {
  __shared__ float xin[128];
  __shared__ float x1[128];
  __shared__ float red[128];
  int g = blockIdx.x, j = threadIdx.x;
  int start = lower_bound_i(n2g, NN, g);
  int end = lower_bound_i(n2g, NN, g + 1);
  float inv = 1.0f / (float)max(end - start, 1);
  xin[j] = sums[g * D + j] * inv;
  __syncthreads();
  float s = bc1[j];
#pragma unroll 8
  for (int k = 0; k < 128; ++k) s = fmaf(xin[k], Wc1[k * D + j], s);
  x1[j] = fmaxf(s, 0.f);
  __syncthreads();
  float s2 = bc2[j];
#pragma unroll 8
  for (int k = 0; k < 128; ++k) s2 = fmaf(x1[k], Wc2[k * D + j], s2);
  float v2 = fmaxf(s2, 0.f);
  red[j] = v2 * Wc3[j];
  __syncthreads();
  for (int o = 64; o > 0; o >>= 1) {
    if (j < o) red[j] += red[j + o];
    __syncthreads();
  }
  if (j == 0) out[g] = red[0] + bc3[0];
}

extern "C" void kernel_launch(void* const* d_in, const int* in_sizes, int n_in,
                              void* d_out, int out_size, void* d_ws, size_t ws_size,
                              hipStream_t stream) {
  const float* h   = (const float*)d_in[0];
  const int* src   = (const int*)d_in[1];
  const int* dst   = (const int*)d_in[2];
  const int* n2g   = (const int*)d_in[3];
  const float* W1  = (const float*)d_in[4];
  const float* b1  = (const float*)d_in[5];
  const float* W2  = (const float*)d_in[6];
  const float* b2  = (const float*)d_in[7];
  const float* Wc1 = (const float*)d_in[8];
  const float* bc1 = (const float*)d_in[9];
  const float* Wc2 = (const float*)d_in[10];
  const float* bc2 = (const float*)d_in[11];
  const float* Wc3 = (const float*)d_in[12];
  const float* bc3 = (const float*)d_in[13];
  float* out = (float*)d_out;

  char* p = (char*)d_ws;
  size_t o = 0;
  auto take = [&](size_t b) { void* q = p + o; o = (o + b + 255) & ~(size_t)255; return q; };
  float* sums = (float*)take(NG * D * 4);
  size_t zero_bytes = o;                    // zero pool sums only
  int* off   = (int*)take((NN + 1) * 4);
  int* bsum  = (int*)take(NB_SCAN * 4);
  int* ic    = (int*)take(NN * 4);
  float* onrm = (float*)take(NN * 4);
  float* inrm = (float*)take(NN * 4);
  int* csr   = (int*)take((size_t)NE * 4);
  float* tbuf = (float*)take((size_t)NN * D * 4);
  float* ubuf = (float*)take((size_t)NN * D * 4);
  (void)ws_size; (void)in_sizes; (void)n_in; (void)out_size;

  // CSR-build partial histograms alias tbuf (build finishes before matmul)
  int* Hin  = (int*)tbuf;                       // [NCHUNK][HSTRIDE]
  int* Hout = Hin + (size_t)NCHUNK * HSTRIDE;   // 13.6 MB each, < 51 MB tbuf

  hipMemsetAsync(d_ws, 0, zero_bytes, stream);
  dim3 hgrid(NCHUNK, NPART);
  k_hist<<<hgrid, 256, 0, stream>>>(src, dst, Hin, Hout);
  k_reduce<<<(NN + 255) / 256, 256, 0, stream>>>(Hin, Hout, ic, onrm, inrm);
  k_scan_a<<<NB_SCAN, 256, 0, stream>>>(ic, bsum);
  k_scan_b<<<1, 128, 0, stream>>>(bsum, off);
  k_scan_c<<<NB_SCAN, 256, 0, stream>>>(ic, bsum, off);
  k_start<<<(NN + 255) / 256, 256, 0, stream>>>(Hin, off);
  k_fill2<<<hgrid, 256, 0, stream>>>(src, dst, Hin, csr);

  // layer 1: t = (h * out_norm) @ W1 ; h1 = relu(in_norm * gather(t) + b1)
  k_matmul<<<(NN + BM - 1) / BM, 256, 0, stream>>>(h, W1, onrm, tbuf);
  k_gather<<<(NN * 64) / 256, 256, 0, stream>>>(tbuf, csr, off, inrm, b1, ubuf);
  // layer 2
  k_matmul<<<(NN + BM - 1) / BM, 256, 0, stream>>>(ubuf, W2, onrm, tbuf);
  k_gather<<<(NN * 64) / 256, 256, 0, stream>>>(tbuf, csr, off, inrm, b2, ubuf);

  k_pool_partial<<<(NN + POOL_CHUNK - 1) / POOL_CHUNK, 128, 0, stream>>>(ubuf, n2g, sums);
  k_mlp<<<NG, 128, 0, stream>>>(sums, n2g, Wc1, bc1, Wc2, bc2, Wc3, bc3, out);
}

// Round 5
// 483.927 us; speedup vs baseline: 2.3916x; 1.1684x over previous
//
#include <hip/hip_runtime.h>
#include <hip/hip_fp16.h>

#define NN 100000
#define NE 1600000
#define D 128
#define NG 64
#define BM 64
#define POOL_CHUNK 256
#define SCAN_CHUNK 1024
#define NB_SCAN ((NN + SCAN_CHUNK - 1) / SCAN_CHUNK)   // 98

// CSR-build tiling: 32 edge chunks x 13 node partitions of 8192
#define NCHUNK 32
#define CH_E (NE / NCHUNK)          // 50000 edges per chunk
#define HP 8192                     // nodes per partition (LDS-resident counters)
#define NPART 13                    // 13*8192 = 106496 >= NN
#define HSTRIDE (NPART * HP)        // padded node stride of partial hist

__device__ __forceinline__ int lower_bound_i(const int* a, int n, int key) {
  int lo = 0, hi = n;
  while (lo < hi) { int mid = (lo + hi) >> 1; if (a[mid] < key) lo = mid + 1; else hi = mid; }
  return lo;
}

// partial histograms per (chunk, partition): LDS atomics only
__global__ __launch_bounds__(256) void k_hist(
    const int* __restrict__ src, const int* __restrict__ dst,
    int* __restrict__ Hin, int* __restrict__ Hout) {
  __shared__ int hin[HP];
  __shared__ int hout[HP];
  const int c = blockIdx.x, p = blockIdx.y, t = threadIdx.x;
  const int base = p * HP;
  for (int i = t; i < HP; i += 256) { hin[i] = 0; hout[i] = 0; }
  __syncthreads();
  const int4* s4 = (const int4*)(src + c * CH_E);
  const int4* d4 = (const int4*)(dst + c * CH_E);
  const int n4 = CH_E / 4;  // 12500
  for (int i = t; i < n4; i += 256) {
    int4 s = s4[i], d = d4[i];
    if ((unsigned)(d.x - base) < HP) atomicAdd(&hin[d.x - base], 1);
    if ((unsigned)(d.y - base) < HP) atomicAdd(&hin[d.y - base], 1);
    if ((unsigned)(d.z - base) < HP) atomicAdd(&hin[d.z - base], 1);
    if ((unsigned)(d.w - base) < HP) atomicAdd(&hin[d.w - base], 1);
    if ((unsigned)(s.x - base) < HP) atomicAdd(&hout[s.x - base], 1);
    if ((unsigned)(s.y - base) < HP) atomicAdd(&hout[s.y - base], 1);
    if ((unsigned)(s.z - base) < HP) atomicAdd(&hout[s.z - base], 1);
    if ((unsigned)(s.w - base) < HP) atomicAdd(&hout[s.w - base], 1);
  }
  __syncthreads();
  size_t rb = (size_t)c * HSTRIDE + base;
  for (int i = t; i < HP; i += 256) {
    Hin[rb + i] = hin[i];
    Hout[rb + i] = hout[i];
  }
}

// reduce partials over chunks -> in-degree (for scan) + both norms
__global__ __launch_bounds__(256) void k_reduce(
    const int* __restrict__ Hin, const int* __restrict__ Hout,
    int* __restrict__ ic, float* __restrict__ onrm, float* __restrict__ inrm) {
  int n = blockIdx.x * 256 + threadIdx.x;
  if (n >= NN) return;
  int si = 0, so = 0;
#pragma unroll 8
  for (int c = 0; c < NCHUNK; ++c) {
    si += Hin[(size_t)c * HSTRIDE + n];
    so += Hout[(size_t)c * HSTRIDE + n];
  }
  ic[n] = si;
  inrm[n] = 1.0f / sqrtf((float)max(si, 1));
  onrm[n] = 1.0f / sqrtf((float)max(so, 1));
}

// phase A: per-block chunk sums (coalesced int4, shuffle reduce)
__global__ __launch_bounds__(256) void k_scan_a(const int* __restrict__ cnt,
                                                int* __restrict__ bsum) {
  int b = blockIdx.x, t = threadIdx.x;
  int idx = b * SCAN_CHUNK + t * 4;
  int4 v = make_int4(0, 0, 0, 0);
  if (idx < NN) v = *(const int4*)(cnt + idx);   // NN % 4 == 0
  int s = v.x + v.y + v.z + v.w;
#pragma unroll
  for (int o = 1; o < 64; o <<= 1) s += __shfl_xor(s, o);
  __shared__ int ws[4];
  if ((t & 63) == 0) ws[t >> 6] = s;
  __syncthreads();
  if (t == 0) bsum[b] = ws[0] + ws[1] + ws[2] + ws[3];
}

// phase B: exclusive scan of the 98 block sums (in place), set off[NN]
__global__ void k_scan_b(int* __restrict__ bsum, int* __restrict__ off) {
  __shared__ int s[128];
  int t = threadIdx.x;
  int v = (t < NB_SCAN) ? bsum[t] : 0;
  s[t] = v;
  __syncthreads();
  for (int o = 1; o < 128; o <<= 1) {
    int u = (t >= o) ? s[t - o] : 0;
    __syncthreads();
    s[t] += u;
    __syncthreads();
  }
  if (t < NB_SCAN) bsum[t] = s[t] - v;  // exclusive prefix
  if (t == 0) off[NN] = NE;
}

// phase C: intra-block exclusive scan + block prefix -> off[]
__global__ __launch_bounds__(256) void k_scan_c(const int* __restrict__ cnt,
                                                const int* __restrict__ bsum,
                                                int* __restrict__ off) {
  int b = blockIdx.x, t = threadIdx.x;
  int idx = b * SCAN_CHUNK + t * 4;
  int4 v = make_int4(0, 0, 0, 0);
  if (idx < NN) v = *(const int4*)(cnt + idx);
  int lsum = v.x + v.y + v.z + v.w;
  int lane = t & 63, wid = t >> 6;
  int x = lsum;
#pragma unroll
  for (int o = 1; o < 64; o <<= 1) {
    int u = __shfl_up(x, o);
    if (lane >= o) x += u;
  }
  __shared__ int wsum[4];
  if (lane == 63) wsum[wid] = x;
  __syncthreads();
  int woff = 0;
  for (int i = 0; i < 4; ++i) woff += (i < wid) ? wsum[i] : 0;
  int excl = x - lsum + woff + bsum[b];
  if (idx < NN) {
    int4 o4;
    o4.x = excl;
    o4.y = excl + v.x;
    o4.z = o4.y + v.y;
    o4.w = o4.z + v.z;
    *(int4*)(off + idx) = o4;
  }
}

// column-wise running offsets: Hin[c][n] <- off[n] + sum_{c'<c} Hin[c'][n]
__global__ __launch_bounds__(256) void k_start(int* __restrict__ Hin,
                                               const int* __restrict__ off) {
  int n = blockIdx.x * 256 + threadIdx.x;
  if (n >= NN) return;
  int run = off[n];
#pragma unroll 8
  for (int c = 0; c < NCHUNK; ++c) {
    size_t idx = (size_t)c * HSTRIDE + n;
    int v = Hin[idx];
    Hin[idx] = run;
    run += v;
  }
}

// fill CSR: LDS cursors (absolute positions), plain global stores
__global__ __launch_bounds__(256) void k_fill2(
    const int* __restrict__ src, const int* __restrict__ dst,
    const int* __restrict__ Hin, int* __restrict__ csr) {
  __shared__ int cur[HP];
  const int c = blockIdx.x, p = blockIdx.y, t = threadIdx.x;
  const int base = p * HP;
  size_t rb = (size_t)c * HSTRIDE + base;
  for (int i = t; i < HP; i += 256) cur[i] = Hin[rb + i];
  __syncthreads();
  const int4* s4 = (const int4*)(src + c * CH_E);
  const int4* d4 = (const int4*)(dst + c * CH_E);
  const int n4 = CH_E / 4;
  for (int i = t; i < n4; i += 256) {
    int4 s = s4[i], d = d4[i];
    if ((unsigned)(d.x - base) < HP) { int pos = atomicAdd(&cur[d.x - base], 1); csr[pos] = s.x; }
    if ((unsigned)(d.y - base) < HP) { int pos = atomicAdd(&cur[d.y - base], 1); csr[pos] = s.y; }
    if ((unsigned)(d.z - base) < HP) { int pos = atomicAdd(&cur[d.z - base], 1); csr[pos] = s.z; }
    if ((unsigned)(d.w - base) < HP) { int pos = atomicAdd(&cur[d.w - base], 1); csr[pos] = s.w; }
  }
}

// C[r,:] = fp16( rs[r] * (A[r,:] @ W) )   (fp32 math, fp16 store)
__global__ __launch_bounds__(256) void k_matmul(
    const float* __restrict__ A, const float* __restrict__ W,
    const float* __restrict__ rs, __half* __restrict__ C) {
  __shared__ float As[BM][132];     // pad 132: a-reads spread over banks
  __shared__ float Ws[128 * 128];
  const int tid = threadIdx.x;
  const int row0 = blockIdx.x * BM;
  {
    const float4* W4 = (const float4*)W;
    float4* Ws4 = (float4*)Ws;
#pragma unroll
    for (int i = 0; i < 16; ++i) Ws4[tid + i * 256] = W4[tid + i * 256];
  }
#pragma unroll
  for (int i = 0; i < 8; ++i) {
    int idx = tid + i * 256;        // 0..2047 float4 slots (64 rows x 32)
    int r = idx >> 5;
    int c4 = idx & 31;
    int grow = row0 + r;
    float4 v = make_float4(0.f, 0.f, 0.f, 0.f);
    if (grow < NN) {
      v = *(const float4*)(A + (size_t)grow * D + c4 * 4);
      float sc = rs[grow];
      v.x *= sc; v.y *= sc; v.z *= sc; v.w *= sc;
    }
    *(float4*)&As[r][c4 * 4] = v;
  }
  __syncthreads();
  const int tx = tid & 15, ty = tid >> 4;
  const int r0 = ty * 4, c0 = tx * 4;
  float acc[4][8];
#pragma unroll
  for (int i = 0; i < 4; ++i)
#pragma unroll
    for (int j = 0; j < 8; ++j) acc[i][j] = 0.f;
#pragma unroll 8
  for (int k = 0; k < 128; ++k) {
    float4 w0 = *(const float4*)&Ws[k * 128 + c0];        // cols c0..c0+3
    float4 w1 = *(const float4*)&Ws[k * 128 + c0 + 64];   // cols 64+c0..
    float av[4];
    av[0] = As[r0 + 0][k]; av[1] = As[r0 + 1][k];
    av[2] = As[r0 + 2][k]; av[3] = As[r0 + 3][k];
#pragma unroll
    for (int i = 0; i < 4; ++i) {
      acc[i][0] = fmaf(av[i], w0.x, acc[i][0]);
      acc[i][1] = fmaf(av[i], w0.y, acc[i][1]);
      acc[i][2] = fmaf(av[i], w0.z, acc[i][2]);
      acc[i][3] = fmaf(av[i], w0.w, acc[i][3]);
      acc[i][4] = fmaf(av[i], w1.x, acc[i][4]);
      acc[i][5] = fmaf(av[i], w1.y, acc[i][5]);
      acc[i][6] = fmaf(av[i], w1.z, acc[i][6]);
      acc[i][7] = fmaf(av[i], w1.w, acc[i][7]);
    }
  }
#pragma unroll
  for (int i = 0; i < 4; ++i) {
    int row = row0 + r0 + i;
    if (row < NN) {
      ushort4 p0, p1;
      p0.x = __half_as_ushort(__float2half_rn(acc[i][0]));
      p0.y = __half_as_ushort(__float2half_rn(acc[i][1]));
      p0.z = __half_as_ushort(__float2half_rn(acc[i][2]));
      p0.w = __half_as_ushort(__float2half_rn(acc[i][3]));
      p1.x = __half_as_ushort(__float2half_rn(acc[i][4]));
      p1.y = __half_as_ushort(__float2half_rn(acc[i][5]));
      p1.z = __half_as_ushort(__float2half_rn(acc[i][6]));
      p1.w = __half_as_ushort(__float2half_rn(acc[i][7]));
      *(ushort4*)(C + (size_t)row * D + c0) = p0;        // 8B packed, coalesced
      *(ushort4*)(C + (size_t)row * D + 64 + c0) = p1;
    }
  }
}

// out[d,:] = relu(in_norm[d] * sum_{s in CSR(d)} t[s,:] + bias)
// one wave per dst node; lane holds 2 feature cols (one half2 per row)
__global__ __launch_bounds__(256) void k_gather(
    const __half* __restrict__ t, const int* __restrict__ csr,
    const int* __restrict__ off, const float* __restrict__ inn,
    const float* __restrict__ bias, float* __restrict__ outp) {
  int w = (blockIdx.x * blockDim.x + threadIdx.x) >> 6;
  int lane = threadIdx.x & 63;
  if (w >= NN) return;
  int lo = off[w], hi = off[w + 1];
  const __half2* tp = (const __half2*)t + lane;   // row stride = 64 half2
  float ax = 0.f, ay = 0.f;
  int e = lo;
  for (; e + 3 < hi; e += 4) {
    int s0 = csr[e], s1 = csr[e + 1], s2 = csr[e + 2], s3 = csr[e + 3];
    float2 v0 = __half22float2(tp[(size_t)s0 * 64]);
    float2 v1 = __half22float2(tp[(size_t)s1 * 64]);
    float2 v2 = __half22float2(tp[(size_t)s2 * 64]);
    float2 v3 = __half22float2(tp[(size_t)s3 * 64]);
    ax += v0.x + v1.x + v2.x + v3.x;
    ay += v0.y + v1.y + v2.y + v3.y;
  }
  for (; e < hi; ++e) {
    float2 v0 = __half22float2(tp[(size_t)csr[e] * 64]);
    ax += v0.x; ay += v0.y;
  }
  float nm = inn[w];
  float2 b = *(const float2*)(bias + 2 * lane);
  float2 o;
  o.x = fmaxf(fmaf(nm, ax, b.x), 0.f);
  o.y = fmaxf(fmaf(nm, ay, b.y), 0.f);
  *(float2*)(outp + (size_t)w * D + 2 * lane) = o;
}

// parallel pool partial sums
__global__ __launch_bounds__(128) void k_pool_partial(
    const float* __restrict__ h2, const int* __restrict__ n2g,
    float* __restrict__ sums) {
  int c = threadIdx.x;
  int n0 = blockIdx.x * POOL_CHUNK;
  int n1 = min(n0 + POOL_CHUNK, NN);
  if (n0 >= NN) return;
  int gcur = n2g[n0];
  float acc = 0.f;
  for (int n = n0; n < n1; ++n) {
    int g = n2g[n];
    if (g != gcur) {
      atomicAdd(&sums[gcur * D + c], acc);
      acc = 0.f;
      gcur = g;
    }
    acc += h2[(size_t)n * D + c];
  }
  atomicAdd(&sums[gcur * D + c], acc);
}

// 3-layer MLP head; one block per graph, 128 threads. Divides sums by count.
__global__ void k_mlp(const float* __restrict__ sums, const int* __restrict__ n2g,
                      const float* __restrict__ Wc1, const float* __restrict__ bc1,
                      const float* __restrict__ Wc2, const float* __restrict__ bc2,
                      const float* __restrict__ Wc3, const float* __restrict__ bc3,
                      float* __restrict__ out) {
  __shared__ float xin[128];
  __shared__ float x1[128];
  __shared__ float red[128];
  int g = blockIdx.x, j = threadIdx.x;
  int start = lower_bound_i(n2g, NN, g);
  int end = lower_bound_i(n2g, NN, g + 1);
  float inv = 1.0f / (float)max(end - start, 1);
  xin[j] = sums[g * D + j] * inv;
  __syncthreads();
  float s = bc1[j];
#pragma unroll 8
  for (int k = 0; k < 128; ++k) s = fmaf(xin[k], Wc1[k * D + j], s);
  x1[j] = fmaxf(s, 0.f);
  __syncthreads();
  float s2 = bc2[j];
#pragma unroll 8
  for (int k = 0; k < 128; ++k) s2 = fmaf(x1[k], Wc2[k * D + j], s2);
  float v2 = fmaxf(s2, 0.f);
  red[j] = v2 * Wc3[j];
  __syncthreads();
  for (int o = 64; o > 0; o >>= 1) {
    if (j < o) red[j] += red[j + o];
    __syncthreads();
  }
  if (j == 0) out[g] = red[0] + bc3[0];
}

extern "C" void kernel_launch(void* const* d_in, const int* in_sizes, int n_in,
                              void* d_out, int out_size, void* d_ws, size_t ws_size,
                              hipStream_t stream) {
  const float* h   = (const float*)d_in[0];
  const int* src   = (const int*)d_in[1];
  const int* dst   = (const int*)d_in[2];
  const int* n2g   = (const int*)d_in[3];
  const float* W1  = (const float*)d_in[4];
  const float* b1  = (const float*)d_in[5];
  const float* W2  = (const float*)d_in[6];
  const float* b2  = (const float*)d_in[7];
  const float* Wc1 = (const float*)d_in[8];
  const float* bc1 = (const float*)d_in[9];
  const float* Wc2 = (const float*)d_in[10];
  const float* bc2 = (const float*)d_in[11];
  const float* Wc3 = (const float*)d_in[12];
  const float* bc3 = (const float*)d_in[13];
  float* out = (float*)d_out;

  char* p = (char*)d_ws;
  size_t o = 0;
  auto take = [&](size_t b) { void* q = p + o; o = (o + b + 255) & ~(size_t)255; return q; };
  float* sums = (float*)take(NG * D * 4);
  size_t zero_bytes = o;                    // zero pool sums only
  int* off   = (int*)take((NN + 1) * 4);
  int* bsum  = (int*)take(NB_SCAN * 4);
  int* ic    = (int*)take(NN * 4);
  float* onrm = (float*)take(NN * 4);
  float* inrm = (float*)take(NN * 4);
  int* csr   = (int*)take((size_t)NE * 4);
  __half* tbuf = (__half*)take((size_t)NN * D * 2);   // fp16 staging (25.6 MB)
  float* ubuf = (float*)take((size_t)NN * D * 4);
  (void)ws_size; (void)in_sizes; (void)n_in; (void)out_size;

  // CSR-build partial histograms alias the big feature buffers
  // (build completes before the first matmul writes tbuf/ubuf)
  int* Hin  = (int*)tbuf;   // 13.6 MB <= 25.6 MB
  int* Hout = (int*)ubuf;   // 13.6 MB <= 51.2 MB

  hipMemsetAsync(d_ws, 0, zero_bytes, stream);
  dim3 hgrid(NCHUNK, NPART);
  k_hist<<<hgrid, 256, 0, stream>>>(src, dst, Hin, Hout);
  k_reduce<<<(NN + 255) / 256, 256, 0, stream>>>(Hin, Hout, ic, onrm, inrm);
  k_scan_a<<<NB_SCAN, 256, 0, stream>>>(ic, bsum);
  k_scan_b<<<1, 128, 0, stream>>>(bsum, off);
  k_scan_c<<<NB_SCAN, 256, 0, stream>>>(ic, bsum, off);
  k_start<<<(NN + 255) / 256, 256, 0, stream>>>(Hin, off);
  k_fill2<<<hgrid, 256, 0, stream>>>(src, dst, Hin, csr);

  // layer 1: t = fp16((h * out_norm) @ W1) ; h1 = relu(in_norm * gather(t) + b1)
  k_matmul<<<(NN + BM - 1) / BM, 256, 0, stream>>>(h, W1, onrm, tbuf);
  k_gather<<<(NN * 64) / 256, 256, 0, stream>>>(tbuf, csr, off, inrm, b1, ubuf);
  // layer 2
  k_matmul<<<(NN + BM - 1) / BM, 256, 0, stream>>>(ubuf, W2, onrm, tbuf);
  k_gather<<<(NN * 64) / 256, 256, 0, stream>>>(tbuf, csr, off, inrm, b2, ubuf);

  k_pool_partial<<<(NN + POOL_CHUNK - 1) / POOL_CHUNK, 128, 0, stream>>>(ubuf, n2g, sums);
  k_mlp<<<NG, 128, 0, stream>>>(sums, n2g, Wc1, bc1, Wc2, bc2, Wc3, bc3, out);
}

// Round 6
// 441.613 us; speedup vs baseline: 2.6207x; 1.0958x over previous
//
#include <hip/hip_runtime.h>
#include <hip/hip_fp16.h>

#define NN 100000
#define NE 1600000
#define D 128
#define NG 64
#define BM 64
#define POOL_CHUNK 256
#define SCAN_CHUNK 1024
#define NB_SCAN ((NN + SCAN_CHUNK - 1) / SCAN_CHUNK)   // 98

// CSR-build tiling: 64 edge chunks x 7 node partitions of 16384
// packed counters: low 16 bits = in-degree (dst), high 16 = out-degree (src)
#define NCHUNK 64
#define CH_E (NE / NCHUNK)          // 25000 edges per chunk
#define HP 16384                    // nodes per partition (64 KB LDS counters)
#define NPART 7                     // 7*16384 = 114688 >= NN
#define HSTRIDE (NPART * HP)

__device__ __forceinline__ int lower_bound_i(const int* a, int n, int key) {
  int lo = 0, hi = n;
  while (lo < hi) { int mid = (lo + hi) >> 1; if (a[mid] < key) lo = mid + 1; else hi = mid; }
  return lo;
}

// partial packed histograms per (chunk, partition): LDS atomics only
__global__ __launch_bounds__(256) void k_hist(
    const int* __restrict__ src, const int* __restrict__ dst,
    int* __restrict__ H) {
  __shared__ int pk[HP];
  const int c = blockIdx.x, p = blockIdx.y, t = threadIdx.x;
  const int base = p * HP;
  for (int i = t; i < HP; i += 256) pk[i] = 0;
  __syncthreads();
  const int4* s4 = (const int4*)(src + c * CH_E);
  const int4* d4 = (const int4*)(dst + c * CH_E);
  const int n4 = CH_E / 4;  // 6250
  for (int i = t; i < n4; i += 256) {
    int4 s = s4[i], d = d4[i];
    if ((unsigned)(d.x - base) < HP) atomicAdd(&pk[d.x - base], 1);
    if ((unsigned)(d.y - base) < HP) atomicAdd(&pk[d.y - base], 1);
    if ((unsigned)(d.z - base) < HP) atomicAdd(&pk[d.z - base], 1);
    if ((unsigned)(d.w - base) < HP) atomicAdd(&pk[d.w - base], 1);
    if ((unsigned)(s.x - base) < HP) atomicAdd(&pk[s.x - base], 65536);
    if ((unsigned)(s.y - base) < HP) atomicAdd(&pk[s.y - base], 65536);
    if ((unsigned)(s.z - base) < HP) atomicAdd(&pk[s.z - base], 65536);
    if ((unsigned)(s.w - base) < HP) atomicAdd(&pk[s.w - base], 65536);
  }
  __syncthreads();
  size_t rb = (size_t)c * HSTRIDE + base;
  for (int i = t; i < HP; i += 256) H[rb + i] = pk[i];
}

// reduce packed partials over chunks -> in-degree (for scan) + both norms
__global__ __launch_bounds__(256) void k_reduce(
    const int* __restrict__ H,
    int* __restrict__ ic, float* __restrict__ onrm, float* __restrict__ inrm) {
  int n = blockIdx.x * 256 + threadIdx.x;
  if (n >= NN) return;
  int si = 0, so = 0;
#pragma unroll 8
  for (int c = 0; c < NCHUNK; ++c) {
    unsigned v = (unsigned)H[(size_t)c * HSTRIDE + n];
    si += (int)(v & 0xffffu);
    so += (int)(v >> 16);
  }
  ic[n] = si;
  inrm[n] = 1.0f / sqrtf((float)max(si, 1));
  onrm[n] = 1.0f / sqrtf((float)max(so, 1));
}

// phase A: per-block chunk sums (coalesced int4, shuffle reduce)
__global__ __launch_bounds__(256) void k_scan_a(const int* __restrict__ cnt,
                                                int* __restrict__ bsum) {
  int b = blockIdx.x, t = threadIdx.x;
  int idx = b * SCAN_CHUNK + t * 4;
  int4 v = make_int4(0, 0, 0, 0);
  if (idx < NN) v = *(const int4*)(cnt + idx);   // NN % 4 == 0
  int s = v.x + v.y + v.z + v.w;
#pragma unroll
  for (int o = 1; o < 64; o <<= 1) s += __shfl_xor(s, o);
  __shared__ int ws[4];
  if ((t & 63) == 0) ws[t >> 6] = s;
  __syncthreads();
  if (t == 0) bsum[b] = ws[0] + ws[1] + ws[2] + ws[3];
}

// phase B: exclusive scan of the 98 block sums (in place), set off[NN]
__global__ void k_scan_b(int* __restrict__ bsum, int* __restrict__ off) {
  __shared__ int s[128];
  int t = threadIdx.x;
  int v = (t < NB_SCAN) ? bsum[t] : 0;
  s[t] = v;
  __syncthreads();
  for (int o = 1; o < 128; o <<= 1) {
    int u = (t >= o) ? s[t - o] : 0;
    __syncthreads();
    s[t] += u;
    __syncthreads();
  }
  if (t < NB_SCAN) bsum[t] = s[t] - v;  // exclusive prefix
  if (t == 0) off[NN] = NE;
}

// phase C: intra-block exclusive scan + block prefix -> off[]
__global__ __launch_bounds__(256) void k_scan_c(const int* __restrict__ cnt,
                                                const int* __restrict__ bsum,
                                                int* __restrict__ off) {
  int b = blockIdx.x, t = threadIdx.x;
  int idx = b * SCAN_CHUNK + t * 4;
  int4 v = make_int4(0, 0, 0, 0);
  if (idx < NN) v = *(const int4*)(cnt + idx);
  int lsum = v.x + v.y + v.z + v.w;
  int lane = t & 63, wid = t >> 6;
  int x = lsum;
#pragma unroll
  for (int o = 1; o < 64; o <<= 1) {
    int u = __shfl_up(x, o);
    if (lane >= o) x += u;
  }
  __shared__ int wsum[4];
  if (lane == 63) wsum[wid] = x;
  __syncthreads();
  int woff = 0;
  for (int i = 0; i < 4; ++i) woff += (i < wid) ? wsum[i] : 0;
  int excl = x - lsum + woff + bsum[b];
  if (idx < NN) {
    int4 o4;
    o4.x = excl;
    o4.y = excl + v.x;
    o4.z = o4.y + v.y;
    o4.w = o4.z + v.z;
    *(int4*)(off + idx) = o4;
  }
}

// column-wise running offsets: H[c][n] <- off[n] + sum_{c'<c} in(H[c'][n])
__global__ __launch_bounds__(256) void k_start(int* __restrict__ H,
                                               const int* __restrict__ off) {
  int n = blockIdx.x * 256 + threadIdx.x;
  if (n >= NN) return;
  int run = off[n];
#pragma unroll 8
  for (int c = 0; c < NCHUNK; ++c) {
    size_t idx = (size_t)c * HSTRIDE + n;
    int v = H[idx];
    H[idx] = run;
    run += (int)((unsigned)v & 0xffffu);
  }
}

// fill CSR: LDS cursors (absolute positions), plain global stores
__global__ __launch_bounds__(256) void k_fill2(
    const int* __restrict__ src, const int* __restrict__ dst,
    const int* __restrict__ H, int* __restrict__ csr) {
  __shared__ int cur[HP];
  const int c = blockIdx.x, p = blockIdx.y, t = threadIdx.x;
  const int base = p * HP;
  size_t rb = (size_t)c * HSTRIDE + base;
  for (int i = t; i < HP; i += 256) cur[i] = H[rb + i];
  __syncthreads();
  const int4* s4 = (const int4*)(src + c * CH_E);
  const int4* d4 = (const int4*)(dst + c * CH_E);
  const int n4 = CH_E / 4;
  for (int i = t; i < n4; i += 256) {
    int4 s = s4[i], d = d4[i];
    if ((unsigned)(d.x - base) < HP) { int pos = atomicAdd(&cur[d.x - base], 1); csr[pos] = s.x; }
    if ((unsigned)(d.y - base) < HP) { int pos = atomicAdd(&cur[d.y - base], 1); csr[pos] = s.y; }
    if ((unsigned)(d.z - base) < HP) { int pos = atomicAdd(&cur[d.z - base], 1); csr[pos] = s.z; }
    if ((unsigned)(d.w - base) < HP) { int pos = atomicAdd(&cur[d.w - base], 1); csr[pos] = s.w; }
  }
}

// C[r,:] = fp16( rs[r] * (A[r,:] @ W) )
// A-tile in LDS (33 KB); W read from global (L1/L2-resident, broadcast)
__global__ __launch_bounds__(256, 3) void k_matmul(
    const float* __restrict__ A, const float* __restrict__ W,
    const float* __restrict__ rs, __half* __restrict__ C) {
  __shared__ float As[BM][132];     // pad 132: bank spread
  const int tid = threadIdx.x;
  const int row0 = blockIdx.x * BM;
#pragma unroll
  for (int i = 0; i < 8; ++i) {
    int idx = tid + i * 256;        // 0..2047 float4 slots (64 rows x 32)
    int r = idx >> 5;
    int c4 = idx & 31;
    int grow = row0 + r;
    float4 v = make_float4(0.f, 0.f, 0.f, 0.f);
    if (grow < NN) {
      v = *(const float4*)(A + (size_t)grow * D + c4 * 4);
      float sc = rs[grow];
      v.x *= sc; v.y *= sc; v.z *= sc; v.w *= sc;
    }
    *(float4*)&As[r][c4 * 4] = v;
  }
  __syncthreads();
  const int tx = tid & 15, ty = tid >> 4;
  const int r0 = ty * 4, c0 = tx * 4;
  float acc[4][8];
#pragma unroll
  for (int i = 0; i < 4; ++i)
#pragma unroll
    for (int j = 0; j < 8; ++j) acc[i][j] = 0.f;
#pragma unroll 4
  for (int k = 0; k < 128; ++k) {
    float4 w0 = *(const float4*)&W[k * 128 + c0];        // cols c0..c0+3
    float4 w1 = *(const float4*)&W[k * 128 + c0 + 64];   // cols 64+c0..
    float av[4];
    av[0] = As[r0 + 0][k]; av[1] = As[r0 + 1][k];
    av[2] = As[r0 + 2][k]; av[3] = As[r0 + 3][k];
#pragma unroll
    for (int i = 0; i < 4; ++i) {
      acc[i][0] = fmaf(av[i], w0.x, acc[i][0]);
      acc[i][1] = fmaf(av[i], w0.y, acc[i][1]);
      acc[i][2] = fmaf(av[i], w0.z, acc[i][2]);
      acc[i][3] = fmaf(av[i], w0.w, acc[i][3]);
      acc[i][4] = fmaf(av[i], w1.x, acc[i][4]);
      acc[i][5] = fmaf(av[i], w1.y, acc[i][5]);
      acc[i][6] = fmaf(av[i], w1.z, acc[i][6]);
      acc[i][7] = fmaf(av[i], w1.w, acc[i][7]);
    }
  }
#pragma unroll
  for (int i = 0; i < 4; ++i) {
    int row = row0 + r0 + i;
    if (row < NN) {
      ushort4 p0, p1;
      p0.x = __half_as_ushort(__float2half_rn(acc[i][0]));
      p0.y = __half_as_ushort(__float2half_rn(acc[i][1]));
      p0.z = __half_as_ushort(__float2half_rn(acc[i][2]));
      p0.w = __half_as_ushort(__float2half_rn(acc[i][3]));
      p1.x = __half_as_ushort(__float2half_rn(acc[i][4]));
      p1.y = __half_as_ushort(__float2half_rn(acc[i][5]));
      p1.z = __half_as_ushort(__float2half_rn(acc[i][6]));
      p1.w = __half_as_ushort(__float2half_rn(acc[i][7]));
      *(ushort4*)(C + (size_t)row * D + c0) = p0;        // 8B packed, coalesced
      *(ushort4*)(C + (size_t)row * D + 64 + c0) = p1;
    }
  }
}

// out[d,:] = relu(in_norm[d] * sum_{s in CSR(d)} t[s,:] + bias)
// one wave per dst node; lane holds 2 feature cols (one half2 per row)
__global__ __launch_bounds__(256) void k_gather(
    const __half* __restrict__ t, const int* __restrict__ csr,
    const int* __restrict__ off, const float* __restrict__ inn,
    const float* __restrict__ bias, float* __restrict__ outp) {
  int w = (blockIdx.x * blockDim.x + threadIdx.x) >> 6;
  int lane = threadIdx.x & 63;
  if (w >= NN) return;
  int lo = off[w], hi = off[w + 1];
  const __half2* tp = (const __half2*)t + lane;   // row stride = 64 half2
  float ax = 0.f, ay = 0.f;
  int e = lo;
  for (; e + 3 < hi; e += 4) {
    int s0 = csr[e], s1 = csr[e + 1], s2 = csr[e + 2], s3 = csr[e + 3];
    float2 v0 = __half22float2(tp[(size_t)s0 * 64]);
    float2 v1 = __half22float2(tp[(size_t)s1 * 64]);
    float2 v2 = __half22float2(tp[(size_t)s2 * 64]);
    float2 v3 = __half22float2(tp[(size_t)s3 * 64]);
    ax += v0.x + v1.x + v2.x + v3.x;
    ay += v0.y + v1.y + v2.y + v3.y;
  }
  for (; e < hi; ++e) {
    float2 v0 = __half22float2(tp[(size_t)csr[e] * 64]);
    ax += v0.x; ay += v0.y;
  }
  float nm = inn[w];
  float2 b = *(const float2*)(bias + 2 * lane);
  float2 o;
  o.x = fmaxf(fmaf(nm, ax, b.x), 0.f);
  o.y = fmaxf(fmaf(nm, ay, b.y), 0.f);
  *(float2*)(outp + (size_t)w * D + 2 * lane) = o;
}

// parallel pool partial sums
__global__ __launch_bounds__(128) void k_pool_partial(
    const float* __restrict__ h2, const int* __restrict__ n2g,
    float* __restrict__ sums) {
  int c = threadIdx.x;
  int n0 = blockIdx.x * POOL_CHUNK;
  int n1 = min(n0 + POOL_CHUNK, NN);
  if (n0 >= NN) return;
  int gcur = n2g[n0];
  float acc = 0.f;
  for (int n = n0; n < n1; ++n) {
    int g = n2g[n];
    if (g != gcur) {
      atomicAdd(&sums[gcur * D + c], acc);
      acc = 0.f;
      gcur = g;
    }
    acc += h2[(size_t)n * D + c];
  }
  atomicAdd(&sums[gcur * D + c], acc);
}

// 3-layer MLP head; one block per graph, 128 threads. Divides sums by count.
__global__ void k_mlp(const float* __restrict__ sums, const int* __restrict__ n2g,
                      const float* __restrict__ Wc1, const float* __restrict__ bc1,
                      const float* __restrict__ Wc2, const float* __restrict__ bc2,
                      const float* __restrict__ Wc3, const float* __restrict__ bc3,
                      float* __restrict__ out) {
  __shared__ float xin[128];
  __shared__ float x1[128];
  __shared__ float red[128];
  int g = blockIdx.x, j = threadIdx.x;
  int start = lower_bound_i(n2g, NN, g);
  int end = lower_bound_i(n2g, NN, g + 1);
  float inv = 1.0f / (float)max(end - start, 1);
  xin[j] = sums[g * D + j] * inv;
  __syncthreads();
  float s = bc1[j];
#pragma unroll 8
  for (int k = 0; k < 128; ++k) s = fmaf(xin[k], Wc1[k * D + j], s);
  x1[j] = fmaxf(s, 0.f);
  __syncthreads();
  float s2 = bc2[j];
#pragma unroll 8
  for (int k = 0; k < 128; ++k) s2 = fmaf(x1[k], Wc2[k * D + j], s2);
  float v2 = fmaxf(s2, 0.f);
  red[j] = v2 * Wc3[j];
  __syncthreads();
  for (int o = 64; o > 0; o >>= 1) {
    if (j < o) red[j] += red[j + o];
    __syncthreads();
  }
  if (j == 0) out[g] = red[0] + bc3[0];
}

extern "C" void kernel_launch(void* const* d_in, const int* in_sizes, int n_in,
                              void* d_out, int out_size, void* d_ws, size_t ws_size,
                              hipStream_t stream) {
  const float* h   = (const float*)d_in[0];
  const int* src   = (const int*)d_in[1];
  const int* dst   = (const int*)d_in[2];
  const int* n2g   = (const int*)d_in[3];
  const float* W1  = (const float*)d_in[4];
  const float* b1  = (const float*)d_in[5];
  const float* W2  = (const float*)d_in[6];
  const float* b2  = (const float*)d_in[7];
  const float* Wc1 = (const float*)d_in[8];
  const float* bc1 = (const float*)d_in[9];
  const float* Wc2 = (const float*)d_in[10];
  const float* bc2 = (const float*)d_in[11];
  const float* Wc3 = (const float*)d_in[12];
  const float* bc3 = (const float*)d_in[13];
  float* out = (float*)d_out;

  char* p = (char*)d_ws;
  size_t o = 0;
  auto take = [&](size_t b) { void* q = p + o; o = (o + b + 255) & ~(size_t)255; return q; };
  float* sums = (float*)take(NG * D * 4);
  size_t zero_bytes = o;                    // zero pool sums only
  int* off   = (int*)take((NN + 1) * 4);
  int* bsum  = (int*)take(NB_SCAN * 4);
  int* ic    = (int*)take(NN * 4);
  float* onrm = (float*)take(NN * 4);
  float* inrm = (float*)take(NN * 4);
  int* csr   = (int*)take((size_t)NE * 4);
  __half* tbuf = (__half*)take((size_t)NN * D * 2);   // fp16 staging (25.6 MB)
  float* ubuf = (float*)take((size_t)NN * D * 4);
  (void)ws_size; (void)in_sizes; (void)n_in; (void)out_size;

  // packed partial histograms alias ubuf (29.4 MB <= 51.2 MB);
  // CSR build completes before gather first writes ubuf
  int* H = (int*)ubuf;

  hipMemsetAsync(d_ws, 0, zero_bytes, stream);
  dim3 hgrid(NCHUNK, NPART);
  k_hist<<<hgrid, 256, 0, stream>>>(src, dst, H);
  k_reduce<<<(NN + 255) / 256, 256, 0, stream>>>(H, ic, onrm, inrm);
  k_scan_a<<<NB_SCAN, 256, 0, stream>>>(ic, bsum);
  k_scan_b<<<1, 128, 0, stream>>>(bsum, off);
  k_scan_c<<<NB_SCAN, 256, 0, stream>>>(ic, bsum, off);
  k_start<<<(NN + 255) / 256, 256, 0, stream>>>(H, off);
  k_fill2<<<hgrid, 256, 0, stream>>>(src, dst, H, csr);

  // layer 1: t = fp16((h * out_norm) @ W1) ; h1 = relu(in_norm * gather(t) + b1)
  k_matmul<<<(NN + BM - 1) / BM, 256, 0, stream>>>(h, W1, onrm, tbuf);
  k_gather<<<(NN * 64) / 256, 256, 0, stream>>>(tbuf, csr, off, inrm, b1, ubuf);
  // layer 2
  k_matmul<<<(NN + BM - 1) / BM, 256, 0, stream>>>(ubuf, W2, onrm, tbuf);
  k_gather<<<(NN * 64) / 256, 256, 0, stream>>>(tbuf, csr, off, inrm, b2, ubuf);

  k_pool_partial<<<(NN + POOL_CHUNK - 1) / POOL_CHUNK, 128, 0, stream>>>(ubuf, n2g, sums);
  k_mlp<<<NG, 128, 0, stream>>>(sums, n2g, Wc1, bc1, Wc2, bc2, Wc3, bc3, out);
}

// Round 7
// 358.998 us; speedup vs baseline: 3.2239x; 1.2301x over previous
//
#include <hip/hip_runtime.h>
#include <hip/hip_fp16.h>

#define NN 100000
#define NE 1600000
#define D 128
#define NG 64
#define BM 64
#define KT 32
#define POOL_CHUNK 64
#define SCAN_CHUNK 1024
#define NB_SCAN ((NN + SCAN_CHUNK - 1) / SCAN_CHUNK)   // 98

// CSR-build tiling: 64 edge chunks x 7 node partitions of 16384
// packed counters: low 16 bits = in-degree (dst), high 16 = out-degree (src)
#define NCHUNK 64
#define CH_E (NE / NCHUNK)          // 25000 edges per chunk
#define HP 16384                    // nodes per partition (64 KB LDS counters)
#define NPART 7                     // 7*16384 = 114688 >= NN
#define HSTRIDE (NPART * HP)

__device__ __forceinline__ int lower_bound_i(const int* a, int n, int key) {
  int lo = 0, hi = n;
  while (lo < hi) { int mid = (lo + hi) >> 1; if (a[mid] < key) lo = mid + 1; else hi = mid; }
  return lo;
}

// partial packed histograms per (chunk, partition): LDS atomics only
__global__ __launch_bounds__(256) void k_hist(
    const int* __restrict__ src, const int* __restrict__ dst,
    int* __restrict__ H) {
  __shared__ int pk[HP];
  const int c = blockIdx.x, p = blockIdx.y, t = threadIdx.x;
  const int base = p * HP;
  for (int i = t; i < HP; i += 256) pk[i] = 0;
  __syncthreads();
  const int4* s4 = (const int4*)(src + c * CH_E);
  const int4* d4 = (const int4*)(dst + c * CH_E);
  const int n4 = CH_E / 4;  // 6250
  for (int i = t; i < n4; i += 256) {
    int4 s = s4[i], d = d4[i];
    if ((unsigned)(d.x - base) < HP) atomicAdd(&pk[d.x - base], 1);
    if ((unsigned)(d.y - base) < HP) atomicAdd(&pk[d.y - base], 1);
    if ((unsigned)(d.z - base) < HP) atomicAdd(&pk[d.z - base], 1);
    if ((unsigned)(d.w - base) < HP) atomicAdd(&pk[d.w - base], 1);
    if ((unsigned)(s.x - base) < HP) atomicAdd(&pk[s.x - base], 65536);
    if ((unsigned)(s.y - base) < HP) atomicAdd(&pk[s.y - base], 65536);
    if ((unsigned)(s.z - base) < HP) atomicAdd(&pk[s.z - base], 65536);
    if ((unsigned)(s.w - base) < HP) atomicAdd(&pk[s.w - base], 65536);
  }
  __syncthreads();
  size_t rb = (size_t)c * HSTRIDE + base;
  for (int i = t; i < HP; i += 256) H[rb + i] = pk[i];
}

// reduce packed partials over chunks -> in-degree (for scan) + both norms
__global__ __launch_bounds__(256) void k_reduce(
    const int* __restrict__ H,
    int* __restrict__ ic, float* __restrict__ onrm, float* __restrict__ inrm) {
  int n = blockIdx.x * 256 + threadIdx.x;
  if (n >= NN) return;
  int si = 0, so = 0;
#pragma unroll 8
  for (int c = 0; c < NCHUNK; ++c) {
    unsigned v = (unsigned)H[(size_t)c * HSTRIDE + n];
    si += (int)(v & 0xffffu);
    so += (int)(v >> 16);
  }
  ic[n] = si;
  inrm[n] = 1.0f / sqrtf((float)max(si, 1));
  onrm[n] = 1.0f / sqrtf((float)max(so, 1));
}

// phase A: per-block chunk sums (coalesced int4, shuffle reduce)
__global__ __launch_bounds__(256) void k_scan_a(const int* __restrict__ cnt,
                                                int* __restrict__ bsum) {
  int b = blockIdx.x, t = threadIdx.x;
  int idx = b * SCAN_CHUNK + t * 4;
  int4 v = make_int4(0, 0, 0, 0);
  if (idx < NN) v = *(const int4*)(cnt + idx);   // NN % 4 == 0
  int s = v.x + v.y + v.z + v.w;
#pragma unroll
  for (int o = 1; o < 64; o <<= 1) s += __shfl_xor(s, o);
  __shared__ int ws[4];
  if ((t & 63) == 0) ws[t >> 6] = s;
  __syncthreads();
  if (t == 0) bsum[b] = ws[0] + ws[1] + ws[2] + ws[3];
}

// phase B: exclusive scan of the 98 block sums (in place), set off[NN]
__global__ void k_scan_b(int* __restrict__ bsum, int* __restrict__ off) {
  __shared__ int s[128];
  int t = threadIdx.x;
  int v = (t < NB_SCAN) ? bsum[t] : 0;
  s[t] = v;
  __syncthreads();
  for (int o = 1; o < 128; o <<= 1) {
    int u = (t >= o) ? s[t - o] : 0;
    __syncthreads();
    s[t] += u;
    __syncthreads();
  }
  if (t < NB_SCAN) bsum[t] = s[t] - v;  // exclusive prefix
  if (t == 0) off[NN] = NE;
}

// phase C: intra-block exclusive scan + block prefix -> off[]
__global__ __launch_bounds__(256) void k_scan_c(const int* __restrict__ cnt,
                                                const int* __restrict__ bsum,
                                                int* __restrict__ off) {
  int b = blockIdx.x, t = threadIdx.x;
  int idx = b * SCAN_CHUNK + t * 4;
  int4 v = make_int4(0, 0, 0, 0);
  if (idx < NN) v = *(const int4*)(cnt + idx);
  int lsum = v.x + v.y + v.z + v.w;
  int lane = t & 63, wid = t >> 6;
  int x = lsum;
#pragma unroll
  for (int o = 1; o < 64; o <<= 1) {
    int u = __shfl_up(x, o);
    if (lane >= o) x += u;
  }
  __shared__ int wsum[4];
  if (lane == 63) wsum[wid] = x;
  __syncthreads();
  int woff = 0;
  for (int i = 0; i < 4; ++i) woff += (i < wid) ? wsum[i] : 0;
  int excl = x - lsum + woff + bsum[b];
  if (idx < NN) {
    int4 o4;
    o4.x = excl;
    o4.y = excl + v.x;
    o4.z = o4.y + v.y;
    o4.w = o4.z + v.z;
    *(int4*)(off + idx) = o4;
  }
}

// column-wise running offsets: H[c][n] <- off[n] + sum_{c'<c} in(H[c'][n])
__global__ __launch_bounds__(256) void k_start(int* __restrict__ H,
                                               const int* __restrict__ off) {
  int n = blockIdx.x * 256 + threadIdx.x;
  if (n >= NN) return;
  int run = off[n];
#pragma unroll 8
  for (int c = 0; c < NCHUNK; ++c) {
    size_t idx = (size_t)c * HSTRIDE + n;
    int v = H[idx];
    H[idx] = run;
    run += (int)((unsigned)v & 0xffffu);
  }
}

// fill CSR: LDS cursors (absolute positions), plain global stores
__global__ __launch_bounds__(256) void k_fill2(
    const int* __restrict__ src, const int* __restrict__ dst,
    const int* __restrict__ H, int* __restrict__ csr) {
  __shared__ int cur[HP];
  const int c = blockIdx.x, p = blockIdx.y, t = threadIdx.x;
  const int base = p * HP;
  size_t rb = (size_t)c * HSTRIDE + base;
  for (int i = t; i < HP; i += 256) cur[i] = H[rb + i];
  __syncthreads();
  const int4* s4 = (const int4*)(src + c * CH_E);
  const int4* d4 = (const int4*)(dst + c * CH_E);
  const int n4 = CH_E / 4;
  for (int i = t; i < n4; i += 256) {
    int4 s = s4[i], d = d4[i];
    if ((unsigned)(d.x - base) < HP) { int pos = atomicAdd(&cur[d.x - base], 1); csr[pos] = s.x; }
    if ((unsigned)(d.y - base) < HP) { int pos = atomicAdd(&cur[d.y - base], 1); csr[pos] = s.y; }
    if ((unsigned)(d.z - base) < HP) { int pos = atomicAdd(&cur[d.z - base], 1); csr[pos] = s.z; }
    if ((unsigned)(d.w - base) < HP) { int pos = atomicAdd(&cur[d.w - base], 1); csr[pos] = s.w; }
  }
}

// C[r,:] = fp16( rs[r] * (A[r,:] @ W) )
// A-tile (33 KB) + K-tiled W (16 KB) in LDS -> 50 KB, 3 blocks/CU
__global__ __launch_bounds__(256, 3) void k_matmul(
    const float* __restrict__ A, const float* __restrict__ W,
    const float* __restrict__ rs, __half* __restrict__ C) {
  __shared__ float As[BM][132];     // pad 132: bank spread
  __shared__ float Ws[KT][128];
  const int tid = threadIdx.x;
  const int row0 = blockIdx.x * BM;
#pragma unroll
  for (int i = 0; i < 8; ++i) {
    int idx = tid + i * 256;        // 0..2047 float4 slots (64 rows x 32)
    int r = idx >> 5;
    int c4 = idx & 31;
    int grow = row0 + r;
    float4 v = make_float4(0.f, 0.f, 0.f, 0.f);
    if (grow < NN) {
      v = *(const float4*)(A + (size_t)grow * D + c4 * 4);
      float sc = rs[grow];
      v.x *= sc; v.y *= sc; v.z *= sc; v.w *= sc;
    }
    *(float4*)&As[r][c4 * 4] = v;
  }
  const int tx = tid & 15, ty = tid >> 4;
  const int r0 = ty * 4, c0 = tx * 4;
  float acc[4][8];
#pragma unroll
  for (int i = 0; i < 4; ++i)
#pragma unroll
    for (int j = 0; j < 8; ++j) acc[i][j] = 0.f;

  for (int k0 = 0; k0 < 128; k0 += KT) {
    __syncthreads();   // As ready (iter 0) / prev Ws-tile consumed
#pragma unroll
    for (int i = 0; i < 4; ++i) {
      int idx = tid + i * 256;      // 0..1023 float4 slots (32 rows x 32)
      int kk = idx >> 5;
      int c4 = idx & 31;
      *(float4*)&Ws[kk][c4 * 4] = *(const float4*)&W[(size_t)(k0 + kk) * 128 + c4 * 4];
    }
    __syncthreads();
#pragma unroll
    for (int kk = 0; kk < KT; ++kk) {
      float4 w0 = *(const float4*)&Ws[kk][c0];        // cols c0..c0+3
      float4 w1 = *(const float4*)&Ws[kk][c0 + 64];   // cols 64+c0..
      int k = k0 + kk;
      float av[4];
      av[0] = As[r0 + 0][k]; av[1] = As[r0 + 1][k];
      av[2] = As[r0 + 2][k]; av[3] = As[r0 + 3][k];
#pragma unroll
      for (int i = 0; i < 4; ++i) {
        acc[i][0] = fmaf(av[i], w0.x, acc[i][0]);
        acc[i][1] = fmaf(av[i], w0.y, acc[i][1]);
        acc[i][2] = fmaf(av[i], w0.z, acc[i][2]);
        acc[i][3] = fmaf(av[i], w0.w, acc[i][3]);
        acc[i][4] = fmaf(av[i], w1.x, acc[i][4]);
        acc[i][5] = fmaf(av[i], w1.y, acc[i][5]);
        acc[i][6] = fmaf(av[i], w1.z, acc[i][6]);
        acc[i][7] = fmaf(av[i], w1.w, acc[i][7]);
      }
    }
  }
#pragma unroll
  for (int i = 0; i < 4; ++i) {
    int row = row0 + r0 + i;
    if (row < NN) {
      ushort4 p0, p1;
      p0.x = __half_as_ushort(__float2half_rn(acc[i][0]));
      p0.y = __half_as_ushort(__float2half_rn(acc[i][1]));
      p0.z = __half_as_ushort(__float2half_rn(acc[i][2]));
      p0.w = __half_as_ushort(__float2half_rn(acc[i][3]));
      p1.x = __half_as_ushort(__float2half_rn(acc[i][4]));
      p1.y = __half_as_ushort(__float2half_rn(acc[i][5]));
      p1.z = __half_as_ushort(__float2half_rn(acc[i][6]));
      p1.w = __half_as_ushort(__float2half_rn(acc[i][7]));
      *(ushort4*)(C + (size_t)row * D + c0) = p0;        // 8B packed, coalesced
      *(ushort4*)(C + (size_t)row * D + 64 + c0) = p1;
    }
  }
}

// out[d,:] = relu(in_norm[d] * sum_{s in CSR(d)} t[s,:] + bias)
// one wave per dst node; 4 lane-groups of 16 process 4 edges/step,
// each lane loads 16B (8 halves); cross-group shfl_xor reduce at end.
__global__ __launch_bounds__(256) void k_gather(
    const __half* __restrict__ t, const int* __restrict__ csr,
    const int* __restrict__ off, const float* __restrict__ inn,
    const float* __restrict__ bias, float* __restrict__ outp) {
  int w = (blockIdx.x * blockDim.x + threadIdx.x) >> 6;
  int lane = threadIdx.x & 63;
  if (w >= NN) return;
  int lo = off[w], hi = off[w + 1];
  const int g = lane >> 4;        // edge subgroup 0..3
  const int li = lane & 15;       // 16B column slot
  float a0 = 0.f, a1 = 0.f, a2 = 0.f, a3 = 0.f;
  float a4 = 0.f, a5 = 0.f, a6 = 0.f, a7 = 0.f;
  for (int e = lo + g; e < hi; e += 4) {
    int s = csr[e];
    float4 raw = *(const float4*)(t + (size_t)s * D + li * 8);
    const __half2* hp = (const __half2*)&raw;
    float2 f0 = __half22float2(hp[0]);
    float2 f1 = __half22float2(hp[1]);
    float2 f2 = __half22float2(hp[2]);
    float2 f3 = __half22float2(hp[3]);
    a0 += f0.x; a1 += f0.y; a2 += f1.x; a3 += f1.y;
    a4 += f2.x; a5 += f2.y; a6 += f3.x; a7 += f3.y;
  }
  // combine the 4 edge subgroups (lanes l, l+16, l+32, l+48 hold same cols)
  a0 += __shfl_xor(a0, 16); a0 += __shfl_xor(a0, 32);
  a1 += __shfl_xor(a1, 16); a1 += __shfl_xor(a1, 32);
  a2 += __shfl_xor(a2, 16); a2 += __shfl_xor(a2, 32);
  a3 += __shfl_xor(a3, 16); a3 += __shfl_xor(a3, 32);
  a4 += __shfl_xor(a4, 16); a4 += __shfl_xor(a4, 32);
  a5 += __shfl_xor(a5, 16); a5 += __shfl_xor(a5, 32);
  a6 += __shfl_xor(a6, 16); a6 += __shfl_xor(a6, 32);
  a7 += __shfl_xor(a7, 16); a7 += __shfl_xor(a7, 32);
  if (lane < 16) {
    float nm = inn[w];
    float4 b0 = *(const float4*)(bias + li * 8);
    float4 b1 = *(const float4*)(bias + li * 8 + 4);
    float4 o0, o1;
    o0.x = fmaxf(fmaf(nm, a0, b0.x), 0.f);
    o0.y = fmaxf(fmaf(nm, a1, b0.y), 0.f);
    o0.z = fmaxf(fmaf(nm, a2, b0.z), 0.f);
    o0.w = fmaxf(fmaf(nm, a3, b0.w), 0.f);
    o1.x = fmaxf(fmaf(nm, a4, b1.x), 0.f);
    o1.y = fmaxf(fmaf(nm, a5, b1.y), 0.f);
    o1.z = fmaxf(fmaf(nm, a6, b1.z), 0.f);
    o1.w = fmaxf(fmaf(nm, a7, b1.w), 0.f);
    *(float4*)(outp + (size_t)w * D + li * 8) = o0;
    *(float4*)(outp + (size_t)w * D + li * 8 + 4) = o1;
  }
}

// parallel pool partial sums: block = 64-node chunk, thread = col (coalesced)
__global__ __launch_bounds__(128) void k_pool_partial(
    const float* __restrict__ h2, const int* __restrict__ n2g,
    float* __restrict__ sums) {
  int c = threadIdx.x;
  int n0 = blockIdx.x * POOL_CHUNK;
  int n1 = min(n0 + POOL_CHUNK, NN);
  if (n0 >= NN) return;
  int gcur = n2g[n0];
  float acc = 0.f;
  for (int n = n0; n < n1; ++n) {
    int g = n2g[n];
    if (g != gcur) {
      atomicAdd(&sums[gcur * D + c], acc);
      acc = 0.f;
      gcur = g;
    }
    acc += h2[(size_t)n * D + c];
  }
  atomicAdd(&sums[gcur * D + c], acc);
}

// 3-layer MLP head; one block per graph, 128 threads. Divides sums by count.
__global__ void k_mlp(const float* __restrict__ sums, const int* __restrict__ n2g,
                      const float* __restrict__ Wc1, const float* __restrict__ bc1,
                      const float* __restrict__ Wc2, const float* __restrict__ bc2,
                      const float* __restrict__ Wc3, const float* __restrict__ bc3,
                      float* __restrict__ out) {
  __shared__ float xin[128];
  __shared__ float x1[128];
  __shared__ float red[128];
  int g = blockIdx.x, j = threadIdx.x;
  int start = lower_bound_i(n2g, NN, g);
  int end = lower_bound_i(n2g, NN, g + 1);
  float inv = 1.0f / (float)max(end - start, 1);
  xin[j] = sums[g * D + j] * inv;
  __syncthreads();
  float s = bc1[j];
#pragma unroll 8
  for (int k = 0; k < 128; ++k) s = fmaf(xin[k], Wc1[k * D + j], s);
  x1[j] = fmaxf(s, 0.f);
  __syncthreads();
  float s2 = bc2[j];
#pragma unroll 8
  for (int k = 0; k < 128; ++k) s2 = fmaf(x1[k], Wc2[k * D + j], s2);
  float v2 = fmaxf(s2, 0.f);
  red[j] = v2 * Wc3[j];
  __syncthreads();
  for (int o = 64; o > 0; o >>= 1) {
    if (j < o) red[j] += red[j + o];
    __syncthreads();
  }
  if (j == 0) out[g] = red[0] + bc3[0];
}

extern "C" void kernel_launch(void* const* d_in, const int* in_sizes, int n_in,
                              void* d_out, int out_size, void* d_ws, size_t ws_size,
                              hipStream_t stream) {
  const float* h   = (const float*)d_in[0];
  const int* src   = (const int*)d_in[1];
  const int* dst   = (const int*)d_in[2];
  const int* n2g   = (const int*)d_in[3];
  const float* W1  = (const float*)d_in[4];
  const float* b1  = (const float*)d_in[5];
  const float* W2  = (const float*)d_in[6];
  const float* b2  = (const float*)d_in[7];
  const float* Wc1 = (const float*)d_in[8];
  const float* bc1 = (const float*)d_in[9];
  const float* Wc2 = (const float*)d_in[10];
  const float* bc2 = (const float*)d_in[11];
  const float* Wc3 = (const float*)d_in[12];
  const float* bc3 = (const float*)d_in[13];
  float* out = (float*)d_out;

  char* p = (char*)d_ws;
  size_t o = 0;
  auto take = [&](size_t b) { void* q = p + o; o = (o + b + 255) & ~(size_t)255; return q; };
  float* sums = (float*)take(NG * D * 4);
  size_t zero_bytes = o;                    // zero pool sums only
  int* off   = (int*)take((NN + 1) * 4);
  int* bsum  = (int*)take(NB_SCAN * 4);
  int* ic    = (int*)take(NN * 4);
  float* onrm = (float*)take(NN * 4);
  float* inrm = (float*)take(NN * 4);
  int* csr   = (int*)take((size_t)NE * 4);
  __half* tbuf = (__half*)take((size_t)NN * D * 2);   // fp16 staging (25.6 MB)
  float* ubuf = (float*)take((size_t)NN * D * 4);
  (void)ws_size; (void)in_sizes; (void)n_in; (void)out_size;

  // packed partial histograms alias ubuf (29.4 MB <= 51.2 MB);
  // CSR build completes before gather first writes ubuf
  int* H = (int*)ubuf;

  hipMemsetAsync(d_ws, 0, zero_bytes, stream);
  dim3 hgrid(NCHUNK, NPART);
  k_hist<<<hgrid, 256, 0, stream>>>(src, dst, H);
  k_reduce<<<(NN + 255) / 256, 256, 0, stream>>>(H, ic, onrm, inrm);
  k_scan_a<<<NB_SCAN, 256, 0, stream>>>(ic, bsum);
  k_scan_b<<<1, 128, 0, stream>>>(bsum, off);
  k_scan_c<<<NB_SCAN, 256, 0, stream>>>(ic, bsum, off);
  k_start<<<(NN + 255) / 256, 256, 0, stream>>>(H, off);
  k_fill2<<<hgrid, 256, 0, stream>>>(src, dst, H, csr);

  // layer 1: t = fp16((h * out_norm) @ W1) ; h1 = relu(in_norm * gather(t) + b1)
  k_matmul<<<(NN + BM - 1) / BM, 256, 0, stream>>>(h, W1, onrm, tbuf);
  k_gather<<<(NN * 64) / 256, 256, 0, stream>>>(tbuf, csr, off, inrm, b1, ubuf);
  // layer 2
  k_matmul<<<(NN + BM - 1) / BM, 256, 0, stream>>>(ubuf, W2, onrm, tbuf);
  k_gather<<<(NN * 64) / 256, 256, 0, stream>>>(tbuf, csr, off, inrm, b2, ubuf);

  k_pool_partial<<<(NN + POOL_CHUNK - 1) / POOL_CHUNK, 128, 0, stream>>>(ubuf, n2g, sums);
  k_mlp<<<NG, 128, 0, stream>>>(sums, n2g, Wc1, bc1, Wc2, bc2, Wc3, bc3, out);
}

// Round 10
// 357.004 us; speedup vs baseline: 3.2419x; 1.0056x over previous
//
#include <hip/hip_runtime.h>
#include <hip/hip_fp16.h>

#define NN 100000
#define NE 1600000
#define D 128
#define NG 64
#define BM 64
#define KT 32
#define POOL_CHUNK 64
#define SCAN_CHUNK 1024
#define NB_SCAN ((NN + SCAN_CHUNK - 1) / SCAN_CHUNK)   // 98

// CSR-build tiling: 64 edge chunks x 7 node partitions of 16384
// packed counters: low 16 bits = in-degree (dst), high 16 = out-degree (src)
#define NCHUNK 64
#define CH_E (NE / NCHUNK)          // 25000 edges per chunk
#define HP 16384                    // nodes per partition (64 KB LDS counters)
#define NPART 7                     // 7*16384 = 114688 >= NN
#define HSTRIDE (NPART * HP)

__device__ __forceinline__ int lower_bound_i(const int* a, int n, int key) {
  int lo = 0, hi = n;
  while (lo < hi) { int mid = (lo + hi) >> 1; if (a[mid] < key) lo = mid + 1; else hi = mid; }
  return lo;
}

// partial packed histograms per (chunk, partition): LDS atomics only
__global__ __launch_bounds__(256) void k_hist(
    const int* __restrict__ src, const int* __restrict__ dst,
    int* __restrict__ H) {
  __shared__ int pk[HP];
  const int c = blockIdx.x, p = blockIdx.y, t = threadIdx.x;
  const int base = p * HP;
  for (int i = t; i < HP; i += 256) pk[i] = 0;
  __syncthreads();
  const int4* s4 = (const int4*)(src + c * CH_E);
  const int4* d4 = (const int4*)(dst + c * CH_E);
  const int n4 = CH_E / 4;  // 6250
  for (int i = t; i < n4; i += 256) {
    int4 s = s4[i], d = d4[i];
    if ((unsigned)(d.x - base) < HP) atomicAdd(&pk[d.x - base], 1);
    if ((unsigned)(d.y - base) < HP) atomicAdd(&pk[d.y - base], 1);
    if ((unsigned)(d.z - base) < HP) atomicAdd(&pk[d.z - base], 1);
    if ((unsigned)(d.w - base) < HP) atomicAdd(&pk[d.w - base], 1);
    if ((unsigned)(s.x - base) < HP) atomicAdd(&pk[s.x - base], 65536);
    if ((unsigned)(s.y - base) < HP) atomicAdd(&pk[s.y - base], 65536);
    if ((unsigned)(s.z - base) < HP) atomicAdd(&pk[s.z - base], 65536);
    if ((unsigned)(s.w - base) < HP) atomicAdd(&pk[s.w - base], 65536);
  }
  __syncthreads();
  size_t rb = (size_t)c * HSTRIDE + base;
  for (int i = t; i < HP; i += 256) H[rb + i] = pk[i];
}

// reduce packed partials over chunks -> in-degree (for scan) + both norms
__global__ __launch_bounds__(256) void k_reduce(
    const int* __restrict__ H,
    int* __restrict__ ic, float* __restrict__ onrm, float* __restrict__ inrm) {
  int n = blockIdx.x * 256 + threadIdx.x;
  if (n >= NN) return;
  int si = 0, so = 0;
#pragma unroll 8
  for (int c = 0; c < NCHUNK; ++c) {
    unsigned v = (unsigned)H[(size_t)c * HSTRIDE + n];
    si += (int)(v & 0xffffu);
    so += (int)(v >> 16);
  }
  ic[n] = si;
  inrm[n] = 1.0f / sqrtf((float)max(si, 1));
  onrm[n] = 1.0f / sqrtf((float)max(so, 1));
}

// phase A: per-block chunk sums (coalesced int4, shuffle reduce)
__global__ __launch_bounds__(256) void k_scan_a(const int* __restrict__ cnt,
                                                int* __restrict__ bsum) {
  int b = blockIdx.x, t = threadIdx.x;
  int idx = b * SCAN_CHUNK + t * 4;
  int4 v = make_int4(0, 0, 0, 0);
  if (idx < NN) v = *(const int4*)(cnt + idx);   // NN % 4 == 0
  int s = v.x + v.y + v.z + v.w;
#pragma unroll
  for (int o = 1; o < 64; o <<= 1) s += __shfl_xor(s, o);
  __shared__ int ws[4];
  if ((t & 63) == 0) ws[t >> 6] = s;
  __syncthreads();
  if (t == 0) bsum[b] = ws[0] + ws[1] + ws[2] + ws[3];
}

// phase B: exclusive scan of the 98 block sums (in place), set off[NN]
__global__ void k_scan_b(int* __restrict__ bsum, int* __restrict__ off) {
  __shared__ int s[128];
  int t = threadIdx.x;
  int v = (t < NB_SCAN) ? bsum[t] : 0;
  s[t] = v;
  __syncthreads();
  for (int o = 1; o < 128; o <<= 1) {
    int u = (t >= o) ? s[t - o] : 0;
    __syncthreads();
    s[t] += u;
    __syncthreads();
  }
  if (t < NB_SCAN) bsum[t] = s[t] - v;  // exclusive prefix
  if (t == 0) off[NN] = NE;
}

// phase C: intra-block exclusive scan + block prefix -> off[]
__global__ __launch_bounds__(256) void k_scan_c(const int* __restrict__ cnt,
                                                const int* __restrict__ bsum,
                                                int* __restrict__ off) {
  int b = blockIdx.x, t = threadIdx.x;
  int idx = b * SCAN_CHUNK + t * 4;
  int4 v = make_int4(0, 0, 0, 0);
  if (idx < NN) v = *(const int4*)(cnt + idx);
  int lsum = v.x + v.y + v.z + v.w;
  int lane = t & 63, wid = t >> 6;
  int x = lsum;
#pragma unroll
  for (int o = 1; o < 64; o <<= 1) {
    int u = __shfl_up(x, o);
    if (lane >= o) x += u;
  }
  __shared__ int wsum[4];
  if (lane == 63) wsum[wid] = x;
  __syncthreads();
  int woff = 0;
  for (int i = 0; i < 4; ++i) woff += (i < wid) ? wsum[i] : 0;
  int excl = x - lsum + woff + bsum[b];
  if (idx < NN) {
    int4 o4;
    o4.x = excl;
    o4.y = excl + v.x;
    o4.z = o4.y + v.y;
    o4.w = o4.z + v.z;
    *(int4*)(off + idx) = o4;
  }
}

// column-wise running offsets: H[c][n] <- off[n] + sum_{c'<c} in(H[c'][n])
__global__ __launch_bounds__(256) void k_start(int* __restrict__ H,
                                               const int* __restrict__ off) {
  int n = blockIdx.x * 256 + threadIdx.x;
  if (n >= NN) return;
  int run = off[n];
#pragma unroll 8
  for (int c = 0; c < NCHUNK; ++c) {
    size_t idx = (size_t)c * HSTRIDE + n;
    int v = H[idx];
    H[idx] = run;
    run += (int)((unsigned)v & 0xffffu);
  }
}

// fill CSR: LDS cursors (absolute positions), plain global stores
__global__ __launch_bounds__(256) void k_fill2(
    const int* __restrict__ src, const int* __restrict__ dst,
    const int* __restrict__ H, int* __restrict__ csr) {
  __shared__ int cur[HP];
  const int c = blockIdx.x, p = blockIdx.y, t = threadIdx.x;
  const int base = p * HP;
  size_t rb = (size_t)c * HSTRIDE + base;
  for (int i = t; i < HP; i += 256) cur[i] = H[rb + i];
  __syncthreads();
  const int4* s4 = (const int4*)(src + c * CH_E);
  const int4* d4 = (const int4*)(dst + c * CH_E);
  const int n4 = CH_E / 4;
  for (int i = t; i < n4; i += 256) {
    int4 s = s4[i], d = d4[i];
    if ((unsigned)(d.x - base) < HP) { int pos = atomicAdd(&cur[d.x - base], 1); csr[pos] = s.x; }
    if ((unsigned)(d.y - base) < HP) { int pos = atomicAdd(&cur[d.y - base], 1); csr[pos] = s.y; }
    if ((unsigned)(d.z - base) < HP) { int pos = atomicAdd(&cur[d.z - base], 1); csr[pos] = s.z; }
    if ((unsigned)(d.w - base) < HP) { int pos = atomicAdd(&cur[d.w - base], 1); csr[pos] = s.w; }
  }
}

// C[r,:] = fp16( rs[r] * (A[r,:] @ W) )
// A-tile (33 KB) + K-tiled W (16 KB) in LDS -> 50 KB, 3 blocks/CU
__global__ __launch_bounds__(256, 3) void k_matmul(
    const float* __restrict__ A, const float* __restrict__ W,
    const float* __restrict__ rs, __half* __restrict__ C) {
  __shared__ float As[BM][132];     // pad 132: bank spread
  __shared__ float Ws[KT][128];
  const int tid = threadIdx.x;
  const int row0 = blockIdx.x * BM;
#pragma unroll
  for (int i = 0; i < 8; ++i) {
    int idx = tid + i * 256;        // 0..2047 float4 slots (64 rows x 32)
    int r = idx >> 5;
    int c4 = idx & 31;
    int grow = row0 + r;
    float4 v = make_float4(0.f, 0.f, 0.f, 0.f);
    if (grow < NN) {
      v = *(const float4*)(A + (size_t)grow * D + c4 * 4);
      float sc = rs[grow];
      v.x *= sc; v.y *= sc; v.z *= sc; v.w *= sc;
    }
    *(float4*)&As[r][c4 * 4] = v;
  }
  const int tx = tid & 15, ty = tid >> 4;
  const int r0 = ty * 4, c0 = tx * 4;
  float acc[4][8];
#pragma unroll
  for (int i = 0; i < 4; ++i)
#pragma unroll
    for (int j = 0; j < 8; ++j) acc[i][j] = 0.f;

  for (int k0 = 0; k0 < 128; k0 += KT) {
    __syncthreads();   // As ready (iter 0) / prev Ws-tile consumed
#pragma unroll
    for (int i = 0; i < 4; ++i) {
      int idx = tid + i * 256;      // 0..1023 float4 slots (32 rows x 32)
      int kk = idx >> 5;
      int c4 = idx & 31;
      *(float4*)&Ws[kk][c4 * 4] = *(const float4*)&W[(size_t)(k0 + kk) * 128 + c4 * 4];
    }
    __syncthreads();
#pragma unroll
    for (int kk = 0; kk < KT; ++kk) {
      float4 w0 = *(const float4*)&Ws[kk][c0];        // cols c0..c0+3
      float4 w1 = *(const float4*)&Ws[kk][c0 + 64];   // cols 64+c0..
      int k = k0 + kk;
      float av[4];
      av[0] = As[r0 + 0][k]; av[1] = As[r0 + 1][k];
      av[2] = As[r0 + 2][k]; av[3] = As[r0 + 3][k];
#pragma unroll
      for (int i = 0; i < 4; ++i) {
        acc[i][0] = fmaf(av[i], w0.x, acc[i][0]);
        acc[i][1] = fmaf(av[i], w0.y, acc[i][1]);
        acc[i][2] = fmaf(av[i], w0.z, acc[i][2]);
        acc[i][3] = fmaf(av[i], w0.w, acc[i][3]);
        acc[i][4] = fmaf(av[i], w1.x, acc[i][4]);
        acc[i][5] = fmaf(av[i], w1.y, acc[i][5]);
        acc[i][6] = fmaf(av[i], w1.z, acc[i][6]);
        acc[i][7] = fmaf(av[i], w1.w, acc[i][7]);
      }
    }
  }
#pragma unroll
  for (int i = 0; i < 4; ++i) {
    int row = row0 + r0 + i;
    if (row < NN) {
      ushort4 p0, p1;
      p0.x = __half_as_ushort(__float2half_rn(acc[i][0]));
      p0.y = __half_as_ushort(__float2half_rn(acc[i][1]));
      p0.z = __half_as_ushort(__float2half_rn(acc[i][2]));
      p0.w = __half_as_ushort(__float2half_rn(acc[i][3]));
      p1.x = __half_as_ushort(__float2half_rn(acc[i][4]));
      p1.y = __half_as_ushort(__float2half_rn(acc[i][5]));
      p1.z = __half_as_ushort(__float2half_rn(acc[i][6]));
      p1.w = __half_as_ushort(__float2half_rn(acc[i][7]));
      *(ushort4*)(C + (size_t)row * D + c0) = p0;        // 8B packed, coalesced
      *(ushort4*)(C + (size_t)row * D + 64 + c0) = p1;
    }
  }
}

// out[d,:] = relu(in_norm[d] * sum_{s in CSR(d)} t[s,:] + bias)
// one wave per dst node; 4 lane-groups of 16 process 4 edges/step,
// each lane loads 16B (8 halves); cross-group shfl_xor reduce at end.
__global__ __launch_bounds__(256) void k_gather(
    const __half* __restrict__ t, const int* __restrict__ csr,
    const int* __restrict__ off, const float* __restrict__ inn,
    const float* __restrict__ bias, float* __restrict__ outp) {
  int w = (blockIdx.x * blockDim.x + threadIdx.x) >> 6;
  int lane = threadIdx.x & 63;
  if (w >= NN) return;
  int lo = off[w], hi = off[w + 1];
  const int g = lane >> 4;        // edge subgroup 0..3
  const int li = lane & 15;       // 16B column slot
  float a0 = 0.f, a1 = 0.f, a2 = 0.f, a3 = 0.f;
  float a4 = 0.f, a5 = 0.f, a6 = 0.f, a7 = 0.f;
  for (int e = lo + g; e < hi; e += 4) {
    int s = csr[e];
    float4 raw = *(const float4*)(t + (size_t)s * D + li * 8);
    const __half2* hp = (const __half2*)&raw;
    float2 f0 = __half22float2(hp[0]);
    float2 f1 = __half22float2(hp[1]);
    float2 f2 = __half22float2(hp[2]);
    float2 f3 = __half22float2(hp[3]);
    a0 += f0.x; a1 += f0.y; a2 += f1.x; a3 += f1.y;
    a4 += f2.x; a5 += f2.y; a6 += f3.x; a7 += f3.y;
  }
  // combine the 4 edge subgroups (lanes l, l+16, l+32, l+48 hold same cols)
  a0 += __shfl_xor(a0, 16); a0 += __shfl_xor(a0, 32);
  a1 += __shfl_xor(a1, 16); a1 += __shfl_xor(a1, 32);
  a2 += __shfl_xor(a2, 16); a2 += __shfl_xor(a2, 32);
  a3 += __shfl_xor(a3, 16); a3 += __shfl_xor(a3, 32);
  a4 += __shfl_xor(a4, 16); a4 += __shfl_xor(a4, 32);
  a5 += __shfl_xor(a5, 16); a5 += __shfl_xor(a5, 32);
  a6 += __shfl_xor(a6, 16); a6 += __shfl_xor(a6, 32);
  a7 += __shfl_xor(a7, 16); a7 += __shfl_xor(a7, 32);
  if (lane < 16) {
    float nm = inn[w];
    float4 b0 = *(const float4*)(bias + li * 8);
    float4 b1 = *(const float4*)(bias + li * 8 + 4);
    float4 o0, o1;
    o0.x = fmaxf(fmaf(nm, a0, b0.x), 0.f);
    o0.y = fmaxf(fmaf(nm, a1, b0.y), 0.f);
    o0.z = fmaxf(fmaf(nm, a2, b0.z), 0.f);
    o0.w = fmaxf(fmaf(nm, a3, b0.w), 0.f);
    o1.x = fmaxf(fmaf(nm, a4, b1.x), 0.f);
    o1.y = fmaxf(fmaf(nm, a5, b1.y), 0.f);
    o1.z = fmaxf(fmaf(nm, a6, b1.z), 0.f);
    o1.w = fmaxf(fmaf(nm, a7, b1.w), 0.f);
    *(float4*)(outp + (size_t)w * D + li * 8) = o0;
    *(float4*)(outp + (size_t)w * D + li * 8 + 4) = o1;
  }
}

// parallel pool partial sums: block = 64-node chunk, thread = col (coalesced)
__global__ __launch_bounds__(128) void k_pool_partial(
    const float* __restrict__ h2, const int* __restrict__ n2g,
    float* __restrict__ sums) {
  int c = threadIdx.x;
  int n0 = blockIdx.x * POOL_CHUNK;
  int n1 = min(n0 + POOL_CHUNK, NN);
  if (n0 >= NN) return;
  int gcur = n2g[n0];
  float acc = 0.f;
  for (int n = n0; n < n1; ++n) {
    int g = n2g[n];
    if (g != gcur) {
      atomicAdd(&sums[gcur * D + c], acc);
      acc = 0.f;
      gcur = g;
    }
    acc += h2[(size_t)n * D + c];
  }
  atomicAdd(&sums[gcur * D + c], acc);
}

// 3-layer MLP head; one block per graph, 128 threads. Divides sums by count.
__global__ void k_mlp(const float* __restrict__ sums, const int* __restrict__ n2g,
                      const float* __restrict__ Wc1, const float* __restrict__ bc1,
                      const float* __restrict__ Wc2, const float* __restrict__ bc2,
                      const float* __restrict__ Wc3, const float* __restrict__ bc3,
                      float* __restrict__ out) {
  __shared__ float xin[128];
  __shared__ float x1[128];
  __shared__ float red[128];
  int g = blockIdx.x, j = threadIdx.x;
  int start = lower_bound_i(n2g, NN, g);
  int end = lower_bound_i(n2g, NN, g + 1);
  float inv = 1.0f / (float)max(end - start, 1);
  xin[j] = sums[g * D + j] * inv;
  __syncthreads();
  float s = bc1[j];
#pragma unroll 8
  for (int k = 0; k < 128; ++k) s = fmaf(xin[k], Wc1[k * D + j], s);
  x1[j] = fmaxf(s, 0.f);
  __syncthreads();
  float s2 = bc2[j];
#pragma unroll 8
  for (int k = 0; k < 128; ++k) s2 = fmaf(x1[k], Wc2[k * D + j], s2);
  float v2 = fmaxf(s2, 0.f);
  red[j] = v2 * Wc3[j];
  __syncthreads();
  for (int o = 64; o > 0; o >>= 1) {
    if (j < o) red[j] += red[j + o];
    __syncthreads();
  }
  if (j == 0) out[g] = red[0] + bc3[0];
}

extern "C" void kernel_launch(void* const* d_in, const int* in_sizes, int n_in,
                              void* d_out, int out_size, void* d_ws, size_t ws_size,
                              hipStream_t stream) {
  const float* h   = (const float*)d_in[0];
  const int* src   = (const int*)d_in[1];
  const int* dst   = (const int*)d_in[2];
  const int* n2g   = (const int*)d_in[3];
  const float* W1  = (const float*)d_in[4];
  const float* b1  = (const float*)d_in[5];
  const float* W2  = (const float*)d_in[6];
  const float* b2  = (const float*)d_in[7];
  const float* Wc1 = (const float*)d_in[8];
  const float* bc1 = (const float*)d_in[9];
  const float* Wc2 = (const float*)d_in[10];
  const float* bc2 = (const float*)d_in[11];
  const float* Wc3 = (const float*)d_in[12];
  const float* bc3 = (const float*)d_in[13];
  float* out = (float*)d_out;

  char* p = (char*)d_ws;
  size_t o = 0;
  auto take = [&](size_t b) { void* q = p + o; o = (o + b + 255) & ~(size_t)255; return q; };
  float* sums = (float*)take(NG * D * 4);
  size_t zero_bytes = o;                    // zero pool sums only
  int* off   = (int*)take((NN + 1) * 4);
  int* bsum  = (int*)take(NB_SCAN * 4);
  int* ic    = (int*)take(NN * 4);
  float* onrm = (float*)take(NN * 4);
  float* inrm = (float*)take(NN * 4);
  int* csr   = (int*)take((size_t)NE * 4);
  __half* tbuf = (__half*)take((size_t)NN * D * 2);   // fp16 staging (25.6 MB)
  float* ubuf = (float*)take((size_t)NN * D * 4);
  (void)ws_size; (void)in_sizes; (void)n_in; (void)out_size;

  // packed partial histograms alias ubuf (29.4 MB <= 51.2 MB);
  // CSR build completes before gather first writes ubuf
  int* H = (int*)ubuf;

  hipMemsetAsync(d_ws, 0, zero_bytes, stream);
  dim3 hgrid(NCHUNK, NPART);
  k_hist<<<hgrid, 256, 0, stream>>>(src, dst, H);
  k_reduce<<<(NN + 255) / 256, 256, 0, stream>>>(H, ic, onrm, inrm);
  k_scan_a<<<NB_SCAN, 256, 0, stream>>>(ic, bsum);
  k_scan_b<<<1, 128, 0, stream>>>(bsum, off);
  k_scan_c<<<NB_SCAN, 256, 0, stream>>>(ic, bsum, off);
  k_start<<<(NN + 255) / 256, 256, 0, stream>>>(H, off);
  k_fill2<<<hgrid, 256, 0, stream>>>(src, dst, H, csr);

  // layer 1: t = fp16((h * onrm) @ W1); h1 = relu(inrm * gather(t) + b1)
  k_matmul<<<(NN + BM - 1) / BM, 256, 0, stream>>>(h, W1, onrm, tbuf);
  k_gather<<<(NN * 64) / 256, 256, 0, stream>>>(tbuf, csr, off, inrm, b1, ubuf);
  // layer 2
  k_matmul<<<(NN + BM - 1) / BM, 256, 0, stream>>>(ubuf, W2, onrm, tbuf);
  k_gather<<<(NN * 64) / 256, 256, 0, stream>>>(tbuf, csr, off, inrm, b2, ubuf);

  k_pool_partial<<<(NN + POOL_CHUNK - 1) / POOL_CHUNK, 128, 0, stream>>>(ubuf, n2g, sums);
  k_mlp<<<NG, 128, 0, stream>>>(sums, n2g, Wc1, bc1, Wc2, bc2, Wc3, bc3, out);
}

// Round 11
// 346.897 us; speedup vs baseline: 3.3363x; 1.0291x over previous
//
#include <hip/hip_runtime.h>
#include <hip/hip_fp16.h>

#define NN 100000
#define NE 1600000
#define D 128
#define NG 64
#define BM 64
#define KT 32
#define POOL_CHUNK 64
#define SCAN_CHUNK 1024
#define NB_SCAN ((NN + SCAN_CHUNK - 1) / SCAN_CHUNK)   // 98

// CSR-build tiling: 64 edge chunks x 7 node partitions of 16384
// packed counters: low 16 bits = in-degree (dst), high 16 = out-degree (src)
#define NCHUNK 64
#define CH_E (NE / NCHUNK)          // 25000 edges per chunk
#define HP 16384                    // nodes per partition (64 KB LDS counters)
#define NPART 7                     // 7*16384 = 114688 >= NN
#define HSTRIDE (NPART * HP)

__device__ __forceinline__ int lower_bound_i(const int* a, int n, int key) {
  int lo = 0, hi = n;
  while (lo < hi) { int mid = (lo + hi) >> 1; if (a[mid] < key) lo = mid + 1; else hi = mid; }
  return lo;
}

// partial packed histograms per (chunk, partition): LDS atomics only
__global__ __launch_bounds__(256) void k_hist(
    const int* __restrict__ src, const int* __restrict__ dst,
    int* __restrict__ H) {
  __shared__ int pk[HP];
  const int c = blockIdx.x, p = blockIdx.y, t = threadIdx.x;
  const int base = p * HP;
  for (int i = t; i < HP; i += 256) pk[i] = 0;
  __syncthreads();
  const int4* s4 = (const int4*)(src + c * CH_E);
  const int4* d4 = (const int4*)(dst + c * CH_E);
  const int n4 = CH_E / 4;  // 6250
  for (int i = t; i < n4; i += 256) {
    int4 s = s4[i], d = d4[i];
    if ((unsigned)(d.x - base) < HP) atomicAdd(&pk[d.x - base], 1);
    if ((unsigned)(d.y - base) < HP) atomicAdd(&pk[d.y - base], 1);
    if ((unsigned)(d.z - base) < HP) atomicAdd(&pk[d.z - base], 1);
    if ((unsigned)(d.w - base) < HP) atomicAdd(&pk[d.w - base], 1);
    if ((unsigned)(s.x - base) < HP) atomicAdd(&pk[s.x - base], 65536);
    if ((unsigned)(s.y - base) < HP) atomicAdd(&pk[s.y - base], 65536);
    if ((unsigned)(s.z - base) < HP) atomicAdd(&pk[s.z - base], 65536);
    if ((unsigned)(s.w - base) < HP) atomicAdd(&pk[s.w - base], 65536);
  }
  __syncthreads();
  size_t rb = (size_t)c * HSTRIDE + base;
  for (int i = t; i < HP; i += 256) H[rb + i] = pk[i];
}

// reduce packed partials over chunks -> in-degree (for scan) + both norms
__global__ __launch_bounds__(256) void k_reduce(
    const int* __restrict__ H,
    int* __restrict__ ic, float* __restrict__ onrm, float* __restrict__ inrm) {
  int n = blockIdx.x * 256 + threadIdx.x;
  if (n >= NN) return;
  int si = 0, so = 0;
#pragma unroll 8
  for (int c = 0; c < NCHUNK; ++c) {
    unsigned v = (unsigned)H[(size_t)c * HSTRIDE + n];
    si += (int)(v & 0xffffu);
    so += (int)(v >> 16);
  }
  ic[n] = si;
  inrm[n] = 1.0f / sqrtf((float)max(si, 1));
  onrm[n] = 1.0f / sqrtf((float)max(so, 1));
}

// phase A: per-block chunk sums (coalesced int4, shuffle reduce)
__global__ __launch_bounds__(256) void k_scan_a(const int* __restrict__ cnt,
                                                int* __restrict__ bsum) {
  int b = blockIdx.x, t = threadIdx.x;
  int idx = b * SCAN_CHUNK + t * 4;
  int4 v = make_int4(0, 0, 0, 0);
  if (idx < NN) v = *(const int4*)(cnt + idx);   // NN % 4 == 0
  int s = v.x + v.y + v.z + v.w;
#pragma unroll
  for (int o = 1; o < 64; o <<= 1) s += __shfl_xor(s, o);
  __shared__ int ws[4];
  if ((t & 63) == 0) ws[t >> 6] = s;
  __syncthreads();
  if (t == 0) bsum[b] = ws[0] + ws[1] + ws[2] + ws[3];
}

// phase B: exclusive scan of the 98 block sums (in place), set off[NN]
__global__ void k_scan_b(int* __restrict__ bsum, int* __restrict__ off) {
  __shared__ int s[128];
  int t = threadIdx.x;
  int v = (t < NB_SCAN) ? bsum[t] : 0;
  s[t] = v;
  __syncthreads();
  for (int o = 1; o < 128; o <<= 1) {
    int u = (t >= o) ? s[t - o] : 0;
    __syncthreads();
    s[t] += u;
    __syncthreads();
  }
  if (t < NB_SCAN) bsum[t] = s[t] - v;  // exclusive prefix
  if (t == 0) off[NN] = NE;
}

// phase C: intra-block exclusive scan + block prefix -> off[]
__global__ __launch_bounds__(256) void k_scan_c(const int* __restrict__ cnt,
                                                const int* __restrict__ bsum,
                                                int* __restrict__ off) {
  int b = blockIdx.x, t = threadIdx.x;
  int idx = b * SCAN_CHUNK + t * 4;
  int4 v = make_int4(0, 0, 0, 0);
  if (idx < NN) v = *(const int4*)(cnt + idx);
  int lsum = v.x + v.y + v.z + v.w;
  int lane = t & 63, wid = t >> 6;
  int x = lsum;
#pragma unroll
  for (int o = 1; o < 64; o <<= 1) {
    int u = __shfl_up(x, o);
    if (lane >= o) x += u;
  }
  __shared__ int wsum[4];
  if (lane == 63) wsum[wid] = x;
  __syncthreads();
  int woff = 0;
  for (int i = 0; i < 4; ++i) woff += (i < wid) ? wsum[i] : 0;
  int excl = x - lsum + woff + bsum[b];
  if (idx < NN) {
    int4 o4;
    o4.x = excl;
    o4.y = excl + v.x;
    o4.z = o4.y + v.y;
    o4.w = o4.z + v.z;
    *(int4*)(off + idx) = o4;
  }
}

// column-wise running offsets: H[c][n] <- off[n] + sum_{c'<c} in(H[c'][n])
__global__ __launch_bounds__(256) void k_start(int* __restrict__ H,
                                               const int* __restrict__ off) {
  int n = blockIdx.x * 256 + threadIdx.x;
  if (n >= NN) return;
  int run = off[n];
#pragma unroll 8
  for (int c = 0; c < NCHUNK; ++c) {
    size_t idx = (size_t)c * HSTRIDE + n;
    int v = H[idx];
    H[idx] = run;
    run += (int)((unsigned)v & 0xffffu);
  }
}

// fill CSR: LDS cursors (absolute positions), plain global stores
__global__ __launch_bounds__(256) void k_fill2(
    const int* __restrict__ src, const int* __restrict__ dst,
    const int* __restrict__ H, int* __restrict__ csr) {
  __shared__ int cur[HP];
  const int c = blockIdx.x, p = blockIdx.y, t = threadIdx.x;
  const int base = p * HP;
  size_t rb = (size_t)c * HSTRIDE + base;
  for (int i = t; i < HP; i += 256) cur[i] = H[rb + i];
  __syncthreads();
  const int4* s4 = (const int4*)(src + c * CH_E);
  const int4* d4 = (const int4*)(dst + c * CH_E);
  const int n4 = CH_E / 4;
  for (int i = t; i < n4; i += 256) {
    int4 s = s4[i], d = d4[i];
    if ((unsigned)(d.x - base) < HP) { int pos = atomicAdd(&cur[d.x - base], 1); csr[pos] = s.x; }
    if ((unsigned)(d.y - base) < HP) { int pos = atomicAdd(&cur[d.y - base], 1); csr[pos] = s.y; }
    if ((unsigned)(d.z - base) < HP) { int pos = atomicAdd(&cur[d.z - base], 1); csr[pos] = s.z; }
    if ((unsigned)(d.w - base) < HP) { int pos = atomicAdd(&cur[d.w - base], 1); csr[pos] = s.w; }
  }
}

// C[r,:] = fp16( rs[r] * (A[r,:] @ W) )
// A-tile (33 KB) + K-tiled W (16 KB) in LDS -> 50 KB, 3 blocks/CU
__global__ __launch_bounds__(256, 3) void k_matmul(
    const float* __restrict__ A, const float* __restrict__ W,
    const float* __restrict__ rs, __half* __restrict__ C) {
  __shared__ float As[BM][132];     // pad 132: bank spread
  __shared__ float Ws[KT][128];
  const int tid = threadIdx.x;
  const int row0 = blockIdx.x * BM;
#pragma unroll
  for (int i = 0; i < 8; ++i) {
    int idx = tid + i * 256;        // 0..2047 float4 slots (64 rows x 32)
    int r = idx >> 5;
    int c4 = idx & 31;
    int grow = row0 + r;
    float4 v = make_float4(0.f, 0.f, 0.f, 0.f);
    if (grow < NN) {
      v = *(const float4*)(A + (size_t)grow * D + c4 * 4);
      float sc = rs[grow];
      v.x *= sc; v.y *= sc; v.z *= sc; v.w *= sc;
    }
    *(float4*)&As[r][c4 * 4] = v;
  }
  const int tx = tid & 15, ty = tid >> 4;
  const int r0 = ty * 4, c0 = tx * 4;
  float acc[4][8];
#pragma unroll
  for (int i = 0; i < 4; ++i)
#pragma unroll
    for (int j = 0; j < 8; ++j) acc[i][j] = 0.f;

  for (int k0 = 0; k0 < 128; k0 += KT) {
    __syncthreads();   // As ready (iter 0) / prev Ws-tile consumed
#pragma unroll
    for (int i = 0; i < 4; ++i) {
      int idx = tid + i * 256;      // 0..1023 float4 slots (32 rows x 32)
      int kk = idx >> 5;
      int c4 = idx & 31;
      *(float4*)&Ws[kk][c4 * 4] = *(const float4*)&W[(size_t)(k0 + kk) * 128 + c4 * 4];
    }
    __syncthreads();
#pragma unroll
    for (int kk = 0; kk < KT; ++kk) {
      float4 w0 = *(const float4*)&Ws[kk][c0];        // cols c0..c0+3
      float4 w1 = *(const float4*)&Ws[kk][c0 + 64];   // cols 64+c0..
      int k = k0 + kk;
      float av[4];
      av[0] = As[r0 + 0][k]; av[1] = As[r0 + 1][k];
      av[2] = As[r0 + 2][k]; av[3] = As[r0 + 3][k];
#pragma unroll
      for (int i = 0; i < 4; ++i) {
        acc[i][0] = fmaf(av[i], w0.x, acc[i][0]);
        acc[i][1] = fmaf(av[i], w0.y, acc[i][1]);
        acc[i][2] = fmaf(av[i], w0.z, acc[i][2]);
        acc[i][3] = fmaf(av[i], w0.w, acc[i][3]);
        acc[i][4] = fmaf(av[i], w1.x, acc[i][4]);
        acc[i][5] = fmaf(av[i], w1.y, acc[i][5]);
        acc[i][6] = fmaf(av[i], w1.z, acc[i][6]);
        acc[i][7] = fmaf(av[i], w1.w, acc[i][7]);
      }
    }
  }
#pragma unroll
  for (int i = 0; i < 4; ++i) {
    int row = row0 + r0 + i;
    if (row < NN) {
      ushort4 p0, p1;
      p0.x = __half_as_ushort(__float2half_rn(acc[i][0]));
      p0.y = __half_as_ushort(__float2half_rn(acc[i][1]));
      p0.z = __half_as_ushort(__float2half_rn(acc[i][2]));
      p0.w = __half_as_ushort(__float2half_rn(acc[i][3]));
      p1.x = __half_as_ushort(__float2half_rn(acc[i][4]));
      p1.y = __half_as_ushort(__float2half_rn(acc[i][5]));
      p1.z = __half_as_ushort(__float2half_rn(acc[i][6]));
      p1.w = __half_as_ushort(__float2half_rn(acc[i][7]));
      *(ushort4*)(C + (size_t)row * D + c0) = p0;        // 8B packed, coalesced
      *(ushort4*)(C + (size_t)row * D + 64 + c0) = p1;
    }
  }
}

// out[d,:] = relu(in_norm[d] * sum_{s in CSR(d)} t[s,:] + bias)
// one wave per dst node; 4 lane-groups of 16 process 4 edges/step,
// each lane loads 16B (8 halves). Unrolled x2: two independent row loads
// in flight per subgroup (VGPR headroom -> MLP), shfl_xor combine at end.
__global__ __launch_bounds__(256) void k_gather(
    const __half* __restrict__ t, const int* __restrict__ csr,
    const int* __restrict__ off, const float* __restrict__ inn,
    const float* __restrict__ bias, float* __restrict__ outp) {
  int w = (blockIdx.x * blockDim.x + threadIdx.x) >> 6;
  int lane = threadIdx.x & 63;
  if (w >= NN) return;
  int lo = off[w], hi = off[w + 1];
  const int g = lane >> 4;        // edge subgroup 0..3
  const int li = lane & 15;       // 16B column slot
  const __half* tp = t + li * 8;
  float a0 = 0.f, a1 = 0.f, a2 = 0.f, a3 = 0.f;
  float a4 = 0.f, a5 = 0.f, a6 = 0.f, a7 = 0.f;
  int e = lo + g;
  for (; e + 4 < hi; e += 8) {
    int s0 = csr[e];
    int s1 = csr[e + 4];
    float4 r0 = *(const float4*)(tp + (size_t)s0 * D);
    float4 r1 = *(const float4*)(tp + (size_t)s1 * D);
    const __half2* h0 = (const __half2*)&r0;
    const __half2* h1 = (const __half2*)&r1;
    float2 f00 = __half22float2(h0[0]);
    float2 f01 = __half22float2(h0[1]);
    float2 f02 = __half22float2(h0[2]);
    float2 f03 = __half22float2(h0[3]);
    float2 f10 = __half22float2(h1[0]);
    float2 f11 = __half22float2(h1[1]);
    float2 f12 = __half22float2(h1[2]);
    float2 f13 = __half22float2(h1[3]);
    a0 += f00.x + f10.x; a1 += f00.y + f10.y;
    a2 += f01.x + f11.x; a3 += f01.y + f11.y;
    a4 += f02.x + f12.x; a5 += f02.y + f12.y;
    a6 += f03.x + f13.x; a7 += f03.y + f13.y;
  }
  if (e < hi) {
    int s0 = csr[e];
    float4 r0 = *(const float4*)(tp + (size_t)s0 * D);
    const __half2* h0 = (const __half2*)&r0;
    float2 f00 = __half22float2(h0[0]);
    float2 f01 = __half22float2(h0[1]);
    float2 f02 = __half22float2(h0[2]);
    float2 f03 = __half22float2(h0[3]);
    a0 += f00.x; a1 += f00.y; a2 += f01.x; a3 += f01.y;
    a4 += f02.x; a5 += f02.y; a6 += f03.x; a7 += f03.y;
  }
  // combine the 4 edge subgroups (lanes l, l+16, l+32, l+48 hold same cols)
  a0 += __shfl_xor(a0, 16); a0 += __shfl_xor(a0, 32);
  a1 += __shfl_xor(a1, 16); a1 += __shfl_xor(a1, 32);
  a2 += __shfl_xor(a2, 16); a2 += __shfl_xor(a2, 32);
  a3 += __shfl_xor(a3, 16); a3 += __shfl_xor(a3, 32);
  a4 += __shfl_xor(a4, 16); a4 += __shfl_xor(a4, 32);
  a5 += __shfl_xor(a5, 16); a5 += __shfl_xor(a5, 32);
  a6 += __shfl_xor(a6, 16); a6 += __shfl_xor(a6, 32);
  a7 += __shfl_xor(a7, 16); a7 += __shfl_xor(a7, 32);
  if (lane < 16) {
    float nm = inn[w];
    float4 b0 = *(const float4*)(bias + li * 8);
    float4 b1 = *(const float4*)(bias + li * 8 + 4);
    float4 o0, o1;
    o0.x = fmaxf(fmaf(nm, a0, b0.x), 0.f);
    o0.y = fmaxf(fmaf(nm, a1, b0.y), 0.f);
    o0.z = fmaxf(fmaf(nm, a2, b0.z), 0.f);
    o0.w = fmaxf(fmaf(nm, a3, b0.w), 0.f);
    o1.x = fmaxf(fmaf(nm, a4, b1.x), 0.f);
    o1.y = fmaxf(fmaf(nm, a5, b1.y), 0.f);
    o1.z = fmaxf(fmaf(nm, a6, b1.z), 0.f);
    o1.w = fmaxf(fmaf(nm, a7, b1.w), 0.f);
    *(float4*)(outp + (size_t)w * D + li * 8) = o0;
    *(float4*)(outp + (size_t)w * D + li * 8 + 4) = o1;
  }
}

// parallel pool partial sums: block = 64-node chunk, thread = col (coalesced)
__global__ __launch_bounds__(128) void k_pool_partial(
    const float* __restrict__ h2, const int* __restrict__ n2g,
    float* __restrict__ sums) {
  int c = threadIdx.x;
  int n0 = blockIdx.x * POOL_CHUNK;
  int n1 = min(n0 + POOL_CHUNK, NN);
  if (n0 >= NN) return;
  int gcur = n2g[n0];
  float acc = 0.f;
  for (int n = n0; n < n1; ++n) {
    int g = n2g[n];
    if (g != gcur) {
      atomicAdd(&sums[gcur * D + c], acc);
      acc = 0.f;
      gcur = g;
    }
    acc += h2[(size_t)n * D + c];
  }
  atomicAdd(&sums[gcur * D + c], acc);
}

// 3-layer MLP head; one block per graph, 128 threads. Divides sums by count.
__global__ void k_mlp(const float* __restrict__ sums, const int* __restrict__ n2g,
                      const float* __restrict__ Wc1, const float* __restrict__ bc1,
                      const float* __restrict__ Wc2, const float* __restrict__ bc2,
                      const float* __restrict__ Wc3, const float* __restrict__ bc3,
                      float* __restrict__ out) {
  __shared__ float xin[128];
  __shared__ float x1[128];
  __shared__ float red[128];
  int g = blockIdx.x, j = threadIdx.x;
  int start = lower_bound_i(n2g, NN, g);
  int end = lower_bound_i(n2g, NN, g + 1);
  float inv = 1.0f / (float)max(end - start, 1);
  xin[j] = sums[g * D + j] * inv;
  __syncthreads();
  float s = bc1[j];
#pragma unroll 8
  for (int k = 0; k < 128; ++k) s = fmaf(xin[k], Wc1[k * D + j], s);
  x1[j] = fmaxf(s, 0.f);
  __syncthreads();
  float s2 = bc2[j];
#pragma unroll 8
  for (int k = 0; k < 128; ++k) s2 = fmaf(x1[k], Wc2[k * D + j], s2);
  float v2 = fmaxf(s2, 0.f);
  red[j] = v2 * Wc3[j];
  __syncthreads();
  for (int o = 64; o > 0; o >>= 1) {
    if (j < o) red[j] += red[j + o];
    __syncthreads();
  }
  if (j == 0) out[g] = red[0] + bc3[0];
}

extern "C" void kernel_launch(void* const* d_in, const int* in_sizes, int n_in,
                              void* d_out, int out_size, void* d_ws, size_t ws_size,
                              hipStream_t stream) {
  const float* h   = (const float*)d_in[0];
  const int* src   = (const int*)d_in[1];
  const int* dst   = (const int*)d_in[2];
  const int* n2g   = (const int*)d_in[3];
  const float* W1  = (const float*)d_in[4];
  const float* b1  = (const float*)d_in[5];
  const float* W2  = (const float*)d_in[6];
  const float* b2  = (const float*)d_in[7];
  const float* Wc1 = (const float*)d_in[8];
  const float* bc1 = (const float*)d_in[9];
  const float* Wc2 = (const float*)d_in[10];
  const float* bc2 = (const float*)d_in[11];
  const float* Wc3 = (const float*)d_in[12];
  const float* bc3 = (const float*)d_in[13];
  float* out = (float*)d_out;

  char* p = (char*)d_ws;
  size_t o = 0;
  auto take = [&](size_t b) { void* q = p + o; o = (o + b + 255) & ~(size_t)255; return q; };
  float* sums = (float*)take(NG * D * 4);
  size_t zero_bytes = o;                    // zero pool sums only
  int* off   = (int*)take((NN + 1) * 4);
  int* bsum  = (int*)take(NB_SCAN * 4);
  int* ic    = (int*)take(NN * 4);
  float* onrm = (float*)take(NN * 4);
  float* inrm = (float*)take(NN * 4);
  int* csr   = (int*)take((size_t)NE * 4);
  __half* tbuf = (__half*)take((size_t)NN * D * 2);   // fp16 staging (25.6 MB)
  float* ubuf = (float*)take((size_t)NN * D * 4);
  (void)ws_size; (void)in_sizes; (void)n_in; (void)out_size;

  // packed partial histograms alias ubuf (29.4 MB <= 51.2 MB);
  // CSR build completes before gather first writes ubuf
  int* H = (int*)ubuf;

  hipMemsetAsync(d_ws, 0, zero_bytes, stream);
  dim3 hgrid(NCHUNK, NPART);
  k_hist<<<hgrid, 256, 0, stream>>>(src, dst, H);
  k_reduce<<<(NN + 255) / 256, 256, 0, stream>>>(H, ic, onrm, inrm);
  k_scan_a<<<NB_SCAN, 256, 0, stream>>>(ic, bsum);
  k_scan_b<<<1, 128, 0, stream>>>(bsum, off);
  k_scan_c<<<NB_SCAN, 256, 0, stream>>>(ic, bsum, off);
  k_start<<<(NN + 255) / 256, 256, 0, stream>>>(H, off);
  k_fill2<<<hgrid, 256, 0, stream>>>(src, dst, H, csr);

  // layer 1: t = fp16((h * onrm) @ W1); h1 = relu(inrm * gather(t) + b1)
  k_matmul<<<(NN + BM - 1) / BM, 256, 0, stream>>>(h, W1, onrm, tbuf);
  k_gather<<<(NN * 64) / 256, 256, 0, stream>>>(tbuf, csr, off, inrm, b1, ubuf);
  // layer 2
  k_matmul<<<(NN + BM - 1) / BM, 256, 0, stream>>>(ubuf, W2, onrm, tbuf);
  k_gather<<<(NN * 64) / 256, 256, 0, stream>>>(tbuf, csr, off, inrm, b2, ubuf);

  k_pool_partial<<<(NN + POOL_CHUNK - 1) / POOL_CHUNK, 128, 0, stream>>>(ubuf, n2g, sums);
  k_mlp<<<NG, 128, 0, stream>>>(sums, n2g, Wc1, bc1, Wc2, bc2, Wc3, bc3, out);
}

// Round 12
// 275.980 us; speedup vs baseline: 4.1936x; 1.2570x over previous
//
#include <hip/hip_runtime.h>
#include <hip/hip_fp16.h>

#define NN 100000
#define NE 1600000
#define D 128
#define NG 64
#define BM 64
#define POOL_CHUNK 64
#define SCAN_CHUNK 1024
#define NB_SCAN ((NN + SCAN_CHUNK - 1) / SCAN_CHUNK)   // 98

// CSR-build tiling: 64 edge chunks x 7 node partitions of 16384
// packed counters: low 16 bits = in-degree (dst), high 16 = out-degree (src)
#define NCHUNK 64
#define CH_E (NE / NCHUNK)          // 25000 edges per chunk
#define HP 16384                    // nodes per partition (64 KB LDS counters)
#define NPART 7                     // 7*16384 = 114688 >= NN
#define HSTRIDE (NPART * HP)

typedef _Float16 half8 __attribute__((ext_vector_type(8)));
typedef float f32x4 __attribute__((ext_vector_type(4)));

__device__ __forceinline__ int lower_bound_i(const int* a, int n, int key) {
  int lo = 0, hi = n;
  while (lo < hi) { int mid = (lo + hi) >> 1; if (a[mid] < key) lo = mid + 1; else hi = mid; }
  return lo;
}

// partial packed histograms per (chunk, partition): LDS atomics only
__global__ __launch_bounds__(256) void k_hist(
    const int* __restrict__ src, const int* __restrict__ dst,
    int* __restrict__ H) {
  __shared__ int pk[HP];
  const int c = blockIdx.x, p = blockIdx.y, t = threadIdx.x;
  const int base = p * HP;
  for (int i = t; i < HP; i += 256) pk[i] = 0;
  __syncthreads();
  const int4* s4 = (const int4*)(src + c * CH_E);
  const int4* d4 = (const int4*)(dst + c * CH_E);
  const int n4 = CH_E / 4;  // 6250
  for (int i = t; i < n4; i += 256) {
    int4 s = s4[i], d = d4[i];
    if ((unsigned)(d.x - base) < HP) atomicAdd(&pk[d.x - base], 1);
    if ((unsigned)(d.y - base) < HP) atomicAdd(&pk[d.y - base], 1);
    if ((unsigned)(d.z - base) < HP) atomicAdd(&pk[d.z - base], 1);
    if ((unsigned)(d.w - base) < HP) atomicAdd(&pk[d.w - base], 1);
    if ((unsigned)(s.x - base) < HP) atomicAdd(&pk[s.x - base], 65536);
    if ((unsigned)(s.y - base) < HP) atomicAdd(&pk[s.y - base], 65536);
    if ((unsigned)(s.z - base) < HP) atomicAdd(&pk[s.z - base], 65536);
    if ((unsigned)(s.w - base) < HP) atomicAdd(&pk[s.w - base], 65536);
  }
  __syncthreads();
  size_t rb = (size_t)c * HSTRIDE + base;
  for (int i = t; i < HP; i += 256) H[rb + i] = pk[i];
}

// reduce packed partials over chunks -> in-degree (for scan) + both norms
__global__ __launch_bounds__(256) void k_reduce(
    const int* __restrict__ H,
    int* __restrict__ ic, float* __restrict__ onrm, float* __restrict__ inrm) {
  int n = blockIdx.x * 256 + threadIdx.x;
  if (n >= NN) return;
  int si = 0, so = 0;
#pragma unroll 8
  for (int c = 0; c < NCHUNK; ++c) {
    unsigned v = (unsigned)H[(size_t)c * HSTRIDE + n];
    si += (int)(v & 0xffffu);
    so += (int)(v >> 16);
  }
  ic[n] = si;
  inrm[n] = 1.0f / sqrtf((float)max(si, 1));
  onrm[n] = 1.0f / sqrtf((float)max(so, 1));
}

// phase A: per-block chunk sums (coalesced int4, shuffle reduce)
__global__ __launch_bounds__(256) void k_scan_a(const int* __restrict__ cnt,
                                                int* __restrict__ bsum) {
  int b = blockIdx.x, t = threadIdx.x;
  int idx = b * SCAN_CHUNK + t * 4;
  int4 v = make_int4(0, 0, 0, 0);
  if (idx < NN) v = *(const int4*)(cnt + idx);   // NN % 4 == 0
  int s = v.x + v.y + v.z + v.w;
#pragma unroll
  for (int o = 1; o < 64; o <<= 1) s += __shfl_xor(s, o);
  __shared__ int ws[4];
  if ((t & 63) == 0) ws[t >> 6] = s;
  __syncthreads();
  if (t == 0) bsum[b] = ws[0] + ws[1] + ws[2] + ws[3];
}

// phase B: exclusive scan of the 98 block sums (in place), set off[NN]
__global__ void k_scan_b(int* __restrict__ bsum, int* __restrict__ off) {
  __shared__ int s[128];
  int t = threadIdx.x;
  int v = (t < NB_SCAN) ? bsum[t] : 0;
  s[t] = v;
  __syncthreads();
  for (int o = 1; o < 128; o <<= 1) {
    int u = (t >= o) ? s[t - o] : 0;
    __syncthreads();
    s[t] += u;
    __syncthreads();
  }
  if (t < NB_SCAN) bsum[t] = s[t] - v;  // exclusive prefix
  if (t == 0) off[NN] = NE;
}

// phase C: intra-block exclusive scan + block prefix -> off[]
__global__ __launch_bounds__(256) void k_scan_c(const int* __restrict__ cnt,
                                                const int* __restrict__ bsum,
                                                int* __restrict__ off) {
  int b = blockIdx.x, t = threadIdx.x;
  int idx = b * SCAN_CHUNK + t * 4;
  int4 v = make_int4(0, 0, 0, 0);
  if (idx < NN) v = *(const int4*)(cnt + idx);
  int lsum = v.x + v.y + v.z + v.w;
  int lane = t & 63, wid = t >> 6;
  int x = lsum;
#pragma unroll
  for (int o = 1; o < 64; o <<= 1) {
    int u = __shfl_up(x, o);
    if (lane >= o) x += u;
  }
  __shared__ int wsum[4];
  if (lane == 63) wsum[wid] = x;
  __syncthreads();
  int woff = 0;
  for (int i = 0; i < 4; ++i) woff += (i < wid) ? wsum[i] : 0;
  int excl = x - lsum + woff + bsum[b];
  if (idx < NN) {
    int4 o4;
    o4.x = excl;
    o4.y = excl + v.x;
    o4.z = o4.y + v.y;
    o4.w = o4.z + v.z;
    *(int4*)(off + idx) = o4;
  }
}

// column-wise running offsets: H[c][n] <- off[n] + sum_{c'<c} in(H[c'][n])
__global__ __launch_bounds__(256) void k_start(int* __restrict__ H,
                                               const int* __restrict__ off) {
  int n = blockIdx.x * 256 + threadIdx.x;
  if (n >= NN) return;
  int run = off[n];
#pragma unroll 8
  for (int c = 0; c < NCHUNK; ++c) {
    size_t idx = (size_t)c * HSTRIDE + n;
    int v = H[idx];
    H[idx] = run;
    run += (int)((unsigned)v & 0xffffu);
  }
}

// fill CSR: LDS cursors (absolute positions), plain global stores
__global__ __launch_bounds__(256) void k_fill2(
    const int* __restrict__ src, const int* __restrict__ dst,
    const int* __restrict__ H, int* __restrict__ csr) {
  __shared__ int cur[HP];
  const int c = blockIdx.x, p = blockIdx.y, t = threadIdx.x;
  const int base = p * HP;
  size_t rb = (size_t)c * HSTRIDE + base;
  for (int i = t; i < HP; i += 256) cur[i] = H[rb + i];
  __syncthreads();
  const int4* s4 = (const int4*)(src + c * CH_E);
  const int4* d4 = (const int4*)(dst + c * CH_E);
  const int n4 = CH_E / 4;
  for (int i = t; i < n4; i += 256) {
    int4 s = s4[i], d = d4[i];
    if ((unsigned)(d.x - base) < HP) { int pos = atomicAdd(&cur[d.x - base], 1); csr[pos] = s.x; }
    if ((unsigned)(d.y - base) < HP) { int pos = atomicAdd(&cur[d.y - base], 1); csr[pos] = s.y; }
    if ((unsigned)(d.z - base) < HP) { int pos = atomicAdd(&cur[d.z - base], 1); csr[pos] = s.z; }
    if ((unsigned)(d.w - base) < HP) { int pos = atomicAdd(&cur[d.w - base], 1); csr[pos] = s.w; }
  }
}

// MFMA matmul: t[r][c] = fp16( rs[r] * (A[r,:] @ W) ), fp32 A in, fp32 accum.
// Block = 64 rows (4 waves x 16), full 128 cols. W staged once as fp16
// transposed Wt[c][k] in LDS (pad 136 halves, k8-XOR swizzle -> b128 frag reads).
__global__ __launch_bounds__(256, 4) void k_matmul(
    const float* __restrict__ A, const float* __restrict__ W,
    const float* __restrict__ rs, __half* __restrict__ C) {
  __shared__ _Float16 Wt[128 * 136];
  const int tid = threadIdx.x;
  const int lane = tid & 63, wv = tid >> 6;
  const int row0 = blockIdx.x * BM + wv * 16;
  // stage Wt: thread reads W[k][4c..4c+3] (coalesced float4), writes fp16
  // at Wt[c][k-swizzled]: slot k8' = (k>>3) ^ ((c>>3)&15), offset k&7.
#pragma unroll
  for (int i = 0; i < 16; ++i) {
    int idx = tid + i * 256;              // 0..4095 float4 slots
    int k = idx >> 5, c0 = (idx & 31) * 4;
    float4 w4 = *(const float4*)&W[(size_t)k * 128 + c0];
    int k8 = k >> 3, ko = k & 7;
#pragma unroll
    for (int j = 0; j < 4; ++j) {
      int c = c0 + j;
      int kidx = (((k8 ^ ((c >> 3) & 15)) << 3) | ko);
      float v = (j == 0) ? w4.x : (j == 1) ? w4.y : (j == 2) ? w4.z : w4.w;
      Wt[c * 136 + kidx] = (_Float16)v;
    }
  }
  // A fragments (overlap with staging; no LDS dependency):
  // lane holds A[row0+(lane&15)][kstep*32 + (lane>>4)*8 + j], scaled, fp16
  const int arow = row0 + (lane & 15);
  const bool valid = arow < NN;
  const float sc = valid ? rs[arow] : 0.f;
  half8 afr[4];
  const float* ap = A + (size_t)arow * D + (lane >> 4) * 8;
#pragma unroll
  for (int s = 0; s < 4; ++s) {
    float4 lo = make_float4(0.f, 0.f, 0.f, 0.f), hi = lo;
    if (valid) {
      lo = *(const float4*)(ap + s * 32);
      hi = *(const float4*)(ap + s * 32 + 4);
    }
    half8 a;
    a[0] = (_Float16)(lo.x * sc); a[1] = (_Float16)(lo.y * sc);
    a[2] = (_Float16)(lo.z * sc); a[3] = (_Float16)(lo.w * sc);
    a[4] = (_Float16)(hi.x * sc); a[5] = (_Float16)(hi.y * sc);
    a[6] = (_Float16)(hi.z * sc); a[7] = (_Float16)(hi.w * sc);
    afr[s] = a;
  }
  __syncthreads();
  f32x4 acc[8];
#pragma unroll
  for (int ct = 0; ct < 8; ++ct) acc[ct] = (f32x4){0.f, 0.f, 0.f, 0.f};
#pragma unroll
  for (int s = 0; s < 4; ++s) {
    const int k8 = s * 4 + (lane >> 4);   // fragment k8 slot before swizzle
#pragma unroll
    for (int ct = 0; ct < 8; ++ct) {
      int c = ct * 16 + (lane & 15);
      int kidx = ((k8 ^ ((c >> 3) & 15)) << 3);
      half8 b = *(const half8*)&Wt[c * 136 + kidx];
      acc[ct] = __builtin_amdgcn_mfma_f32_16x16x32_f16(afr[s], b, acc[ct], 0, 0, 0);
    }
  }
  // C/D layout: col = lane&15 (+ct*16), row = row0 + (lane>>4)*4 + r
  const int dcol = lane & 15;
  const int drow0 = row0 + (lane >> 4) * 4;
#pragma unroll
  for (int ct = 0; ct < 8; ++ct) {
#pragma unroll
    for (int r = 0; r < 4; ++r) {
      int row = drow0 + r;
      if (row < NN)
        C[(size_t)row * D + ct * 16 + dcol] = __float2half_rn(acc[ct][r]);
    }
  }
}

// out[d,:] = relu(in_norm[d] * sum_{s in CSR(d)} t[s,:] + bias)
// one wave per dst node; 4 lane-groups of 16 process 4 edges/step,
// each lane loads 16B (8 halves). Unrolled x2: two independent row loads
// in flight per subgroup, shfl_xor combine at end.
__global__ __launch_bounds__(256) void k_gather(
    const __half* __restrict__ t, const int* __restrict__ csr,
    const int* __restrict__ off, const float* __restrict__ inn,
    const float* __restrict__ bias, float* __restrict__ outp) {
  int w = (blockIdx.x * blockDim.x + threadIdx.x) >> 6;
  int lane = threadIdx.x & 63;
  if (w >= NN) return;
  int lo = off[w], hi = off[w + 1];
  const int g = lane >> 4;        // edge subgroup 0..3
  const int li = lane & 15;       // 16B column slot
  const __half* tp = t + li * 8;
  float a0 = 0.f, a1 = 0.f, a2 = 0.f, a3 = 0.f;
  float a4 = 0.f, a5 = 0.f, a6 = 0.f, a7 = 0.f;
  int e = lo + g;
  for (; e + 4 < hi; e += 8) {
    int s0 = csr[e];
    int s1 = csr[e + 4];
    float4 r0 = *(const float4*)(tp + (size_t)s0 * D);
    float4 r1 = *(const float4*)(tp + (size_t)s1 * D);
    const __half2* h0 = (const __half2*)&r0;
    const __half2* h1 = (const __half2*)&r1;
    float2 f00 = __half22float2(h0[0]);
    float2 f01 = __half22float2(h0[1]);
    float2 f02 = __half22float2(h0[2]);
    float2 f03 = __half22float2(h0[3]);
    float2 f10 = __half22float2(h1[0]);
    float2 f11 = __half22float2(h1[1]);
    float2 f12 = __half22float2(h1[2]);
    float2 f13 = __half22float2(h1[3]);
    a0 += f00.x + f10.x; a1 += f00.y + f10.y;
    a2 += f01.x + f11.x; a3 += f01.y + f11.y;
    a4 += f02.x + f12.x; a5 += f02.y + f12.y;
    a6 += f03.x + f13.x; a7 += f03.y + f13.y;
  }
  if (e < hi) {
    int s0 = csr[e];
    float4 r0 = *(const float4*)(tp + (size_t)s0 * D);
    const __half2* h0 = (const __half2*)&r0;
    float2 f00 = __half22float2(h0[0]);
    float2 f01 = __half22float2(h0[1]);
    float2 f02 = __half22float2(h0[2]);
    float2 f03 = __half22float2(h0[3]);
    a0 += f00.x; a1 += f00.y; a2 += f01.x; a3 += f01.y;
    a4 += f02.x; a5 += f02.y; a6 += f03.x; a7 += f03.y;
  }
  a0 += __shfl_xor(a0, 16); a0 += __shfl_xor(a0, 32);
  a1 += __shfl_xor(a1, 16); a1 += __shfl_xor(a1, 32);
  a2 += __shfl_xor(a2, 16); a2 += __shfl_xor(a2, 32);
  a3 += __shfl_xor(a3, 16); a3 += __shfl_xor(a3, 32);
  a4 += __shfl_xor(a4, 16); a4 += __shfl_xor(a4, 32);
  a5 += __shfl_xor(a5, 16); a5 += __shfl_xor(a5, 32);
  a6 += __shfl_xor(a6, 16); a6 += __shfl_xor(a6, 32);
  a7 += __shfl_xor(a7, 16); a7 += __shfl_xor(a7, 32);
  if (lane < 16) {
    float nm = inn[w];
    float4 b0 = *(const float4*)(bias + li * 8);
    float4 b1 = *(const float4*)(bias + li * 8 + 4);
    float4 o0, o1;
    o0.x = fmaxf(fmaf(nm, a0, b0.x), 0.f);
    o0.y = fmaxf(fmaf(nm, a1, b0.y), 0.f);
    o0.z = fmaxf(fmaf(nm, a2, b0.z), 0.f);
    o0.w = fmaxf(fmaf(nm, a3, b0.w), 0.f);
    o1.x = fmaxf(fmaf(nm, a4, b1.x), 0.f);
    o1.y = fmaxf(fmaf(nm, a5, b1.y), 0.f);
    o1.z = fmaxf(fmaf(nm, a6, b1.z), 0.f);
    o1.w = fmaxf(fmaf(nm, a7, b1.w), 0.f);
    *(float4*)(outp + (size_t)w * D + li * 8) = o0;
    *(float4*)(outp + (size_t)w * D + li * 8 + 4) = o1;
  }
}

// parallel pool partial sums: block = 64-node chunk, thread = col (coalesced)
__global__ __launch_bounds__(128) void k_pool_partial(
    const float* __restrict__ h2, const int* __restrict__ n2g,
    float* __restrict__ sums) {
  int c = threadIdx.x;
  int n0 = blockIdx.x * POOL_CHUNK;
  int n1 = min(n0 + POOL_CHUNK, NN);
  if (n0 >= NN) return;
  int gcur = n2g[n0];
  float acc = 0.f;
  for (int n = n0; n < n1; ++n) {
    int g = n2g[n];
    if (g != gcur) {
      atomicAdd(&sums[gcur * D + c], acc);
      acc = 0.f;
      gcur = g;
    }
    acc += h2[(size_t)n * D + c];
  }
  atomicAdd(&sums[gcur * D + c], acc);
}

// 3-layer MLP head; one block per graph, 128 threads. Divides sums by count.
__global__ void k_mlp(const float* __restrict__ sums, const int* __restrict__ n2g,
                      const float* __restrict__ Wc1, const float* __restrict__ bc1,
                      const float* __restrict__ Wc2, const float* __restrict__ bc2,
                      const float* __restrict__ Wc3, const float* __restrict__ bc3,
                      float* __restrict__ out) {
  __shared__ float xin[128];
  __shared__ float x1[128];
  __shared__ float red[128];
  int g = blockIdx.x, j = threadIdx.x;
  int start = lower_bound_i(n2g, NN, g);
  int end = lower_bound_i(n2g, NN, g + 1);
  float inv = 1.0f / (float)max(end - start, 1);
  xin[j] = sums[g * D + j] * inv;
  __syncthreads();
  float s = bc1[j];
#pragma unroll 8
  for (int k = 0; k < 128; ++k) s = fmaf(xin[k], Wc1[k * D + j], s);
  x1[j] = fmaxf(s, 0.f);
  __syncthreads();
  float s2 = bc2[j];
#pragma unroll 8
  for (int k = 0; k < 128; ++k) s2 = fmaf(x1[k], Wc2[k * D + j], s2);
  float v2 = fmaxf(s2, 0.f);
  red[j] = v2 * Wc3[j];
  __syncthreads();
  for (int o = 64; o > 0; o >>= 1) {
    if (j < o) red[j] += red[j + o];
    __syncthreads();
  }
  if (j == 0) out[g] = red[0] + bc3[0];
}

extern "C" void kernel_launch(void* const* d_in, const int* in_sizes, int n_in,
                              void* d_out, int out_size, void* d_ws, size_t ws_size,
                              hipStream_t stream) {
  const float* h   = (const float*)d_in[0];
  const int* src   = (const int*)d_in[1];
  const int* dst   = (const int*)d_in[2];
  const int* n2g   = (const int*)d_in[3];
  const float* W1  = (const float*)d_in[4];
  const float* b1  = (const float*)d_in[5];
  const float* W2  = (const float*)d_in[6];
  const float* b2  = (const float*)d_in[7];
  const float* Wc1 = (const float*)d_in[8];
  const float* bc1 = (const float*)d_in[9];
  const float* Wc2 = (const float*)d_in[10];
  const float* bc2 = (const float*)d_in[11];
  const float* Wc3 = (const float*)d_in[12];
  const float* bc3 = (const float*)d_in[13];
  float* out = (float*)d_out;

  char* p = (char*)d_ws;
  size_t o = 0;
  auto take = [&](size_t b) { void* q = p + o; o = (o + b + 255) & ~(size_t)255; return q; };
  float* sums = (float*)take(NG * D * 4);
  size_t zero_bytes = o;                    // zero pool sums only
  int* off   = (int*)take((NN + 1) * 4);
  int* bsum  = (int*)take(NB_SCAN * 4);
  int* ic    = (int*)take(NN * 4);
  float* onrm = (float*)take(NN * 4);
  float* inrm = (float*)take(NN * 4);
  int* csr   = (int*)take((size_t)NE * 4);
  __half* tbuf = (__half*)take((size_t)NN * D * 2);   // fp16 staging (25.6 MB)
  float* ubuf = (float*)take((size_t)NN * D * 4);
  (void)ws_size; (void)in_sizes; (void)n_in; (void)out_size;

  // packed partial histograms alias ubuf (29.4 MB <= 51.2 MB);
  // CSR build completes before gather first writes ubuf
  int* H = (int*)ubuf;

  hipMemsetAsync(d_ws, 0, zero_bytes, stream);
  dim3 hgrid(NCHUNK, NPART);
  k_hist<<<hgrid, 256, 0, stream>>>(src, dst, H);
  k_reduce<<<(NN + 255) / 256, 256, 0, stream>>>(H, ic, onrm, inrm);
  k_scan_a<<<NB_SCAN, 256, 0, stream>>>(ic, bsum);
  k_scan_b<<<1, 128, 0, stream>>>(bsum, off);
  k_scan_c<<<NB_SCAN, 256, 0, stream>>>(ic, bsum, off);
  k_start<<<(NN + 255) / 256, 256, 0, stream>>>(H, off);
  k_fill2<<<hgrid, 256, 0, stream>>>(src, dst, H, csr);

  // layer 1: t = fp16((h * onrm) @ W1); h1 = relu(inrm * gather(t) + b1)
  k_matmul<<<(NN + BM - 1) / BM, 256, 0, stream>>>(h, W1, onrm, tbuf);
  k_gather<<<(NN * 64) / 256, 256, 0, stream>>>(tbuf, csr, off, inrm, b1, ubuf);
  // layer 2
  k_matmul<<<(NN + BM - 1) / BM, 256, 0, stream>>>(ubuf, W2, onrm, tbuf);
  k_gather<<<(NN * 64) / 256, 256, 0, stream>>>(tbuf, csr, off, inrm, b2, ubuf);

  k_pool_partial<<<(NN + POOL_CHUNK - 1) / POOL_CHUNK, 128, 0, stream>>>(ubuf, n2g, sums);
  k_mlp<<<NG, 128, 0, stream>>>(sums, n2g, Wc1, bc1, Wc2, bc2, Wc3, bc3, out);
}

// Round 13
// 272.549 us; speedup vs baseline: 4.2464x; 1.0126x over previous
//
#include <hip/hip_runtime.h>
#include <hip/hip_fp16.h>

#define NN 100000
#define NE 1600000
#define D 128
#define NG 64
#define BM 64
#define POOL_CHUNK 64
#define SCAN_CHUNK 1024
#define NB_SCAN ((NN + SCAN_CHUNK - 1) / SCAN_CHUNK)   // 98

// CSR-build tiling: 64 edge chunks x 7 node partitions of 16384
// packed counters: low 16 bits = in-degree (dst), high 16 = out-degree (src)
#define NCHUNK 64
#define CH_E (NE / NCHUNK)          // 25000 edges per chunk
#define HP 16384                    // nodes per partition (64 KB LDS counters)
#define NPART 7                     // 7*16384 = 114688 >= NN
#define HSTRIDE (NPART * HP)

typedef _Float16 half8 __attribute__((ext_vector_type(8)));
typedef float f32x4 __attribute__((ext_vector_type(4)));

__device__ __forceinline__ int lower_bound_i(const int* a, int n, int key) {
  int lo = 0, hi = n;
  while (lo < hi) { int mid = (lo + hi) >> 1; if (a[mid] < key) lo = mid + 1; else hi = mid; }
  return lo;
}

// partial packed histograms per (chunk, partition): LDS atomics only
__global__ __launch_bounds__(256) void k_hist(
    const int* __restrict__ src, const int* __restrict__ dst,
    int* __restrict__ H) {
  __shared__ int pk[HP];
  const int c = blockIdx.x, p = blockIdx.y, t = threadIdx.x;
  const int base = p * HP;
  for (int i = t; i < HP; i += 256) pk[i] = 0;
  __syncthreads();
  const int4* s4 = (const int4*)(src + c * CH_E);
  const int4* d4 = (const int4*)(dst + c * CH_E);
  const int n4 = CH_E / 4;  // 6250
  for (int i = t; i < n4; i += 256) {
    int4 s = s4[i], d = d4[i];
    if ((unsigned)(d.x - base) < HP) atomicAdd(&pk[d.x - base], 1);
    if ((unsigned)(d.y - base) < HP) atomicAdd(&pk[d.y - base], 1);
    if ((unsigned)(d.z - base) < HP) atomicAdd(&pk[d.z - base], 1);
    if ((unsigned)(d.w - base) < HP) atomicAdd(&pk[d.w - base], 1);
    if ((unsigned)(s.x - base) < HP) atomicAdd(&pk[s.x - base], 65536);
    if ((unsigned)(s.y - base) < HP) atomicAdd(&pk[s.y - base], 65536);
    if ((unsigned)(s.z - base) < HP) atomicAdd(&pk[s.z - base], 65536);
    if ((unsigned)(s.w - base) < HP) atomicAdd(&pk[s.w - base], 65536);
  }
  __syncthreads();
  size_t rb = (size_t)c * HSTRIDE + base;
  for (int i = t; i < HP; i += 256) H[rb + i] = pk[i];
}

// reduce packed partials over chunks -> in-degree (for scan) + both norms
__global__ __launch_bounds__(256) void k_reduce(
    const int* __restrict__ H,
    int* __restrict__ ic, float* __restrict__ onrm, float* __restrict__ inrm) {
  int n = blockIdx.x * 256 + threadIdx.x;
  if (n >= NN) return;
  int si = 0, so = 0;
#pragma unroll 8
  for (int c = 0; c < NCHUNK; ++c) {
    unsigned v = (unsigned)H[(size_t)c * HSTRIDE + n];
    si += (int)(v & 0xffffu);
    so += (int)(v >> 16);
  }
  ic[n] = si;
  inrm[n] = 1.0f / sqrtf((float)max(si, 1));
  onrm[n] = 1.0f / sqrtf((float)max(so, 1));
}

// phase A: per-block chunk sums (coalesced int4, shuffle reduce)
__global__ __launch_bounds__(256) void k_scan_a(const int* __restrict__ cnt,
                                                int* __restrict__ bsum) {
  int b = blockIdx.x, t = threadIdx.x;
  int idx = b * SCAN_CHUNK + t * 4;
  int4 v = make_int4(0, 0, 0, 0);
  if (idx < NN) v = *(const int4*)(cnt + idx);   // NN % 4 == 0
  int s = v.x + v.y + v.z + v.w;
#pragma unroll
  for (int o = 1; o < 64; o <<= 1) s += __shfl_xor(s, o);
  __shared__ int ws[4];
  if ((t & 63) == 0) ws[t >> 6] = s;
  __syncthreads();
  if (t == 0) bsum[b] = ws[0] + ws[1] + ws[2] + ws[3];
}

// phase B: exclusive scan of the 98 block sums (in place), set off[NN]
__global__ void k_scan_b(int* __restrict__ bsum, int* __restrict__ off) {
  __shared__ int s[128];
  int t = threadIdx.x;
  int v = (t < NB_SCAN) ? bsum[t] : 0;
  s[t] = v;
  __syncthreads();
  for (int o = 1; o < 128; o <<= 1) {
    int u = (t >= o) ? s[t - o] : 0;
    __syncthreads();
    s[t] += u;
    __syncthreads();
  }
  if (t < NB_SCAN) bsum[t] = s[t] - v;  // exclusive prefix
  if (t == 0) off[NN] = NE;
}

// phase C: intra-block exclusive scan + block prefix -> off[]
__global__ __launch_bounds__(256) void k_scan_c(const int* __restrict__ cnt,
                                                const int* __restrict__ bsum,
                                                int* __restrict__ off) {
  int b = blockIdx.x, t = threadIdx.x;
  int idx = b * SCAN_CHUNK + t * 4;
  int4 v = make_int4(0, 0, 0, 0);
  if (idx < NN) v = *(const int4*)(cnt + idx);
  int lsum = v.x + v.y + v.z + v.w;
  int lane = t & 63, wid = t >> 6;
  int x = lsum;
#pragma unroll
  for (int o = 1; o < 64; o <<= 1) {
    int u = __shfl_up(x, o);
    if (lane >= o) x += u;
  }
  __shared__ int wsum[4];
  if (lane == 63) wsum[wid] = x;
  __syncthreads();
  int woff = 0;
  for (int i = 0; i < 4; ++i) woff += (i < wid) ? wsum[i] : 0;
  int excl = x - lsum + woff + bsum[b];
  if (idx < NN) {
    int4 o4;
    o4.x = excl;
    o4.y = excl + v.x;
    o4.z = o4.y + v.y;
    o4.w = o4.z + v.z;
    *(int4*)(off + idx) = o4;
  }
}

// column-wise running offsets: H[c][n] <- off[n] + sum_{c'<c} in(H[c'][n])
__global__ __launch_bounds__(256) void k_start(int* __restrict__ H,
                                               const int* __restrict__ off) {
  int n = blockIdx.x * 256 + threadIdx.x;
  if (n >= NN) return;
  int run = off[n];
#pragma unroll 8
  for (int c = 0; c < NCHUNK; ++c) {
    size_t idx = (size_t)c * HSTRIDE + n;
    int v = H[idx];
    H[idx] = run;
    run += (int)((unsigned)v & 0xffffu);
  }
}

// fill CSR: LDS cursors (absolute positions), plain global stores
__global__ __launch_bounds__(256) void k_fill2(
    const int* __restrict__ src, const int* __restrict__ dst,
    const int* __restrict__ H, int* __restrict__ csr) {
  __shared__ int cur[HP];
  const int c = blockIdx.x, p = blockIdx.y, t = threadIdx.x;
  const int base = p * HP;
  size_t rb = (size_t)c * HSTRIDE + base;
  for (int i = t; i < HP; i += 256) cur[i] = H[rb + i];
  __syncthreads();
  const int4* s4 = (const int4*)(src + c * CH_E);
  const int4* d4 = (const int4*)(dst + c * CH_E);
  const int n4 = CH_E / 4;
  for (int i = t; i < n4; i += 256) {
    int4 s = s4[i], d = d4[i];
    if ((unsigned)(d.x - base) < HP) { int pos = atomicAdd(&cur[d.x - base], 1); csr[pos] = s.x; }
    if ((unsigned)(d.y - base) < HP) { int pos = atomicAdd(&cur[d.y - base], 1); csr[pos] = s.y; }
    if ((unsigned)(d.z - base) < HP) { int pos = atomicAdd(&cur[d.z - base], 1); csr[pos] = s.z; }
    if ((unsigned)(d.w - base) < HP) { int pos = atomicAdd(&cur[d.w - base], 1); csr[pos] = s.w; }
  }
}

// MFMA matmul: t[r][c] = fp16( rs[r] * (A[r,:] @ W) ), fp32 accum.
// A is fp32 (layer 1) or fp16 (layer 2), templated. W staged once as fp16
// transposed Wt[c][k] in LDS (pad 136 halves, k8-XOR swizzle -> b128 frag reads).
template <typename AT>
__global__ __launch_bounds__(256, 4) void k_matmul(
    const AT* __restrict__ A, const float* __restrict__ W,
    const float* __restrict__ rs, __half* __restrict__ C) {
  __shared__ _Float16 Wt[128 * 136];
  const int tid = threadIdx.x;
  const int lane = tid & 63, wv = tid >> 6;
  const int row0 = blockIdx.x * BM + wv * 16;
  // stage Wt: thread reads W[k][4c..4c+3] (coalesced float4), writes fp16
  // at Wt[c][k-swizzled]: slot k8' = (k>>3) ^ ((c>>3)&15), offset k&7.
#pragma unroll
  for (int i = 0; i < 16; ++i) {
    int idx = tid + i * 256;              // 0..4095 float4 slots
    int k = idx >> 5, c0 = (idx & 31) * 4;
    float4 w4 = *(const float4*)&W[(size_t)k * 128 + c0];
    int k8 = k >> 3, ko = k & 7;
#pragma unroll
    for (int j = 0; j < 4; ++j) {
      int c = c0 + j;
      int kidx = (((k8 ^ ((c >> 3) & 15)) << 3) | ko);
      float v = (j == 0) ? w4.x : (j == 1) ? w4.y : (j == 2) ? w4.z : w4.w;
      Wt[c * 136 + kidx] = (_Float16)v;
    }
  }
  // A fragments: lane holds A[row0+(lane&15)][s*32 + (lane>>4)*8 + j], scaled
  const int arow = row0 + (lane & 15);
  const bool valid = arow < NN;
  const float sc = valid ? rs[arow] : 0.f;
  half8 afr[4];
#pragma unroll
  for (int s = 0; s < 4; ++s) {
    half8 a;
    if constexpr (sizeof(AT) == 4) {
      const float* ap = (const float*)A + (size_t)arow * D + (lane >> 4) * 8;
      float4 lo = make_float4(0.f, 0.f, 0.f, 0.f), hi = lo;
      if (valid) {
        lo = *(const float4*)(ap + s * 32);
        hi = *(const float4*)(ap + s * 32 + 4);
      }
      a[0] = (_Float16)(lo.x * sc); a[1] = (_Float16)(lo.y * sc);
      a[2] = (_Float16)(lo.z * sc); a[3] = (_Float16)(lo.w * sc);
      a[4] = (_Float16)(hi.x * sc); a[5] = (_Float16)(hi.y * sc);
      a[6] = (_Float16)(hi.z * sc); a[7] = (_Float16)(hi.w * sc);
    } else {
      const _Float16* ap = (const _Float16*)A + (size_t)arow * D + (lane >> 4) * 8;
      half8 raw = {};
      if (valid) raw = *(const half8*)(ap + s * 32);
#pragma unroll
      for (int j = 0; j < 8; ++j) a[j] = (_Float16)((float)raw[j] * sc);
    }
    afr[s] = a;
  }
  __syncthreads();
  f32x4 acc[8];
#pragma unroll
  for (int ct = 0; ct < 8; ++ct) acc[ct] = (f32x4){0.f, 0.f, 0.f, 0.f};
#pragma unroll
  for (int s = 0; s < 4; ++s) {
    const int k8 = s * 4 + (lane >> 4);   // fragment k8 slot before swizzle
#pragma unroll
    for (int ct = 0; ct < 8; ++ct) {
      int c = ct * 16 + (lane & 15);
      int kidx = ((k8 ^ ((c >> 3) & 15)) << 3);
      half8 b = *(const half8*)&Wt[c * 136 + kidx];
      acc[ct] = __builtin_amdgcn_mfma_f32_16x16x32_f16(afr[s], b, acc[ct], 0, 0, 0);
    }
  }
  // C/D layout: col = lane&15 (+ct*16), row = row0 + (lane>>4)*4 + r
  const int dcol = lane & 15;
  const int drow0 = row0 + (lane >> 4) * 4;
#pragma unroll
  for (int ct = 0; ct < 8; ++ct) {
#pragma unroll
    for (int r = 0; r < 4; ++r) {
      int row = drow0 + r;
      if (row < NN)
        C[(size_t)row * D + ct * 16 + dcol] = __float2half_rn(acc[ct][r]);
    }
  }
}

// out[d,:] = fp16(relu(in_norm[d] * sum_{s in CSR(d)} t[s,:] + bias))
// one wave per dst node; 4 lane-groups of 16 process 4 edges/step,
// each lane loads 16B (8 halves). Unrolled x2: two independent row loads
// in flight per subgroup, shfl_xor combine at end.
__global__ __launch_bounds__(256) void k_gather(
    const __half* __restrict__ t, const int* __restrict__ csr,
    const int* __restrict__ off, const float* __restrict__ inn,
    const float* __restrict__ bias, __half* __restrict__ outp) {
  int w = (blockIdx.x * blockDim.x + threadIdx.x) >> 6;
  int lane = threadIdx.x & 63;
  if (w >= NN) return;
  int lo = off[w], hi = off[w + 1];
  const int g = lane >> 4;        // edge subgroup 0..3
  const int li = lane & 15;       // 16B column slot
  const __half* tp = t + li * 8;
  float a0 = 0.f, a1 = 0.f, a2 = 0.f, a3 = 0.f;
  float a4 = 0.f, a5 = 0.f, a6 = 0.f, a7 = 0.f;
  int e = lo + g;
  for (; e + 4 < hi; e += 8) {
    int s0 = csr[e];
    int s1 = csr[e + 4];
    float4 r0 = *(const float4*)(tp + (size_t)s0 * D);
    float4 r1 = *(const float4*)(tp + (size_t)s1 * D);
    const __half2* h0 = (const __half2*)&r0;
    const __half2* h1 = (const __half2*)&r1;
    float2 f00 = __half22float2(h0[0]);
    float2 f01 = __half22float2(h0[1]);
    float2 f02 = __half22float2(h0[2]);
    float2 f03 = __half22float2(h0[3]);
    float2 f10 = __half22float2(h1[0]);
    float2 f11 = __half22float2(h1[1]);
    float2 f12 = __half22float2(h1[2]);
    float2 f13 = __half22float2(h1[3]);
    a0 += f00.x + f10.x; a1 += f00.y + f10.y;
    a2 += f01.x + f11.x; a3 += f01.y + f11.y;
    a4 += f02.x + f12.x; a5 += f02.y + f12.y;
    a6 += f03.x + f13.x; a7 += f03.y + f13.y;
  }
  if (e < hi) {
    int s0 = csr[e];
    float4 r0 = *(const float4*)(tp + (size_t)s0 * D);
    const __half2* h0 = (const __half2*)&r0;
    float2 f00 = __half22float2(h0[0]);
    float2 f01 = __half22float2(h0[1]);
    float2 f02 = __half22float2(h0[2]);
    float2 f03 = __half22float2(h0[3]);
    a0 += f00.x; a1 += f00.y; a2 += f01.x; a3 += f01.y;
    a4 += f02.x; a5 += f02.y; a6 += f03.x; a7 += f03.y;
  }
  a0 += __shfl_xor(a0, 16); a0 += __shfl_xor(a0, 32);
  a1 += __shfl_xor(a1, 16); a1 += __shfl_xor(a1, 32);
  a2 += __shfl_xor(a2, 16); a2 += __shfl_xor(a2, 32);
  a3 += __shfl_xor(a3, 16); a3 += __shfl_xor(a3, 32);
  a4 += __shfl_xor(a4, 16); a4 += __shfl_xor(a4, 32);
  a5 += __shfl_xor(a5, 16); a5 += __shfl_xor(a5, 32);
  a6 += __shfl_xor(a6, 16); a6 += __shfl_xor(a6, 32);
  a7 += __shfl_xor(a7, 16); a7 += __shfl_xor(a7, 32);
  if (lane < 16) {
    float nm = inn[w];
    float4 b0 = *(const float4*)(bias + li * 8);
    float4 b1 = *(const float4*)(bias + li * 8 + 4);
    float o0 = fmaxf(fmaf(nm, a0, b0.x), 0.f);
    float o1 = fmaxf(fmaf(nm, a1, b0.y), 0.f);
    float o2 = fmaxf(fmaf(nm, a2, b0.z), 0.f);
    float o3 = fmaxf(fmaf(nm, a3, b0.w), 0.f);
    float o4 = fmaxf(fmaf(nm, a4, b1.x), 0.f);
    float o5 = fmaxf(fmaf(nm, a5, b1.y), 0.f);
    float o6 = fmaxf(fmaf(nm, a6, b1.z), 0.f);
    float o7 = fmaxf(fmaf(nm, a7, b1.w), 0.f);
    uint4 u;
    u.x = (unsigned)__half_as_ushort(__float2half_rn(o0)) |
          ((unsigned)__half_as_ushort(__float2half_rn(o1)) << 16);
    u.y = (unsigned)__half_as_ushort(__float2half_rn(o2)) |
          ((unsigned)__half_as_ushort(__float2half_rn(o3)) << 16);
    u.z = (unsigned)__half_as_ushort(__float2half_rn(o4)) |
          ((unsigned)__half_as_ushort(__float2half_rn(o5)) << 16);
    u.w = (unsigned)__half_as_ushort(__float2half_rn(o6)) |
          ((unsigned)__half_as_ushort(__float2half_rn(o7)) << 16);
    *(uint4*)(outp + (size_t)w * D + li * 8) = u;
  }
}

// parallel pool partial sums over fp16 h2: block = 64-node chunk, thread = col
__global__ __launch_bounds__(128) void k_pool_partial(
    const __half* __restrict__ h2, const int* __restrict__ n2g,
    float* __restrict__ sums) {
  int c = threadIdx.x;
  int n0 = blockIdx.x * POOL_CHUNK;
  int n1 = min(n0 + POOL_CHUNK, NN);
  if (n0 >= NN) return;
  int gcur = n2g[n0];
  float acc = 0.f;
  for (int n = n0; n < n1; ++n) {
    int g = n2g[n];
    if (g != gcur) {
      atomicAdd(&sums[gcur * D + c], acc);
      acc = 0.f;
      gcur = g;
    }
    acc += __half2float(h2[(size_t)n * D + c]);
  }
  atomicAdd(&sums[gcur * D + c], acc);
}

// 3-layer MLP head; one block per graph, 128 threads. Divides sums by count.
__global__ void k_mlp(const float* __restrict__ sums, const int* __restrict__ n2g,
                      const float* __restrict__ Wc1, const float* __restrict__ bc1,
                      const float* __restrict__ Wc2, const float* __restrict__ bc2,
                      const float* __restrict__ Wc3, const float* __restrict__ bc3,
                      float* __restrict__ out) {
  __shared__ float xin[128];
  __shared__ float x1[128];
  __shared__ float red[128];
  int g = blockIdx.x, j = threadIdx.x;
  int start = lower_bound_i(n2g, NN, g);
  int end = lower_bound_i(n2g, NN, g + 1);
  float inv = 1.0f / (float)max(end - start, 1);
  xin[j] = sums[g * D + j] * inv;
  __syncthreads();
  float s = bc1[j];
#pragma unroll 8
  for (int k = 0; k < 128; ++k) s = fmaf(xin[k], Wc1[k * D + j], s);
  x1[j] = fmaxf(s, 0.f);
  __syncthreads();
  float s2 = bc2[j];
#pragma unroll 8
  for (int k = 0; k < 128; ++k) s2 = fmaf(x1[k], Wc2[k * D + j], s2);
  float v2 = fmaxf(s2, 0.f);
  red[j] = v2 * Wc3[j];
  __syncthreads();
  for (int o = 64; o > 0; o >>= 1) {
    if (j < o) red[j] += red[j + o];
    __syncthreads();
  }
  if (j == 0) out[g] = red[0] + bc3[0];
}

extern "C" void kernel_launch(void* const* d_in, const int* in_sizes, int n_in,
                              void* d_out, int out_size, void* d_ws, size_t ws_size,
                              hipStream_t stream) {
  const float* h   = (const float*)d_in[0];
  const int* src   = (const int*)d_in[1];
  const int* dst   = (const int*)d_in[2];
  const int* n2g   = (const int*)d_in[3];
  const float* W1  = (const float*)d_in[4];
  const float* b1  = (const float*)d_in[5];
  const float* W2  = (const float*)d_in[6];
  const float* b2  = (const float*)d_in[7];
  const float* Wc1 = (const float*)d_in[8];
  const float* bc1 = (const float*)d_in[9];
  const float* Wc2 = (const float*)d_in[10];
  const float* bc2 = (const float*)d_in[11];
  const float* Wc3 = (const float*)d_in[12];
  const float* bc3 = (const float*)d_in[13];
  float* out = (float*)d_out;

  char* p = (char*)d_ws;
  size_t o = 0;
  auto take = [&](size_t b) { void* q = p + o; o = (o + b + 255) & ~(size_t)255; return q; };
  float* sums = (float*)take(NG * D * 4);
  size_t zero_bytes = o;                    // zero pool sums only
  int* off   = (int*)take((NN + 1) * 4);
  int* bsum  = (int*)take(NB_SCAN * 4);
  int* ic    = (int*)take(NN * 4);
  float* onrm = (float*)take(NN * 4);
  float* inrm = (float*)take(NN * 4);
  int* csr   = (int*)take((size_t)NE * 4);
  __half* tbuf = (__half*)take((size_t)NN * D * 2);   // t (25.6 MB, fp16)
  __half* hbuf = (__half*)take((size_t)NN * D * 4);   // h1/h2 fp16 in 51.2 MB slot
  (void)ws_size; (void)in_sizes; (void)n_in; (void)out_size;

  // packed partial histograms alias the hbuf slot (29.4 MB <= 51.2 MB);
  // CSR build completes before gather1 first writes hbuf
  int* H = (int*)hbuf;

  hipMemsetAsync(d_ws, 0, zero_bytes, stream);
  dim3 hgrid(NCHUNK, NPART);
  k_hist<<<hgrid, 256, 0, stream>>>(src, dst, H);
  k_reduce<<<(NN + 255) / 256, 256, 0, stream>>>(H, ic, onrm, inrm);
  k_scan_a<<<NB_SCAN, 256, 0, stream>>>(ic, bsum);
  k_scan_b<<<1, 128, 0, stream>>>(bsum, off);
  k_scan_c<<<NB_SCAN, 256, 0, stream>>>(ic, bsum, off);
  k_start<<<(NN + 255) / 256, 256, 0, stream>>>(H, off);
  k_fill2<<<hgrid, 256, 0, stream>>>(src, dst, H, csr);

  // layer 1: t = fp16((h * onrm) @ W1); h1 = fp16(relu(inrm * gather(t) + b1))
  k_matmul<float><<<(NN + BM - 1) / BM, 256, 0, stream>>>(h, W1, onrm, tbuf);
  k_gather<<<(NN * 64) / 256, 256, 0, stream>>>(tbuf, csr, off, inrm, b1, hbuf);
  // layer 2
  k_matmul<__half><<<(NN + BM - 1) / BM, 256, 0, stream>>>(hbuf, W2, onrm, tbuf);
  k_gather<<<(NN * 64) / 256, 256, 0, stream>>>(tbuf, csr, off, inrm, b2, hbuf);

  k_pool_partial<<<(NN + POOL_CHUNK - 1) / POOL_CHUNK, 128, 0, stream>>>(hbuf, n2g, sums);
  k_mlp<<<NG, 128, 0, stream>>>(sums, n2g, Wc1, bc1, Wc2, bc2, Wc3, bc3, out);
}

// Round 14
// 270.331 us; speedup vs baseline: 4.2813x; 1.0082x over previous
//
#include <hip/hip_runtime.h>
#include <hip/hip_fp16.h>

#define NN 100000
#define NE 1600000
#define D 128
#define NG 64
#define BM 64
#define POOL_CHUNK 64
#define SCAN_CHUNK 1024
#define NB_SCAN ((NN + SCAN_CHUNK - 1) / SCAN_CHUNK)   // 98

// CSR-build tiling: 64 edge chunks x 7 node partitions of 16384
// packed counters: low 16 bits = in-degree (dst), high 16 = out-degree (src)
#define NCHUNK 64
#define CH_E (NE / NCHUNK)          // 25000 edges per chunk
#define HP 16384                    // nodes per partition (64 KB LDS counters)
#define NPART 7                     // 7*16384 = 114688 >= NN
#define HSTRIDE (NPART * HP)

typedef _Float16 half8 __attribute__((ext_vector_type(8)));
typedef float f32x4 __attribute__((ext_vector_type(4)));

__device__ __forceinline__ int lower_bound_i(const int* a, int n, int key) {
  int lo = 0, hi = n;
  while (lo < hi) { int mid = (lo + hi) >> 1; if (a[mid] < key) lo = mid + 1; else hi = mid; }
  return lo;
}

// partial packed histograms per (chunk, partition): LDS atomics only
__global__ __launch_bounds__(256) void k_hist(
    const int* __restrict__ src, const int* __restrict__ dst,
    int* __restrict__ H) {
  __shared__ int pk[HP];
  const int c = blockIdx.x, p = blockIdx.y, t = threadIdx.x;
  const int base = p * HP;
  for (int i = t; i < HP; i += 256) pk[i] = 0;
  __syncthreads();
  const int4* s4 = (const int4*)(src + c * CH_E);
  const int4* d4 = (const int4*)(dst + c * CH_E);
  const int n4 = CH_E / 4;  // 6250
  for (int i = t; i < n4; i += 256) {
    int4 s = s4[i], d = d4[i];
    if ((unsigned)(d.x - base) < HP) atomicAdd(&pk[d.x - base], 1);
    if ((unsigned)(d.y - base) < HP) atomicAdd(&pk[d.y - base], 1);
    if ((unsigned)(d.z - base) < HP) atomicAdd(&pk[d.z - base], 1);
    if ((unsigned)(d.w - base) < HP) atomicAdd(&pk[d.w - base], 1);
    if ((unsigned)(s.x - base) < HP) atomicAdd(&pk[s.x - base], 65536);
    if ((unsigned)(s.y - base) < HP) atomicAdd(&pk[s.y - base], 65536);
    if ((unsigned)(s.z - base) < HP) atomicAdd(&pk[s.z - base], 65536);
    if ((unsigned)(s.w - base) < HP) atomicAdd(&pk[s.w - base], 65536);
  }
  __syncthreads();
  size_t rb = (size_t)c * HSTRIDE + base;
  for (int i = t; i < HP; i += 256) H[rb + i] = pk[i];
}

// reduce packed partials over chunks -> in-degree (for scan) + both norms
__global__ __launch_bounds__(256) void k_reduce(
    const int* __restrict__ H,
    int* __restrict__ ic, float* __restrict__ onrm, float* __restrict__ inrm) {
  int n = blockIdx.x * 256 + threadIdx.x;
  if (n >= NN) return;
  int si = 0, so = 0;
#pragma unroll 8
  for (int c = 0; c < NCHUNK; ++c) {
    unsigned v = (unsigned)H[(size_t)c * HSTRIDE + n];
    si += (int)(v & 0xffffu);
    so += (int)(v >> 16);
  }
  ic[n] = si;
  inrm[n] = 1.0f / sqrtf((float)max(si, 1));
  onrm[n] = 1.0f / sqrtf((float)max(so, 1));
}

// phase A: per-block chunk sums (coalesced int4, shuffle reduce)
__global__ __launch_bounds__(256) void k_scan_a(const int* __restrict__ cnt,
                                                int* __restrict__ bsum) {
  int b = blockIdx.x, t = threadIdx.x;
  int idx = b * SCAN_CHUNK + t * 4;
  int4 v = make_int4(0, 0, 0, 0);
  if (idx < NN) v = *(const int4*)(cnt + idx);   // NN % 4 == 0
  int s = v.x + v.y + v.z + v.w;
#pragma unroll
  for (int o = 1; o < 64; o <<= 1) s += __shfl_xor(s, o);
  __shared__ int ws[4];
  if ((t & 63) == 0) ws[t >> 6] = s;
  __syncthreads();
  if (t == 0) bsum[b] = ws[0] + ws[1] + ws[2] + ws[3];
}

// phase B: exclusive scan of the 98 block sums (in place), set off[NN]
__global__ void k_scan_b(int* __restrict__ bsum, int* __restrict__ off) {
  __shared__ int s[128];
  int t = threadIdx.x;
  int v = (t < NB_SCAN) ? bsum[t] : 0;
  s[t] = v;
  __syncthreads();
  for (int o = 1; o < 128; o <<= 1) {
    int u = (t >= o) ? s[t - o] : 0;
    __syncthreads();
    s[t] += u;
    __syncthreads();
  }
  if (t < NB_SCAN) bsum[t] = s[t] - v;  // exclusive prefix
  if (t == 0) off[NN] = NE;
}

// phase C: intra-block exclusive scan + block prefix -> off[]
__global__ __launch_bounds__(256) void k_scan_c(const int* __restrict__ cnt,
                                                const int* __restrict__ bsum,
                                                int* __restrict__ off) {
  int b = blockIdx.x, t = threadIdx.x;
  int idx = b * SCAN_CHUNK + t * 4;
  int4 v = make_int4(0, 0, 0, 0);
  if (idx < NN) v = *(const int4*)(cnt + idx);
  int lsum = v.x + v.y + v.z + v.w;
  int lane = t & 63, wid = t >> 6;
  int x = lsum;
#pragma unroll
  for (int o = 1; o < 64; o <<= 1) {
    int u = __shfl_up(x, o);
    if (lane >= o) x += u;
  }
  __shared__ int wsum[4];
  if (lane == 63) wsum[wid] = x;
  __syncthreads();
  int woff = 0;
  for (int i = 0; i < 4; ++i) woff += (i < wid) ? wsum[i] : 0;
  int excl = x - lsum + woff + bsum[b];
  if (idx < NN) {
    int4 o4;
    o4.x = excl;
    o4.y = excl + v.x;
    o4.z = o4.y + v.y;
    o4.w = o4.z + v.z;
    *(int4*)(off + idx) = o4;
  }
}

// column-wise running offsets: H[c][n] <- off[n] + sum_{c'<c} in(H[c'][n])
__global__ __launch_bounds__(256) void k_start(int* __restrict__ H,
                                               const int* __restrict__ off) {
  int n = blockIdx.x * 256 + threadIdx.x;
  if (n >= NN) return;
  int run = off[n];
#pragma unroll 8
  for (int c = 0; c < NCHUNK; ++c) {
    size_t idx = (size_t)c * HSTRIDE + n;
    int v = H[idx];
    H[idx] = run;
    run += (int)((unsigned)v & 0xffffu);
  }
}

// fill CSR: LDS cursors (absolute positions), plain global stores
__global__ __launch_bounds__(256) void k_fill2(
    const int* __restrict__ src, const int* __restrict__ dst,
    const int* __restrict__ H, int* __restrict__ csr) {
  __shared__ int cur[HP];
  const int c = blockIdx.x, p = blockIdx.y, t = threadIdx.x;
  const int base = p * HP;
  size_t rb = (size_t)c * HSTRIDE + base;
  for (int i = t; i < HP; i += 256) cur[i] = H[rb + i];
  __syncthreads();
  const int4* s4 = (const int4*)(src + c * CH_E);
  const int4* d4 = (const int4*)(dst + c * CH_E);
  const int n4 = CH_E / 4;
  for (int i = t; i < n4; i += 256) {
    int4 s = s4[i], d = d4[i];
    if ((unsigned)(d.x - base) < HP) { int pos = atomicAdd(&cur[d.x - base], 1); csr[pos] = s.x; }
    if ((unsigned)(d.y - base) < HP) { int pos = atomicAdd(&cur[d.y - base], 1); csr[pos] = s.y; }
    if ((unsigned)(d.z - base) < HP) { int pos = atomicAdd(&cur[d.z - base], 1); csr[pos] = s.z; }
    if ((unsigned)(d.w - base) < HP) { int pos = atomicAdd(&cur[d.w - base], 1); csr[pos] = s.w; }
  }
}

// MFMA matmul: t[r][c] = fp16( rs[r] * (A[r,:] @ W) ), fp32 accum.
// A is fp32 (layer 1) or fp16 (layer 2), templated. W staged once as fp16
// transposed Wt[c][k] in LDS (pad 136 halves, k8-XOR swizzle -> b128 frag reads).
template <typename AT>
__global__ __launch_bounds__(256, 4) void k_matmul(
    const AT* __restrict__ A, const float* __restrict__ W,
    const float* __restrict__ rs, __half* __restrict__ C) {
  __shared__ _Float16 Wt[128 * 136];
  const int tid = threadIdx.x;
  const int lane = tid & 63, wv = tid >> 6;
  const int row0 = blockIdx.x * BM + wv * 16;
#pragma unroll
  for (int i = 0; i < 16; ++i) {
    int idx = tid + i * 256;              // 0..4095 float4 slots
    int k = idx >> 5, c0 = (idx & 31) * 4;
    float4 w4 = *(const float4*)&W[(size_t)k * 128 + c0];
    int k8 = k >> 3, ko = k & 7;
#pragma unroll
    for (int j = 0; j < 4; ++j) {
      int c = c0 + j;
      int kidx = (((k8 ^ ((c >> 3) & 15)) << 3) | ko);
      float v = (j == 0) ? w4.x : (j == 1) ? w4.y : (j == 2) ? w4.z : w4.w;
      Wt[c * 136 + kidx] = (_Float16)v;
    }
  }
  const int arow = row0 + (lane & 15);
  const bool valid = arow < NN;
  const float sc = valid ? rs[arow] : 0.f;
  half8 afr[4];
#pragma unroll
  for (int s = 0; s < 4; ++s) {
    half8 a;
    if constexpr (sizeof(AT) == 4) {
      const float* ap = (const float*)A + (size_t)arow * D + (lane >> 4) * 8;
      float4 lo = make_float4(0.f, 0.f, 0.f, 0.f), hi = lo;
      if (valid) {
        lo = *(const float4*)(ap + s * 32);
        hi = *(const float4*)(ap + s * 32 + 4);
      }
      a[0] = (_Float16)(lo.x * sc); a[1] = (_Float16)(lo.y * sc);
      a[2] = (_Float16)(lo.z * sc); a[3] = (_Float16)(lo.w * sc);
      a[4] = (_Float16)(hi.x * sc); a[5] = (_Float16)(hi.y * sc);
      a[6] = (_Float16)(hi.z * sc); a[7] = (_Float16)(hi.w * sc);
    } else {
      const _Float16* ap = (const _Float16*)A + (size_t)arow * D + (lane >> 4) * 8;
      half8 raw = {};
      if (valid) raw = *(const half8*)(ap + s * 32);
#pragma unroll
      for (int j = 0; j < 8; ++j) a[j] = (_Float16)((float)raw[j] * sc);
    }
    afr[s] = a;
  }
  __syncthreads();
  f32x4 acc[8];
#pragma unroll
  for (int ct = 0; ct < 8; ++ct) acc[ct] = (f32x4){0.f, 0.f, 0.f, 0.f};
#pragma unroll
  for (int s = 0; s < 4; ++s) {
    const int k8 = s * 4 + (lane >> 4);
#pragma unroll
    for (int ct = 0; ct < 8; ++ct) {
      int c = ct * 16 + (lane & 15);
      int kidx = ((k8 ^ ((c >> 3) & 15)) << 3);
      half8 b = *(const half8*)&Wt[c * 136 + kidx];
      acc[ct] = __builtin_amdgcn_mfma_f32_16x16x32_f16(afr[s], b, acc[ct], 0, 0, 0);
    }
  }
  const int dcol = lane & 15;
  const int drow0 = row0 + (lane >> 4) * 4;
#pragma unroll
  for (int ct = 0; ct < 8; ++ct) {
#pragma unroll
    for (int r = 0; r < 4; ++r) {
      int row = drow0 + r;
      if (row < NN)
        C[(size_t)row * D + ct * 16 + dcol] = __float2half_rn(acc[ct][r]);
    }
  }
}

// out[d,:] = fp16(relu(in_norm[d] * sum_{s in CSR(d)} t[s,:] + bias))
// one wave per dst node; 4 lane-groups of 16, 16B per lane per edge.
// Unrolled x4: four independent index+row loads in flight per subgroup.
__global__ __launch_bounds__(256) void k_gather(
    const __half* __restrict__ t, const int* __restrict__ csr,
    const int* __restrict__ off, const float* __restrict__ inn,
    const float* __restrict__ bias, __half* __restrict__ outp) {
  int w = (blockIdx.x * blockDim.x + threadIdx.x) >> 6;
  int lane = threadIdx.x & 63;
  if (w >= NN) return;
  int lo = off[w], hi = off[w + 1];
  const int g = lane >> 4;        // edge subgroup 0..3
  const int li = lane & 15;       // 16B column slot
  const __half* tp = t + li * 8;
  float a0 = 0.f, a1 = 0.f, a2 = 0.f, a3 = 0.f;
  float a4 = 0.f, a5 = 0.f, a6 = 0.f, a7 = 0.f;
  int e = lo + g;
  for (; e + 12 < hi; e += 16) {
    int s0 = csr[e];
    int s1 = csr[e + 4];
    int s2 = csr[e + 8];
    int s3 = csr[e + 12];
    float4 r0 = *(const float4*)(tp + (size_t)s0 * D);
    float4 r1 = *(const float4*)(tp + (size_t)s1 * D);
    float4 r2 = *(const float4*)(tp + (size_t)s2 * D);
    float4 r3 = *(const float4*)(tp + (size_t)s3 * D);
    const __half2* h0 = (const __half2*)&r0;
    const __half2* h1 = (const __half2*)&r1;
    const __half2* h2 = (const __half2*)&r2;
    const __half2* h3 = (const __half2*)&r3;
    float2 f00 = __half22float2(h0[0]), f01 = __half22float2(h0[1]);
    float2 f02 = __half22float2(h0[2]), f03 = __half22float2(h0[3]);
    float2 f10 = __half22float2(h1[0]), f11 = __half22float2(h1[1]);
    float2 f12 = __half22float2(h1[2]), f13 = __half22float2(h1[3]);
    float2 f20 = __half22float2(h2[0]), f21 = __half22float2(h2[1]);
    float2 f22 = __half22float2(h2[2]), f23 = __half22float2(h2[3]);
    float2 f30 = __half22float2(h3[0]), f31 = __half22float2(h3[1]);
    float2 f32 = __half22float2(h3[2]), f33 = __half22float2(h3[3]);
    a0 += (f00.x + f10.x) + (f20.x + f30.x);
    a1 += (f00.y + f10.y) + (f20.y + f30.y);
    a2 += (f01.x + f11.x) + (f21.x + f31.x);
    a3 += (f01.y + f11.y) + (f21.y + f31.y);
    a4 += (f02.x + f12.x) + (f22.x + f32.x);
    a5 += (f02.y + f12.y) + (f22.y + f32.y);
    a6 += (f03.x + f13.x) + (f23.x + f33.x);
    a7 += (f03.y + f13.y) + (f23.y + f33.y);
  }
  for (; e < hi; e += 4) {
    int s0 = csr[e];
    float4 r0 = *(const float4*)(tp + (size_t)s0 * D);
    const __half2* h0 = (const __half2*)&r0;
    float2 f00 = __half22float2(h0[0]), f01 = __half22float2(h0[1]);
    float2 f02 = __half22float2(h0[2]), f03 = __half22float2(h0[3]);
    a0 += f00.x; a1 += f00.y; a2 += f01.x; a3 += f01.y;
    a4 += f02.x; a5 += f02.y; a6 += f03.x; a7 += f03.y;
  }
  a0 += __shfl_xor(a0, 16); a0 += __shfl_xor(a0, 32);
  a1 += __shfl_xor(a1, 16); a1 += __shfl_xor(a1, 32);
  a2 += __shfl_xor(a2, 16); a2 += __shfl_xor(a2, 32);
  a3 += __shfl_xor(a3, 16); a3 += __shfl_xor(a3, 32);
  a4 += __shfl_xor(a4, 16); a4 += __shfl_xor(a4, 32);
  a5 += __shfl_xor(a5, 16); a5 += __shfl_xor(a5, 32);
  a6 += __shfl_xor(a6, 16); a6 += __shfl_xor(a6, 32);
  a7 += __shfl_xor(a7, 16); a7 += __shfl_xor(a7, 32);
  if (lane < 16) {
    float nm = inn[w];
    float4 b0 = *(const float4*)(bias + li * 8);
    float4 b1 = *(const float4*)(bias + li * 8 + 4);
    float o0 = fmaxf(fmaf(nm, a0, b0.x), 0.f);
    float o1 = fmaxf(fmaf(nm, a1, b0.y), 0.f);
    float o2 = fmaxf(fmaf(nm, a2, b0.z), 0.f);
    float o3 = fmaxf(fmaf(nm, a3, b0.w), 0.f);
    float o4 = fmaxf(fmaf(nm, a4, b1.x), 0.f);
    float o5 = fmaxf(fmaf(nm, a5, b1.y), 0.f);
    float o6 = fmaxf(fmaf(nm, a6, b1.z), 0.f);
    float o7 = fmaxf(fmaf(nm, a7, b1.w), 0.f);
    uint4 u;
    u.x = (unsigned)__half_as_ushort(__float2half_rn(o0)) |
          ((unsigned)__half_as_ushort(__float2half_rn(o1)) << 16);
    u.y = (unsigned)__half_as_ushort(__float2half_rn(o2)) |
          ((unsigned)__half_as_ushort(__float2half_rn(o3)) << 16);
    u.z = (unsigned)__half_as_ushort(__float2half_rn(o4)) |
          ((unsigned)__half_as_ushort(__float2half_rn(o5)) << 16);
    u.w = (unsigned)__half_as_ushort(__float2half_rn(o6)) |
          ((unsigned)__half_as_ushort(__float2half_rn(o7)) << 16);
    *(uint4*)(outp + (size_t)w * D + li * 8) = u;
  }
}

// parallel pool partial sums over fp16 h2: block = 64-node chunk, thread = col
__global__ __launch_bounds__(128) void k_pool_partial(
    const __half* __restrict__ h2, const int* __restrict__ n2g,
    float* __restrict__ sums) {
  int c = threadIdx.x;
  int n0 = blockIdx.x * POOL_CHUNK;
  int n1 = min(n0 + POOL_CHUNK, NN);
  if (n0 >= NN) return;
  int gcur = n2g[n0];
  float acc = 0.f;
  for (int n = n0; n < n1; ++n) {
    int g = n2g[n];
    if (g != gcur) {
      atomicAdd(&sums[gcur * D + c], acc);
      acc = 0.f;
      gcur = g;
    }
    acc += __half2float(h2[(size_t)n * D + c]);
  }
  atomicAdd(&sums[gcur * D + c], acc);
}

// 3-layer MLP head; one block per graph, 128 threads. Divides sums by count.
__global__ void k_mlp(const float* __restrict__ sums, const int* __restrict__ n2g,
                      const float* __restrict__ Wc1, const float* __restrict__ bc1,
                      const float* __restrict__ Wc2, const float* __restrict__ bc2,
                      const float* __restrict__ Wc3, const float* __restrict__ bc3,
                      float* __restrict__ out) {
  __shared__ float xin[128];
  __shared__ float x1[128];
  __shared__ float red[128];
  int g = blockIdx.x, j = threadIdx.x;
  int start = lower_bound_i(n2g, NN, g);
  int end = lower_bound_i(n2g, NN, g + 1);
  float inv = 1.0f / (float)max(end - start, 1);
  xin[j] = sums[g * D + j] * inv;
  __syncthreads();
  float s = bc1[j];
#pragma unroll 8
  for (int k = 0; k < 128; ++k) s = fmaf(xin[k], Wc1[k * D + j], s);
  x1[j] = fmaxf(s, 0.f);
  __syncthreads();
  float s2 = bc2[j];
#pragma unroll 8
  for (int k = 0; k < 128; ++k) s2 = fmaf(x1[k], Wc2[k * D + j], s2);
  float v2 = fmaxf(s2, 0.f);
  red[j] = v2 * Wc3[j];
  __syncthreads();
  for (int o = 64; o > 0; o >>= 1) {
    if (j < o) red[j] += red[j + o];
    __syncthreads();
  }
  if (j == 0) out[g] = red[0] + bc3[0];
}

extern "C" void kernel_launch(void* const* d_in, const int* in_sizes, int n_in,
                              void* d_out, int out_size, void* d_ws, size_t ws_size,
                              hipStream_t stream) {
  const float* h   = (const float*)d_in[0];
  const int* src   = (const int*)d_in[1];
  const int* dst   = (const int*)d_in[2];
  const int* n2g   = (const int*)d_in[3];
  const float* W1  = (const float*)d_in[4];
  const float* b1  = (const float*)d_in[5];
  const float* W2  = (const float*)d_in[6];
  const float* b2  = (const float*)d_in[7];
  const float* Wc1 = (const float*)d_in[8];
  const float* bc1 = (const float*)d_in[9];
  const float* Wc2 = (const float*)d_in[10];
  const float* bc2 = (const float*)d_in[11];
  const float* Wc3 = (const float*)d_in[12];
  const float* bc3 = (const float*)d_in[13];
  float* out = (float*)d_out;

  char* p = (char*)d_ws;
  size_t o = 0;
  auto take = [&](size_t b) { void* q = p + o; o = (o + b + 255) & ~(size_t)255; return q; };
  float* sums = (float*)take(NG * D * 4);
  size_t zero_bytes = o;                    // zero pool sums only
  int* off   = (int*)take((NN + 1) * 4);
  int* bsum  = (int*)take(NB_SCAN * 4);
  int* ic    = (int*)take(NN * 4);
  float* onrm = (float*)take(NN * 4);
  float* inrm = (float*)take(NN * 4);
  int* csr   = (int*)take((size_t)NE * 4);
  __half* tbuf = (__half*)take((size_t)NN * D * 2);   // t (25.6 MB, fp16)
  __half* hbuf = (__half*)take((size_t)NN * D * 4);   // h1/h2 fp16 in 51.2 MB slot
  (void)ws_size; (void)in_sizes; (void)n_in; (void)out_size;

  // packed partial histograms alias the hbuf slot (29.4 MB <= 51.2 MB);
  // CSR build completes before gather1 first writes hbuf
  int* H = (int*)hbuf;

  hipMemsetAsync(d_ws, 0, zero_bytes, stream);
  dim3 hgrid(NCHUNK, NPART);
  k_hist<<<hgrid, 256, 0, stream>>>(src, dst, H);
  k_reduce<<<(NN + 255) / 256, 256, 0, stream>>>(H, ic, onrm, inrm);
  k_scan_a<<<NB_SCAN, 256, 0, stream>>>(ic, bsum);
  k_scan_b<<<1, 128, 0, stream>>>(bsum, off);
  k_scan_c<<<NB_SCAN, 256, 0, stream>>>(ic, bsum, off);
  k_start<<<(NN + 255) / 256, 256, 0, stream>>>(H, off);
  k_fill2<<<hgrid, 256, 0, stream>>>(src, dst, H, csr);

  // layer 1: t = fp16((h * onrm) @ W1); h1 = fp16(relu(inrm * gather(t) + b1))
  k_matmul<float><<<(NN + BM - 1) / BM, 256, 0, stream>>>(h, W1, onrm, tbuf);
  k_gather<<<(NN * 64) / 256, 256, 0, stream>>>(tbuf, csr, off, inrm, b1, hbuf);
  // layer 2
  k_matmul<__half><<<(NN + BM - 1) / BM, 256, 0, stream>>>(hbuf, W2, onrm, tbuf);
  k_gather<<<(NN * 64) / 256, 256, 0, stream>>>(tbuf, csr, off, inrm, b2, hbuf);

  k_pool_partial<<<(NN + POOL_CHUNK - 1) / POOL_CHUNK, 128, 0, stream>>>(hbuf, n2g, sums);
  k_mlp<<<NG, 128, 0, stream>>>(sums, n2g, Wc1, bc1, Wc2, bc2, Wc3, bc3, out);
}